// Round 5
// baseline (2999.502 us; speedup 1.0000x reference)
//
#include <hip/hip_runtime.h>
#include <hip/hip_bf16.h>
#include <cstdint>
#include <cstddef>

typedef __attribute__((ext_vector_type(8))) _Float16 f16x8;
typedef __attribute__((ext_vector_type(4))) float f32x4;

__device__ __forceinline__ float h2f(unsigned short u) {
  union { unsigned short s; _Float16 h; } x; x.s = u; return (float)x.h;
}
__device__ __forceinline__ unsigned short f2h(float f) {
  union { unsigned short s; _Float16 h; } x; x.h = (_Float16)f; return x.s;
}
__device__ __forceinline__ void gload_lds16(const void* g, void* l) {
  __builtin_amdgcn_global_load_lds((const __attribute__((address_space(1))) unsigned int*)g,
                                   (__attribute__((address_space(3))) unsigned int*)l, 16, 0, 0);
}

// ============ input transform: fp32 NCHW [N,3,H,W] -> fp16 [N,H,W,4] (c3=0) ============
__global__ void in_transform(const float* __restrict__ in, unsigned short* __restrict__ out,
                             int HW, int total) {
  int i = blockIdx.x * 256 + threadIdx.x;
  if (i >= total) return;
  int n = i / HW;
  int r = i - n * HW;
  const float* p = in + (long)n * 3 * HW + r;
  uint2 v;
  v.x = (unsigned)f2h(p[0]) | ((unsigned)f2h(p[HW]) << 16);
  v.y = (unsigned)f2h(p[2 * HW]);
  ((uint2*)out)[i] = v;
}

// ============ conv1 weight transform: [96][3][11][11] fp32 -> [17][128][32] fp16 ============
__global__ void wt1_transform(const float* __restrict__ w, unsigned short* __restrict__ o,
                              int total) {
  int i = blockIdx.x * 256 + threadIdx.x;
  if (i >= total) return;
  int j = i & 31;
  int r = i >> 5;
  int co = r & 127;
  int kk = r >> 7;
  int run = kk * 4 + (j >> 3);
  int ky = run / 6;
  int e = (run - ky * 6) * 8 + (j & 7);
  int kx = e >> 2, c = e & 3;
  float v = 0.f;
  if (ky < 11 && kx < 11 && c < 3 && co < 96)
    v = w[((co * 3 + c) * 11 + ky) * 11 + kx];
  o[i] = f2h(v);
}

// ============ conv1 MFMA: fp16 [N,Hi,Wi,4] -> fp16 NHWC [N,Ho,Wo,96], K=11x11x3 s=2 ============
__global__ __launch_bounds__(256)
void conv1_mfma(const unsigned short* __restrict__ in, const unsigned short* __restrict__ wt,
                unsigned short* __restrict__ out, int Hi, int Wi, int Ho, int Wo, int NPIX) {
  __shared__ __align__(16) unsigned short sA[128 * 32];
  __shared__ __align__(16) unsigned short sB[128 * 32];
  __shared__ int sOB[128];
  const int t = threadIdx.x;
  const int px0 = blockIdx.x * 128;
  if (t < 128) {
    int g = px0 + t;
    int ob = -1;
    if (g < NPIX) {
      int n = g / (Ho * Wo);
      int r = g - n * Ho * Wo;
      int oy = r / Wo, ox = r - (r / Wo) * Wo;
      ob = ((n * Ho + oy) * Wo + ox) * 96;
    }
    sOB[t] = ob;
  }
  long rbase[2];
#pragma unroll
  for (int i = 0; i < 2; ++i) {
    int pxl = i * 64 + (t >> 2);
    int g = px0 + pxl;
    long rb = 0;
    if (g < NPIX) {
      int n = g / (Ho * Wo);
      int r = g - n * Ho * Wo;
      int oy = r / Wo, ox = r - (r / Wo) * Wo;
      rb = ((long)(n * Hi + 2 * oy) * Wi + 2 * ox) * 4;
    }
    rbase[i] = rb;
  }
  const int a4 = t & 3;
  f32x4 acc[4][4];
  f32x4 zz = {0.f, 0.f, 0.f, 0.f};
#pragma unroll
  for (int m = 0; m < 4; ++m)
#pragma unroll
    for (int n = 0; n < 4; ++n) acc[m][n] = zz;
  const int w = t >> 6;
  const int l = t & 63;
  const int wpx = (w & 1) * 64, wco = (w >> 1) * 64;
  const int arow = wpx + (l & 15);
  const int brow = wco + (l & 15);
  const int q8 = (l >> 4) * 8;
  const int W4 = Wi * 4;
  for (int kk = 0; kk < 17; ++kk) {
    int run = kk * 4 + a4;
    int ky = run / 6;
    int e0 = (run - ky * 6) * 8;
    long koff = (long)ky * W4 + e0;
    gload_lds16(in + rbase[0] + koff, &sA[t * 8]);
    gload_lds16(in + rbase[1] + koff, &sA[(256 + t) * 8]);
    const unsigned short* wp = wt + (long)kk * 4096;
    gload_lds16(wp + t * 8, &sB[t * 8]);
    gload_lds16(wp + 2048 + t * 8, &sB[(256 + t) * 8]);
    __syncthreads();
    f16x8 av[4], bv[4];
#pragma unroll
    for (int m = 0; m < 4; ++m) av[m] = *(const f16x8*)&sA[(arow + m * 16) * 32 + q8];
#pragma unroll
    for (int n = 0; n < 4; ++n) bv[n] = *(const f16x8*)&sB[(brow + n * 16) * 32 + q8];
#pragma unroll
    for (int m = 0; m < 4; ++m)
#pragma unroll
      for (int n = 0; n < 4; ++n)
        acc[m][n] = __builtin_amdgcn_mfma_f32_16x16x32_f16(av[m], bv[n], acc[m][n], 0, 0, 0);
    __syncthreads();
  }
#pragma unroll
  for (int m = 0; m < 4; ++m) {
#pragma unroll
    for (int r = 0; r < 4; ++r) {
      int pxl = wpx + m * 16 + (l >> 4) * 4 + r;
      int ob = sOB[pxl];
#pragma unroll
      for (int n = 0; n < 4; ++n) {
        int co = wco + n * 16 + (l & 15);
        if (ob >= 0 && co < 96) out[ob + co] = f2h(acc[m][n][r]);
      }
    }
  }
}

// ============ implicit-GEMM MFMA conv (stride 1, VALID), fp16 ============
template <int K>
__global__ __launch_bounds__(256)
void conv_mfma(const unsigned short* __restrict__ in, const unsigned short* __restrict__ wt,
               unsigned short* __restrict__ out,
               int Ci, int Hi, int Wi, int Ho, int Wo, int Co_pad, int Co_real, int NPIX) {
  __shared__ __align__(16) unsigned short sA[128 * 32];
  __shared__ __align__(16) unsigned short sB[128 * 32];
  __shared__ int sOB[128];
  const int t = threadIdx.x;
  const int px0 = blockIdx.x * 128;
  const int co0 = blockIdx.y * 128;
  if (t < 128) {
    int g = px0 + t;
    int ob = -1;
    if (g < NPIX) {
      int n = g / (Ho * Wo);
      int r = g - n * Ho * Wo;
      int oy = r / Wo, ox = r - (r / Wo) * Wo;
      ob = ((n * Ho + oy) * Wo + ox) * Co_real;
    }
    sOB[t] = ob;
  }
  long rbase[2];
#pragma unroll
  for (int i = 0; i < 2; ++i) {
    int pxl = i * 64 + (t >> 2);
    int g = px0 + pxl;
    long rb = 0;
    if (g < NPIX) {
      int n = g / (Ho * Wo);
      int r = g - n * Ho * Wo;
      int oy = r / Wo, ox = r - (r / Wo) * Wo;
      rb = ((long)(n * Hi + oy) * Wi + ox) * Ci;
    }
    rbase[i] = rb;
  }
  const int seg8 = (t & 3) * 8;
  const int colA = t >> 2;
  f32x4 acc[4][4];
  f32x4 zz = {0.f, 0.f, 0.f, 0.f};
#pragma unroll
  for (int m = 0; m < 4; ++m)
#pragma unroll
    for (int n = 0; n < 4; ++n) acc[m][n] = zz;
  const int w = t >> 6;
  const int l = t & 63;
  const int wpx = (w & 1) * 64, wco = (w >> 1) * 64;
  const int arow = wpx + (l & 15);
  const int brow = wco + (l & 15);
  const int q8 = (l >> 4) * 8;
  int ci0 = 0, kx = 0, ky = 0;
  const int NK = (Ci >> 5) * K * K;
  for (int kk = 0; kk < NK; ++kk) {
    long koff = (long)(ky * Wi + kx) * Ci + ci0 + seg8;
#pragma unroll
    for (int i = 0; i < 2; ++i)
      gload_lds16(in + rbase[i] + koff, &sA[(i * 256 + t) * 8]);
    long wbase = (long)((ky * K + kx) * Co_pad + co0) * Ci + ci0 + seg8;
#pragma unroll
    for (int i = 0; i < 2; ++i)
      gload_lds16(wt + wbase + (long)(i * 64 + colA) * Ci, &sB[(i * 256 + t) * 8]);
    __syncthreads();
    f16x8 av[4], bv[4];
#pragma unroll
    for (int m = 0; m < 4; ++m) av[m] = *(const f16x8*)&sA[(arow + m * 16) * 32 + q8];
#pragma unroll
    for (int n = 0; n < 4; ++n) bv[n] = *(const f16x8*)&sB[(brow + n * 16) * 32 + q8];
#pragma unroll
    for (int m = 0; m < 4; ++m)
#pragma unroll
      for (int n = 0; n < 4; ++n)
        acc[m][n] = __builtin_amdgcn_mfma_f32_16x16x32_f16(av[m], bv[n], acc[m][n], 0, 0, 0);
    __syncthreads();
    ci0 += 32;
    if (ci0 == Ci) { ci0 = 0; ++kx; if (kx == K) { kx = 0; ++ky; } }
  }
#pragma unroll
  for (int m = 0; m < 4; ++m) {
#pragma unroll
    for (int r = 0; r < 4; ++r) {
      int pxl = wpx + m * 16 + (l >> 4) * 4 + r;
      int ob = sOB[pxl];
#pragma unroll
      for (int n = 0; n < 4; ++n) {
        int co = co0 + wco + n * 16 + (l & 15);
        if (ob >= 0 && co < Co_real) out[ob + co] = f2h(acc[m][n][r]);
      }
    }
  }
}

// ============ weight transform: [Co][Ci][K][K] fp32 -> [K*K][Co_pad][Ci] fp16 ============
__global__ void wt_transform(const float* __restrict__ w, unsigned short* __restrict__ o,
                             int Co, int Co_pad, int Ci, int KK, long total) {
  long i = (long)blockIdx.x * blockDim.x + threadIdx.x;
  if (i >= total) return;
  int ci = (int)(i % Ci);
  long r = i / Ci;
  int co = (int)(r % Co_pad);
  int rk = (int)(r / Co_pad);
  float v = 0.f;
  if (co < Co) v = w[((long)co * Ci + ci) * KK + rk];
  o[i] = f2h(v);
}

// ============ BN stats: vectorized grid-stride partial sums ============
// requires blockDim*8 % C == 0 -> per-thread channel base is constant.
__global__ void bn_stats_part(const unsigned short* __restrict__ x, float* __restrict__ part,
                              int C, long total8) {
  const int t = threadIdx.x;
  const int G = C >> 3;           // uint4 column-groups per row
  float s[8], q[8];
#pragma unroll
  for (int j = 0; j < 8; ++j) { s[j] = 0.f; q[j] = 0.f; }
  long i = (long)blockIdx.x * blockDim.x + t;
  const long stride = (long)gridDim.x * blockDim.x;
  for (; i < total8; i += stride) {
    const uint4 v = ((const uint4*)x)[i];
    float f[8];
    f[0] = h2f((unsigned short)(v.x & 0xffff)); f[1] = h2f((unsigned short)(v.x >> 16));
    f[2] = h2f((unsigned short)(v.y & 0xffff)); f[3] = h2f((unsigned short)(v.y >> 16));
    f[4] = h2f((unsigned short)(v.z & 0xffff)); f[5] = h2f((unsigned short)(v.z >> 16));
    f[6] = h2f((unsigned short)(v.w & 0xffff)); f[7] = h2f((unsigned short)(v.w >> 16));
#pragma unroll
    for (int j = 0; j < 8; ++j) {
      s[j] += f[j];
      q[j] = fmaf(f[j], f[j], q[j]);
    }
  }
  __shared__ float ls[256][8];
  __shared__ float lq[256][8];
#pragma unroll
  for (int j = 0; j < 8; ++j) { ls[t][j] = s[j]; lq[t][j] = q[j]; }
  __syncthreads();
  // deterministic: thread u (< C) sums its channel across the K=blockDim/G owners
  if (t < C) {
    const int g = t >> 3, j = t & 7;
    const int Kc = blockDim.x / G;
    float ts = 0.f, tq = 0.f;
    for (int k = 0; k < Kc; ++k) {
      ts += ls[g + k * G][j];
      tq += lq[g + k * G][j];
    }
    part[((long)blockIdx.x * C + t) * 2] = ts;
    part[((long)blockIdx.x * C + t) * 2 + 1] = tq;
  }
}

__global__ void bn_finalize(const float* __restrict__ part, const float* __restrict__ g,
                            const float* __restrict__ b, float* __restrict__ sc,
                            float* __restrict__ sh, int C, int nch, float cnt) {
  int c = threadIdx.x;
  if (c >= C) return;
  float s = 0.f, q = 0.f;
  for (int k = 0; k < nch; ++k) {
    s += part[((long)k * C + c) * 2];
    q += part[((long)k * C + c) * 2 + 1];
  }
  float m = s / cnt;
  float v = q / cnt - m * m;
  float r = rsqrtf(v + 1e-5f);
  float scl = r * g[c];
  sc[c] = scl;
  sh[c] = b[c] - m * scl;
}

// ============ BN apply (8-wide, in place or fp16->fp32) ============
template <bool RELU, bool OUTF32>
__global__ void bn_apply_k(const unsigned short* __restrict__ x, void* __restrict__ y,
                           const float* __restrict__ sc, const float* __restrict__ sh,
                           int C, long total8) {
  long i = (long)blockIdx.x * blockDim.x + threadIdx.x;
  if (i >= total8) return;
  const uint4 v = ((const uint4*)x)[i];
  long base = i * 8;
  int c0 = (int)(base % C);
  const float4 s0 = *(const float4*)&sc[c0];
  const float4 s1 = *(const float4*)&sc[c0 + 4];
  const float4 h0 = *(const float4*)&sh[c0];
  const float4 h1 = *(const float4*)&sh[c0 + 4];
  float f[8];
  f[0] = h2f((unsigned short)(v.x & 0xffff)); f[1] = h2f((unsigned short)(v.x >> 16));
  f[2] = h2f((unsigned short)(v.y & 0xffff)); f[3] = h2f((unsigned short)(v.y >> 16));
  f[4] = h2f((unsigned short)(v.z & 0xffff)); f[5] = h2f((unsigned short)(v.z >> 16));
  f[6] = h2f((unsigned short)(v.w & 0xffff)); f[7] = h2f((unsigned short)(v.w >> 16));
  const float S[8] = {s0.x, s0.y, s0.z, s0.w, s1.x, s1.y, s1.z, s1.w};
  const float H[8] = {h0.x, h0.y, h0.z, h0.w, h1.x, h1.y, h1.z, h1.w};
#pragma unroll
  for (int j = 0; j < 8; ++j) {
    f[j] = fmaf(f[j], S[j], H[j]);
    if (RELU) f[j] = fmaxf(f[j], 0.f);
  }
  if (OUTF32) {
    float4 o0 = {f[0], f[1], f[2], f[3]}, o1 = {f[4], f[5], f[6], f[7]};
    ((float4*)y)[2 * i] = o0;
    ((float4*)y)[2 * i + 1] = o1;
  } else {
    uint4 o;
    o.x = (unsigned)f2h(f[0]) | ((unsigned)f2h(f[1]) << 16);
    o.y = (unsigned)f2h(f[2]) | ((unsigned)f2h(f[3]) << 16);
    o.z = (unsigned)f2h(f[4]) | ((unsigned)f2h(f[5]) << 16);
    o.w = (unsigned)f2h(f[6]) | ((unsigned)f2h(f[7]) << 16);
    ((uint4*)y)[i] = o;
  }
}

// ============ MaxPool 3x3 s2 (NHWC fp16), 8 channels/thread ============
__global__ void pool_k(const unsigned short* __restrict__ in, unsigned short* __restrict__ out,
                       int C8, int Hi, int Wi, int Ho, int Wo, long total8) {
  long i = (long)blockIdx.x * blockDim.x + threadIdx.x;
  if (i >= total8) return;
  int cg = (int)(i % C8);
  long r = i / C8;
  int ox = (int)(r % Wo);
  r /= Wo;
  int oy = (int)(r % Ho);
  int n = (int)(r / Ho);
  const uint4* bp = (const uint4*)in + ((long)(n * Hi + 2 * oy) * Wi + 2 * ox) * C8 + cg;
  float m[8];
#pragma unroll
  for (int j = 0; j < 8; ++j) m[j] = -3.4e38f;
#pragma unroll
  for (int dy = 0; dy < 3; ++dy)
#pragma unroll
    for (int dx = 0; dx < 3; ++dx) {
      const uint4 v = bp[((long)dy * Wi + dx) * C8];
      m[0] = fmaxf(m[0], h2f((unsigned short)(v.x & 0xffff)));
      m[1] = fmaxf(m[1], h2f((unsigned short)(v.x >> 16)));
      m[2] = fmaxf(m[2], h2f((unsigned short)(v.y & 0xffff)));
      m[3] = fmaxf(m[3], h2f((unsigned short)(v.y >> 16)));
      m[4] = fmaxf(m[4], h2f((unsigned short)(v.z & 0xffff)));
      m[5] = fmaxf(m[5], h2f((unsigned short)(v.z >> 16)));
      m[6] = fmaxf(m[6], h2f((unsigned short)(v.w & 0xffff)));
      m[7] = fmaxf(m[7], h2f((unsigned short)(v.w >> 16)));
    }
  uint4 o;
  o.x = (unsigned)f2h(m[0]) | ((unsigned)f2h(m[1]) << 16);
  o.y = (unsigned)f2h(m[2]) | ((unsigned)f2h(m[3]) << 16);
  o.z = (unsigned)f2h(m[4]) | ((unsigned)f2h(m[5]) << 16);
  o.w = (unsigned)f2h(m[6]) | ((unsigned)f2h(m[7]) << 16);
  ((uint4*)out)[i] = o;
}

// ============ cross-correlation (fp32, NHWC) ============
__global__ void xcorr_k(const float* __restrict__ o1, const float* __restrict__ o2,
                        float* __restrict__ corr) {
  const int p = blockIdx.x;
  const int oy = p / 17, ox = p - (p / 17) * 17;
  float acc = 0.f;
  for (int i = threadIdx.x; i < 147456; i += 256) {
    int c = i & 127;
    int r = i >> 7;
    int kx = r % 6;
    r /= 6;
    int ky = r % 6;
    int b = r / 6;
    acc = fmaf(o1[(((b * 22 + oy + ky) * 22) + ox + kx) * 128 + c], o2[i], acc);
  }
#pragma unroll
  for (int off = 32; off > 0; off >>= 1) acc += __shfl_down(acc, off, 64);
  __shared__ float sh[4];
  const int lane = threadIdx.x & 63, wid = threadIdx.x >> 6;
  if (lane == 0) sh[wid] = acc;
  __syncthreads();
  if (threadIdx.x == 0) {
    float tt = sh[0] + sh[1] + sh[2] + sh[3];
    corr[p] = tt * (1.f / 147456.f);
  }
}

__global__ void bcast_out(const float* __restrict__ corr, float* __restrict__ out, int total) {
  int i = blockIdx.x * blockDim.x + threadIdx.x;
  if (i < total) out[i] = corr[i % 289];
}

// ============ host ============
extern "C" void kernel_launch(void* const* d_in, const int* in_sizes, int n_in,
                              void* d_out, int out_size, void* d_ws, size_t ws_size,
                              hipStream_t stream) {
  (void)in_sizes; (void)n_in; (void)ws_size; (void)out_size;
  const float* input1 = (const float*)d_in[0];
  const float* input2 = (const float*)d_in[1];
  const float* cw[5];
  const float* bg[5];
  const float* bb[5];
  for (int i = 0; i < 5; ++i) {
    cw[i] = (const float*)d_in[2 + 2 * i];
    bg[i] = (const float*)d_in[12 + 2 * i];
    bb[i] = (const float*)d_in[13 + 2 * i];
  }
  char* p = (char*)d_ws;
  auto alloc = [&](size_t bytes) {
    char* r = p;
    p += (bytes + 255) & ~(size_t)255;
    return r;
  };
  unsigned short* P = (unsigned short*)alloc(93000000);
  unsigned short* Q = (unsigned short*)alloc(7200000);
  unsigned short* R = (unsigned short*)alloc(23000000);
  float* O1 = (float*)alloc(32l * 22 * 22 * 128 * 4);
  float* O2 = (float*)alloc(32l * 6 * 6 * 128 * 4);
  unsigned short* I1h = (unsigned short*)alloc(32l * 255 * 255 * 4 * 2 + 16384);
  unsigned short* I2h = (unsigned short*)alloc(32l * 127 * 127 * 4 * 2 + 16384);
  unsigned short* W1h = (unsigned short*)alloc(17l * 128 * 32 * 2);
  unsigned short* W2 = (unsigned short*)alloc(25l * 256 * 96 * 2);
  unsigned short* W3 = (unsigned short*)alloc(9l * 256 * 256 * 2);
  unsigned short* W4 = (unsigned short*)alloc(9l * 256 * 192 * 2);
  unsigned short* W5 = (unsigned short*)alloc(9l * 128 * 192 * 2);
  float* part = (float*)alloc(1024l * 256 * 2 * 4);
  float* sc = (float*)alloc(256 * 4);
  float* sh = (float*)alloc(256 * 4);
  float* corr = (float*)alloc(289 * 4);

  // weight + input transforms
  {
    int t1 = 17 * 128 * 32;
    wt1_transform<<<(unsigned)((t1 + 255) / 256), 256, 0, stream>>>(cw[0], W1h, t1);
    long t2 = 25l * 256 * 96;
    wt_transform<<<(unsigned)((t2 + 255) / 256), 256, 0, stream>>>(cw[1], W2, 256, 256, 96, 25, t2);
    long t3 = 9l * 256 * 256;
    wt_transform<<<(unsigned)((t3 + 255) / 256), 256, 0, stream>>>(cw[2], W3, 192, 256, 256, 9, t3);
    long t4 = 9l * 256 * 192;
    wt_transform<<<(unsigned)((t4 + 255) / 256), 256, 0, stream>>>(cw[3], W4, 192, 256, 192, 9, t4);
    long t5 = 9l * 128 * 192;
    wt_transform<<<(unsigned)((t5 + 255) / 256), 256, 0, stream>>>(cw[4], W5, 128, 128, 192, 9, t5);
    int p1 = 32 * 255 * 255;
    in_transform<<<(unsigned)((p1 + 255) / 256), 256, 0, stream>>>(input1, I1h, 255 * 255, p1);
    int p2 = 32 * 127 * 127;
    in_transform<<<(unsigned)((p2 + 255) / 256), 256, 0, stream>>>(input2, I2h, 127 * 127, p2);
  }

  const int N = 32;
  auto stats_apply = [&](unsigned short* X, int C, long NP, const float* g, const float* b,
                         bool relu, float* outf) {
    long t8 = NP * C / 8;
    // blockDim*8 % C == 0: 192 for C%96==0 patterns, 256 otherwise
    int bd = (C == 96 || C == 192) ? 192 : 256;
    int nb = (int)((t8 + bd - 1) / bd);
    if (nb > 1024) nb = 1024;
    if (nb < 1) nb = 1;
    bn_stats_part<<<nb, bd, 0, stream>>>(X, part, C, t8);
    int Cr = ((C + 63) / 64) * 64;
    bn_finalize<<<1, Cr, 0, stream>>>(part, g, b, sc, sh, C, nb, (float)NP);
    unsigned blocks = (unsigned)((t8 + 255) / 256);
    if (outf)
      bn_apply_k<false, true><<<blocks, 256, 0, stream>>>(X, outf, sc, sh, C, t8);
    else
      bn_apply_k<true, false><<<blocks, 256, 0, stream>>>(X, X, sc, sh, C, t8);
  };
  auto mfma_conv = [&](int K, const unsigned short* in, const unsigned short* wt,
                       unsigned short* out, int Ci, int Hi, int Ho, int Co_pad, int Co_real) {
    int NPIX = N * Ho * Ho;
    dim3 g((unsigned)((NPIX + 127) / 128), (unsigned)(Co_pad / 128));
    if (K == 5)
      conv_mfma<5><<<g, 256, 0, stream>>>(in, wt, out, Ci, Hi, Hi, Ho, Ho, Co_pad, Co_real, NPIX);
    else
      conv_mfma<3><<<g, 256, 0, stream>>>(in, wt, out, Ci, Hi, Hi, Ho, Ho, Co_pad, Co_real, NPIX);
  };

  auto run_branch = [&](const unsigned short* inh, int Hin, float* Oout) {
    int H1 = (Hin - 11) / 2 + 1;
    int P1 = (H1 - 3) / 2 + 1;
    int H2 = P1 - 4;
    int P2 = (H2 - 3) / 2 + 1;
    int H3 = P2 - 2, H4 = P2 - 4, H5 = P2 - 6;
    // conv1 (MFMA) -> P
    int NPIX1 = N * H1 * H1;
    conv1_mfma<<<(unsigned)((NPIX1 + 127) / 128), 256, 0, stream>>>(
        inh, W1h, P, Hin, Hin, H1, H1, NPIX1);
    stats_apply(P, 96, (long)N * H1 * H1, bg[0], bb[0], true, nullptr);
    // pool1 -> R
    long pt1 = (long)N * P1 * P1 * 96 / 8;
    pool_k<<<(unsigned)((pt1 + 255) / 256), 256, 0, stream>>>(P, R, 12, H1, H1, P1, P1, pt1);
    // conv2 -> P
    mfma_conv(5, R, W2, P, 96, P1, H2, 256, 256);
    stats_apply(P, 256, (long)N * H2 * H2, bg[1], bb[1], true, nullptr);
    // pool2 -> R
    long pt2 = (long)N * P2 * P2 * 256 / 8;
    pool_k<<<(unsigned)((pt2 + 255) / 256), 256, 0, stream>>>(P, R, 32, H2, H2, P2, P2, pt2);
    // conv3 -> P
    mfma_conv(3, R, W3, P, 256, P2, H3, 256, 192);
    stats_apply(P, 192, (long)N * H3 * H3, bg[2], bb[2], true, nullptr);
    // conv4 -> Q
    mfma_conv(3, P, W4, Q, 192, H3, H4, 256, 192);
    stats_apply(Q, 192, (long)N * H4 * H4, bg[3], bb[3], true, nullptr);
    // conv5 -> P
    mfma_conv(3, Q, W5, P, 192, H4, H5, 128, 128);
    stats_apply(P, 128, (long)N * H5 * H5, bg[4], bb[4], false, Oout);
  };

  run_branch(I1h, 255, O1);
  run_branch(I2h, 127, O2);

  xcorr_k<<<289, 256, 0, stream>>>(O1, O2, corr);
  bcast_out<<<(9248 + 255) / 256, 256, 0, stream>>>(corr, (float*)d_out, 9248);
}

// Round 6
// 1116.751 us; speedup vs baseline: 2.6859x; 2.6859x over previous
//
#include <hip/hip_runtime.h>
#include <hip/hip_bf16.h>
#include <cstdint>
#include <cstddef>

typedef __attribute__((ext_vector_type(8))) _Float16 f16x8;
typedef __attribute__((ext_vector_type(4))) float f32x4;

__device__ __forceinline__ float h2f(unsigned short u) {
  union { unsigned short s; _Float16 h; } x; x.s = u; return (float)x.h;
}
__device__ __forceinline__ unsigned short f2h(float f) {
  union { unsigned short s; _Float16 h; } x; x.h = (_Float16)f; return x.s;
}
__device__ __forceinline__ void gload_lds16(const void* g, void* l) {
  __builtin_amdgcn_global_load_lds((const __attribute__((address_space(1))) unsigned int*)g,
                                   (__attribute__((address_space(3))) unsigned int*)l, 16, 0, 0);
}

// ============ input transform: fp32 NCHW [N,3,H,W] -> fp16 [N,H,W,4] (c3=0) ============
__global__ void in_transform(const float* __restrict__ in, unsigned short* __restrict__ out,
                             int HW, int total) {
  int i = blockIdx.x * 256 + threadIdx.x;
  if (i >= total) return;
  int n = i / HW;
  int r = i - n * HW;
  const float* p = in + (long)n * 3 * HW + r;
  uint2 v;
  v.x = (unsigned)f2h(p[0]) | ((unsigned)f2h(p[HW]) << 16);
  v.y = (unsigned)f2h(p[2 * HW]);
  ((uint2*)out)[i] = v;
}

// ============ conv1 weight transform: [96][3][11][11] fp32 -> [17][128][32] fp16 ============
__global__ void wt1_transform(const float* __restrict__ w, unsigned short* __restrict__ o,
                              int total) {
  int i = blockIdx.x * 256 + threadIdx.x;
  if (i >= total) return;
  int j = i & 31;
  int r = i >> 5;
  int co = r & 127;
  int kk = r >> 7;
  int run = kk * 4 + (j >> 3);
  int ky = run / 6;
  int e = (run - ky * 6) * 8 + (j & 7);
  int kx = e >> 2, c = e & 3;
  float v = 0.f;
  if (ky < 11 && kx < 11 && c < 3 && co < 96)
    v = w[((co * 3 + c) * 11 + ky) * 11 + kx];
  o[i] = f2h(v);
}

// ============ conv1 MFMA: fp16 [N,Hi,Wi,4] -> fp16 NHWC [N,Ho,Wo,96], K=11x11x3 s=2 ============
__global__ __launch_bounds__(256)
void conv1_mfma(const unsigned short* __restrict__ in, const unsigned short* __restrict__ wt,
                unsigned short* __restrict__ out, int Hi, int Wi, int Ho, int Wo, int NPIX) {
  __shared__ __align__(16) unsigned short sA[128 * 32];
  __shared__ __align__(16) unsigned short sB[128 * 32];
  __shared__ int sOB[128];
  const int t = threadIdx.x;
  const int px0 = blockIdx.x * 128;
  if (t < 128) {
    int g = px0 + t;
    int ob = -1;
    if (g < NPIX) {
      int n = g / (Ho * Wo);
      int r = g - n * Ho * Wo;
      int oy = r / Wo, ox = r - (r / Wo) * Wo;
      ob = ((n * Ho + oy) * Wo + ox) * 96;
    }
    sOB[t] = ob;
  }
  long rbase[2];
#pragma unroll
  for (int i = 0; i < 2; ++i) {
    int pxl = i * 64 + (t >> 2);
    int g = px0 + pxl;
    long rb = 0;
    if (g < NPIX) {
      int n = g / (Ho * Wo);
      int r = g - n * Ho * Wo;
      int oy = r / Wo, ox = r - (r / Wo) * Wo;
      rb = ((long)(n * Hi + 2 * oy) * Wi + 2 * ox) * 4;
    }
    rbase[i] = rb;
  }
  const int a4 = t & 3;
  f32x4 acc[4][4];
  f32x4 zz = {0.f, 0.f, 0.f, 0.f};
#pragma unroll
  for (int m = 0; m < 4; ++m)
#pragma unroll
    for (int n = 0; n < 4; ++n) acc[m][n] = zz;
  const int w = t >> 6;
  const int l = t & 63;
  const int wpx = (w & 1) * 64, wco = (w >> 1) * 64;
  const int arow = wpx + (l & 15);
  const int brow = wco + (l & 15);
  const int q8 = (l >> 4) * 8;
  const int W4 = Wi * 4;
  for (int kk = 0; kk < 17; ++kk) {
    int run = kk * 4 + a4;
    int ky = run / 6;
    int e0 = (run - ky * 6) * 8;
    long koff = (long)ky * W4 + e0;
    gload_lds16(in + rbase[0] + koff, &sA[t * 8]);
    gload_lds16(in + rbase[1] + koff, &sA[(256 + t) * 8]);
    const unsigned short* wp = wt + (long)kk * 4096;
    gload_lds16(wp + t * 8, &sB[t * 8]);
    gload_lds16(wp + 2048 + t * 8, &sB[(256 + t) * 8]);
    __syncthreads();
    f16x8 av[4], bv[4];
#pragma unroll
    for (int m = 0; m < 4; ++m) av[m] = *(const f16x8*)&sA[(arow + m * 16) * 32 + q8];
#pragma unroll
    for (int n = 0; n < 4; ++n) bv[n] = *(const f16x8*)&sB[(brow + n * 16) * 32 + q8];
#pragma unroll
    for (int m = 0; m < 4; ++m)
#pragma unroll
      for (int n = 0; n < 4; ++n)
        acc[m][n] = __builtin_amdgcn_mfma_f32_16x16x32_f16(av[m], bv[n], acc[m][n], 0, 0, 0);
    __syncthreads();
  }
#pragma unroll
  for (int m = 0; m < 4; ++m) {
#pragma unroll
    for (int r = 0; r < 4; ++r) {
      int pxl = wpx + m * 16 + (l >> 4) * 4 + r;
      int ob = sOB[pxl];
#pragma unroll
      for (int n = 0; n < 4; ++n) {
        int co = wco + n * 16 + (l & 15);
        if (ob >= 0 && co < 96) out[ob + co] = f2h(acc[m][n][r]);
      }
    }
  }
}

// ============ implicit-GEMM MFMA conv (stride 1, VALID), fp16 ============
template <int K>
__global__ __launch_bounds__(256)
void conv_mfma(const unsigned short* __restrict__ in, const unsigned short* __restrict__ wt,
               unsigned short* __restrict__ out,
               int Ci, int Hi, int Wi, int Ho, int Wo, int Co_pad, int Co_real, int NPIX) {
  __shared__ __align__(16) unsigned short sA[128 * 32];
  __shared__ __align__(16) unsigned short sB[128 * 32];
  __shared__ int sOB[128];
  const int t = threadIdx.x;
  const int px0 = blockIdx.x * 128;
  const int co0 = blockIdx.y * 128;
  if (t < 128) {
    int g = px0 + t;
    int ob = -1;
    if (g < NPIX) {
      int n = g / (Ho * Wo);
      int r = g - n * Ho * Wo;
      int oy = r / Wo, ox = r - (r / Wo) * Wo;
      ob = ((n * Ho + oy) * Wo + ox) * Co_real;
    }
    sOB[t] = ob;
  }
  long rbase[2];
#pragma unroll
  for (int i = 0; i < 2; ++i) {
    int pxl = i * 64 + (t >> 2);
    int g = px0 + pxl;
    long rb = 0;
    if (g < NPIX) {
      int n = g / (Ho * Wo);
      int r = g - n * Ho * Wo;
      int oy = r / Wo, ox = r - (r / Wo) * Wo;
      rb = ((long)(n * Hi + oy) * Wi + ox) * Ci;
    }
    rbase[i] = rb;
  }
  const int seg8 = (t & 3) * 8;
  const int colA = t >> 2;
  f32x4 acc[4][4];
  f32x4 zz = {0.f, 0.f, 0.f, 0.f};
#pragma unroll
  for (int m = 0; m < 4; ++m)
#pragma unroll
    for (int n = 0; n < 4; ++n) acc[m][n] = zz;
  const int w = t >> 6;
  const int l = t & 63;
  const int wpx = (w & 1) * 64, wco = (w >> 1) * 64;
  const int arow = wpx + (l & 15);
  const int brow = wco + (l & 15);
  const int q8 = (l >> 4) * 8;
  int ci0 = 0, kx = 0, ky = 0;
  const int NK = (Ci >> 5) * K * K;
  for (int kk = 0; kk < NK; ++kk) {
    long koff = (long)(ky * Wi + kx) * Ci + ci0 + seg8;
#pragma unroll
    for (int i = 0; i < 2; ++i)
      gload_lds16(in + rbase[i] + koff, &sA[(i * 256 + t) * 8]);
    long wbase = (long)((ky * K + kx) * Co_pad + co0) * Ci + ci0 + seg8;
#pragma unroll
    for (int i = 0; i < 2; ++i)
      gload_lds16(wt + wbase + (long)(i * 64 + colA) * Ci, &sB[(i * 256 + t) * 8]);
    __syncthreads();
    f16x8 av[4], bv[4];
#pragma unroll
    for (int m = 0; m < 4; ++m) av[m] = *(const f16x8*)&sA[(arow + m * 16) * 32 + q8];
#pragma unroll
    for (int n = 0; n < 4; ++n) bv[n] = *(const f16x8*)&sB[(brow + n * 16) * 32 + q8];
#pragma unroll
    for (int m = 0; m < 4; ++m)
#pragma unroll
      for (int n = 0; n < 4; ++n)
        acc[m][n] = __builtin_amdgcn_mfma_f32_16x16x32_f16(av[m], bv[n], acc[m][n], 0, 0, 0);
    __syncthreads();
    ci0 += 32;
    if (ci0 == Ci) { ci0 = 0; ++kx; if (kx == K) { kx = 0; ++ky; } }
  }
#pragma unroll
  for (int m = 0; m < 4; ++m) {
#pragma unroll
    for (int r = 0; r < 4; ++r) {
      int pxl = wpx + m * 16 + (l >> 4) * 4 + r;
      int ob = sOB[pxl];
#pragma unroll
      for (int n = 0; n < 4; ++n) {
        int co = co0 + wco + n * 16 + (l & 15);
        if (ob >= 0 && co < Co_real) out[ob + co] = f2h(acc[m][n][r]);
      }
    }
  }
}

// ============ weight transform: [Co][Ci][K][K] fp32 -> [K*K][Co_pad][Ci] fp16 ============
__global__ void wt_transform(const float* __restrict__ w, unsigned short* __restrict__ o,
                             int Co, int Co_pad, int Ci, int KK, long total) {
  long i = (long)blockIdx.x * blockDim.x + threadIdx.x;
  if (i >= total) return;
  int ci = (int)(i % Ci);
  long r = i / Ci;
  int co = (int)(r % Co_pad);
  int rk = (int)(r / Co_pad);
  float v = 0.f;
  if (co < Co) v = w[((long)co * Ci + ci) * KK + rk];
  o[i] = f2h(v);
}

// ============ BN stats: vectorized grid-stride partial sums ============
// requires blockDim*8 % C == 0 -> per-thread channel base is constant.
__global__ void bn_stats_part(const unsigned short* __restrict__ x, float* __restrict__ part,
                              int C, long total8) {
  const int t = threadIdx.x;
  const int G = C >> 3;           // uint4 column-groups per row
  float s[8], q[8];
#pragma unroll
  for (int j = 0; j < 8; ++j) { s[j] = 0.f; q[j] = 0.f; }
  long i = (long)blockIdx.x * blockDim.x + t;
  const long stride = (long)gridDim.x * blockDim.x;
  for (; i < total8; i += stride) {
    const uint4 v = ((const uint4*)x)[i];
    float f[8];
    f[0] = h2f((unsigned short)(v.x & 0xffff)); f[1] = h2f((unsigned short)(v.x >> 16));
    f[2] = h2f((unsigned short)(v.y & 0xffff)); f[3] = h2f((unsigned short)(v.y >> 16));
    f[4] = h2f((unsigned short)(v.z & 0xffff)); f[5] = h2f((unsigned short)(v.z >> 16));
    f[6] = h2f((unsigned short)(v.w & 0xffff)); f[7] = h2f((unsigned short)(v.w >> 16));
#pragma unroll
    for (int j = 0; j < 8; ++j) {
      s[j] += f[j];
      q[j] = fmaf(f[j], f[j], q[j]);
    }
  }
  __shared__ float ls[256][8];
  __shared__ float lq[256][8];
#pragma unroll
  for (int j = 0; j < 8; ++j) { ls[t][j] = s[j]; lq[t][j] = q[j]; }
  __syncthreads();
  // deterministic: thread u (< C) sums its channel across the K=blockDim/G owners
  if (t < C) {
    const int g = t >> 3, j = t & 7;
    const int Kc = blockDim.x / G;
    float ts = 0.f, tq = 0.f;
    for (int k = 0; k < Kc; ++k) {
      ts += ls[g + k * G][j];
      tq += lq[g + k * G][j];
    }
    part[((long)blockIdx.x * C + t) * 2] = ts;
    part[((long)blockIdx.x * C + t) * 2 + 1] = tq;
  }
}

// ============ BN finalize: one block per channel, deterministic tree ============
__global__ void bn_finalize(const float* __restrict__ part, const float* __restrict__ g,
                            const float* __restrict__ b, float* __restrict__ sc,
                            float* __restrict__ sh, int C, int nch, float cnt) {
  const int c = blockIdx.x;
  const int t = threadIdx.x;
  float s = 0.f, q = 0.f;
  for (int k = t; k < nch; k += 256) {
    s += part[((long)k * C + c) * 2];
    q += part[((long)k * C + c) * 2 + 1];
  }
  __shared__ float ss[256], qq[256];
  ss[t] = s; qq[t] = q;
  __syncthreads();
  for (int off = 128; off > 0; off >>= 1) {
    if (t < off) { ss[t] += ss[t + off]; qq[t] += qq[t + off]; }
    __syncthreads();
  }
  if (t == 0) {
    float m = ss[0] / cnt;
    float v = qq[0] / cnt - m * m;
    float r = rsqrtf(v + 1e-5f);
    float scl = r * g[c];
    sc[c] = scl;
    sh[c] = b[c] - m * scl;
  }
}

// ============ BN apply (8-wide, in place or fp16->fp32) ============
template <bool RELU, bool OUTF32>
__global__ void bn_apply_k(const unsigned short* __restrict__ x, void* __restrict__ y,
                           const float* __restrict__ sc, const float* __restrict__ sh,
                           int C, long total8) {
  long i = (long)blockIdx.x * blockDim.x + threadIdx.x;
  if (i >= total8) return;
  const uint4 v = ((const uint4*)x)[i];
  long base = i * 8;
  int c0 = (int)(base % C);
  const float4 s0 = *(const float4*)&sc[c0];
  const float4 s1 = *(const float4*)&sc[c0 + 4];
  const float4 h0 = *(const float4*)&sh[c0];
  const float4 h1 = *(const float4*)&sh[c0 + 4];
  float f[8];
  f[0] = h2f((unsigned short)(v.x & 0xffff)); f[1] = h2f((unsigned short)(v.x >> 16));
  f[2] = h2f((unsigned short)(v.y & 0xffff)); f[3] = h2f((unsigned short)(v.y >> 16));
  f[4] = h2f((unsigned short)(v.z & 0xffff)); f[5] = h2f((unsigned short)(v.z >> 16));
  f[6] = h2f((unsigned short)(v.w & 0xffff)); f[7] = h2f((unsigned short)(v.w >> 16));
  const float S[8] = {s0.x, s0.y, s0.z, s0.w, s1.x, s1.y, s1.z, s1.w};
  const float H[8] = {h0.x, h0.y, h0.z, h0.w, h1.x, h1.y, h1.z, h1.w};
#pragma unroll
  for (int j = 0; j < 8; ++j) {
    f[j] = fmaf(f[j], S[j], H[j]);
    if (RELU) f[j] = fmaxf(f[j], 0.f);
  }
  if (OUTF32) {
    float4 o0 = {f[0], f[1], f[2], f[3]}, o1 = {f[4], f[5], f[6], f[7]};
    ((float4*)y)[2 * i] = o0;
    ((float4*)y)[2 * i + 1] = o1;
  } else {
    uint4 o;
    o.x = (unsigned)f2h(f[0]) | ((unsigned)f2h(f[1]) << 16);
    o.y = (unsigned)f2h(f[2]) | ((unsigned)f2h(f[3]) << 16);
    o.z = (unsigned)f2h(f[4]) | ((unsigned)f2h(f[5]) << 16);
    o.w = (unsigned)f2h(f[6]) | ((unsigned)f2h(f[7]) << 16);
    ((uint4*)y)[i] = o;
  }
}

// ============ MaxPool 3x3 s2 (NHWC fp16), 8 channels/thread ============
__global__ void pool_k(const unsigned short* __restrict__ in, unsigned short* __restrict__ out,
                       int C8, int Hi, int Wi, int Ho, int Wo, long total8) {
  long i = (long)blockIdx.x * blockDim.x + threadIdx.x;
  if (i >= total8) return;
  int cg = (int)(i % C8);
  long r = i / C8;
  int ox = (int)(r % Wo);
  r /= Wo;
  int oy = (int)(r % Ho);
  int n = (int)(r / Ho);
  const uint4* bp = (const uint4*)in + ((long)(n * Hi + 2 * oy) * Wi + 2 * ox) * C8 + cg;
  float m[8];
#pragma unroll
  for (int j = 0; j < 8; ++j) m[j] = -3.4e38f;
#pragma unroll
  for (int dy = 0; dy < 3; ++dy)
#pragma unroll
    for (int dx = 0; dx < 3; ++dx) {
      const uint4 v = bp[((long)dy * Wi + dx) * C8];
      m[0] = fmaxf(m[0], h2f((unsigned short)(v.x & 0xffff)));
      m[1] = fmaxf(m[1], h2f((unsigned short)(v.x >> 16)));
      m[2] = fmaxf(m[2], h2f((unsigned short)(v.y & 0xffff)));
      m[3] = fmaxf(m[3], h2f((unsigned short)(v.y >> 16)));
      m[4] = fmaxf(m[4], h2f((unsigned short)(v.z & 0xffff)));
      m[5] = fmaxf(m[5], h2f((unsigned short)(v.z >> 16)));
      m[6] = fmaxf(m[6], h2f((unsigned short)(v.w & 0xffff)));
      m[7] = fmaxf(m[7], h2f((unsigned short)(v.w >> 16)));
    }
  uint4 o;
  o.x = (unsigned)f2h(m[0]) | ((unsigned)f2h(m[1]) << 16);
  o.y = (unsigned)f2h(m[2]) | ((unsigned)f2h(m[3]) << 16);
  o.z = (unsigned)f2h(m[4]) | ((unsigned)f2h(m[5]) << 16);
  o.w = (unsigned)f2h(m[6]) | ((unsigned)f2h(m[7]) << 16);
  ((uint4*)out)[i] = o;
}

// ============ cross-correlation (fp32, NHWC) ============
__global__ void xcorr_k(const float* __restrict__ o1, const float* __restrict__ o2,
                        float* __restrict__ corr) {
  const int p = blockIdx.x;
  const int oy = p / 17, ox = p - (p / 17) * 17;
  float acc = 0.f;
  for (int i = threadIdx.x; i < 147456; i += 256) {
    int c = i & 127;
    int r = i >> 7;
    int kx = r % 6;
    r /= 6;
    int ky = r % 6;
    int b = r / 6;
    acc = fmaf(o1[(((b * 22 + oy + ky) * 22) + ox + kx) * 128 + c], o2[i], acc);
  }
#pragma unroll
  for (int off = 32; off > 0; off >>= 1) acc += __shfl_down(acc, off, 64);
  __shared__ float sh[4];
  const int lane = threadIdx.x & 63, wid = threadIdx.x >> 6;
  if (lane == 0) sh[wid] = acc;
  __syncthreads();
  if (threadIdx.x == 0) {
    float tt = sh[0] + sh[1] + sh[2] + sh[3];
    corr[p] = tt * (1.f / 147456.f);
  }
}

__global__ void bcast_out(const float* __restrict__ corr, float* __restrict__ out, int total) {
  int i = blockIdx.x * blockDim.x + threadIdx.x;
  if (i < total) out[i] = corr[i % 289];
}

// ============ host ============
extern "C" void kernel_launch(void* const* d_in, const int* in_sizes, int n_in,
                              void* d_out, int out_size, void* d_ws, size_t ws_size,
                              hipStream_t stream) {
  (void)in_sizes; (void)n_in; (void)ws_size; (void)out_size;
  const float* input1 = (const float*)d_in[0];
  const float* input2 = (const float*)d_in[1];
  const float* cw[5];
  const float* bg[5];
  const float* bb[5];
  for (int i = 0; i < 5; ++i) {
    cw[i] = (const float*)d_in[2 + 2 * i];
    bg[i] = (const float*)d_in[12 + 2 * i];
    bb[i] = (const float*)d_in[13 + 2 * i];
  }
  char* p = (char*)d_ws;
  auto alloc = [&](size_t bytes) {
    char* r = p;
    p += (bytes + 255) & ~(size_t)255;
    return r;
  };
  unsigned short* P = (unsigned short*)alloc(93000000);
  unsigned short* Q = (unsigned short*)alloc(7200000);
  unsigned short* R = (unsigned short*)alloc(23000000);
  float* O1 = (float*)alloc(32l * 22 * 22 * 128 * 4);
  float* O2 = (float*)alloc(32l * 6 * 6 * 128 * 4);
  unsigned short* I1h = (unsigned short*)alloc(32l * 255 * 255 * 4 * 2 + 16384);
  unsigned short* I2h = (unsigned short*)alloc(32l * 127 * 127 * 4 * 2 + 16384);
  unsigned short* W1h = (unsigned short*)alloc(17l * 128 * 32 * 2);
  unsigned short* W2 = (unsigned short*)alloc(25l * 256 * 96 * 2);
  unsigned short* W3 = (unsigned short*)alloc(9l * 256 * 256 * 2);
  unsigned short* W4 = (unsigned short*)alloc(9l * 256 * 192 * 2);
  unsigned short* W5 = (unsigned short*)alloc(9l * 128 * 192 * 2);
  float* part = (float*)alloc(1024l * 256 * 2 * 4);
  float* sc = (float*)alloc(256 * 4);
  float* sh = (float*)alloc(256 * 4);
  float* corr = (float*)alloc(289 * 4);

  // weight + input transforms
  {
    int t1 = 17 * 128 * 32;
    wt1_transform<<<(unsigned)((t1 + 255) / 256), 256, 0, stream>>>(cw[0], W1h, t1);
    long t2 = 25l * 256 * 96;
    wt_transform<<<(unsigned)((t2 + 255) / 256), 256, 0, stream>>>(cw[1], W2, 256, 256, 96, 25, t2);
    long t3 = 9l * 256 * 256;
    wt_transform<<<(unsigned)((t3 + 255) / 256), 256, 0, stream>>>(cw[2], W3, 192, 256, 256, 9, t3);
    long t4 = 9l * 256 * 192;
    wt_transform<<<(unsigned)((t4 + 255) / 256), 256, 0, stream>>>(cw[3], W4, 192, 256, 192, 9, t4);
    long t5 = 9l * 128 * 192;
    wt_transform<<<(unsigned)((t5 + 255) / 256), 256, 0, stream>>>(cw[4], W5, 128, 128, 192, 9, t5);
    int p1 = 32 * 255 * 255;
    in_transform<<<(unsigned)((p1 + 255) / 256), 256, 0, stream>>>(input1, I1h, 255 * 255, p1);
    int p2 = 32 * 127 * 127;
    in_transform<<<(unsigned)((p2 + 255) / 256), 256, 0, stream>>>(input2, I2h, 127 * 127, p2);
  }

  const int N = 32;
  auto stats_apply = [&](unsigned short* X, int C, long NP, const float* g, const float* b,
                         bool relu, float* outf) {
    long t8 = NP * C / 8;
    int bd = (C == 96 || C == 192) ? 192 : 256;
    int nb = (int)((t8 + bd - 1) / bd);
    if (nb > 1024) nb = 1024;
    if (nb < 1) nb = 1;
    bn_stats_part<<<nb, bd, 0, stream>>>(X, part, C, t8);
    bn_finalize<<<C, 256, 0, stream>>>(part, g, b, sc, sh, C, nb, (float)NP);
    unsigned blocks = (unsigned)((t8 + 255) / 256);
    if (outf)
      bn_apply_k<false, true><<<blocks, 256, 0, stream>>>(X, outf, sc, sh, C, t8);
    else
      bn_apply_k<true, false><<<blocks, 256, 0, stream>>>(X, X, sc, sh, C, t8);
  };
  auto mfma_conv = [&](int K, const unsigned short* in, const unsigned short* wt,
                       unsigned short* out, int Ci, int Hi, int Ho, int Co_pad, int Co_real) {
    int NPIX = N * Ho * Ho;
    dim3 g((unsigned)((NPIX + 127) / 128), (unsigned)(Co_pad / 128));
    if (K == 5)
      conv_mfma<5><<<g, 256, 0, stream>>>(in, wt, out, Ci, Hi, Hi, Ho, Ho, Co_pad, Co_real, NPIX);
    else
      conv_mfma<3><<<g, 256, 0, stream>>>(in, wt, out, Ci, Hi, Hi, Ho, Ho, Co_pad, Co_real, NPIX);
  };

  auto run_branch = [&](const unsigned short* inh, int Hin, float* Oout) {
    int H1 = (Hin - 11) / 2 + 1;
    int P1 = (H1 - 3) / 2 + 1;
    int H2 = P1 - 4;
    int P2 = (H2 - 3) / 2 + 1;
    int H3 = P2 - 2, H4 = P2 - 4, H5 = P2 - 6;
    // conv1 (MFMA) -> P
    int NPIX1 = N * H1 * H1;
    conv1_mfma<<<(unsigned)((NPIX1 + 127) / 128), 256, 0, stream>>>(
        inh, W1h, P, Hin, Hin, H1, H1, NPIX1);
    stats_apply(P, 96, (long)N * H1 * H1, bg[0], bb[0], true, nullptr);
    // pool1 -> R
    long pt1 = (long)N * P1 * P1 * 96 / 8;
    pool_k<<<(unsigned)((pt1 + 255) / 256), 256, 0, stream>>>(P, R, 12, H1, H1, P1, P1, pt1);
    // conv2 -> P
    mfma_conv(5, R, W2, P, 96, P1, H2, 256, 256);
    stats_apply(P, 256, (long)N * H2 * H2, bg[1], bb[1], true, nullptr);
    // pool2 -> R
    long pt2 = (long)N * P2 * P2 * 256 / 8;
    pool_k<<<(unsigned)((pt2 + 255) / 256), 256, 0, stream>>>(P, R, 32, H2, H2, P2, P2, pt2);
    // conv3 -> P
    mfma_conv(3, R, W3, P, 256, P2, H3, 256, 192);
    stats_apply(P, 192, (long)N * H3 * H3, bg[2], bb[2], true, nullptr);
    // conv4 -> Q
    mfma_conv(3, P, W4, Q, 192, H3, H4, 256, 192);
    stats_apply(Q, 192, (long)N * H4 * H4, bg[3], bb[3], true, nullptr);
    // conv5 -> P
    mfma_conv(3, Q, W5, P, 192, H4, H5, 128, 128);
    stats_apply(P, 128, (long)N * H5 * H5, bg[4], bb[4], false, Oout);
  };

  run_branch(I1h, 255, O1);
  run_branch(I2h, 127, O2);

  xcorr_k<<<289, 256, 0, stream>>>(O1, O2, corr);
  bcast_out<<<(9248 + 255) / 256, 256, 0, stream>>>(corr, (float*)d_out, 9248);
}

// Round 7
// 833.675 us; speedup vs baseline: 3.5979x; 1.3396x over previous
//
#include <hip/hip_runtime.h>
#include <hip/hip_bf16.h>
#include <cstdint>
#include <cstddef>

typedef __attribute__((ext_vector_type(8))) _Float16 f16x8;
typedef __attribute__((ext_vector_type(4))) float f32x4;

__device__ __forceinline__ float h2f(unsigned short u) {
  union { unsigned short s; _Float16 h; } x; x.s = u; return (float)x.h;
}
__device__ __forceinline__ unsigned short f2h(float f) {
  union { unsigned short s; _Float16 h; } x; x.h = (_Float16)f; return x.s;
}
__device__ __forceinline__ void gload_lds16(const void* g, void* l) {
  __builtin_amdgcn_global_load_lds((const __attribute__((address_space(1))) unsigned int*)g,
                                   (__attribute__((address_space(3))) unsigned int*)l, 16, 0, 0);
}

// ============ input transform: fp32 NCHW [N,3,H,W] -> fp16 [N,H,W,4] (c3=0) ============
__global__ void in_transform(const float* __restrict__ in, unsigned short* __restrict__ out,
                             int HW, int total) {
  int i = blockIdx.x * 256 + threadIdx.x;
  if (i >= total) return;
  int n = i / HW;
  int r = i - n * HW;
  const float* p = in + (long)n * 3 * HW + r;
  uint2 v;
  v.x = (unsigned)f2h(p[0]) | ((unsigned)f2h(p[HW]) << 16);
  v.y = (unsigned)f2h(p[2 * HW]);
  ((uint2*)out)[i] = v;
}

// ============ conv1 weight transform: [96][3][11][11] fp32 -> [17][128][32] fp16 ============
__global__ void wt1_transform(const float* __restrict__ w, unsigned short* __restrict__ o,
                              int total) {
  int i = blockIdx.x * 256 + threadIdx.x;
  if (i >= total) return;
  int j = i & 31;
  int r = i >> 5;
  int co = r & 127;
  int kk = r >> 7;
  int run = kk * 4 + (j >> 3);
  int ky = run / 6;
  int e = (run - ky * 6) * 8 + (j & 7);
  int kx = e >> 2, c = e & 3;
  float v = 0.f;
  if (ky < 11 && kx < 11 && c < 3 && co < 96)
    v = w[((co * 3 + c) * 11 + ky) * 11 + kx];
  o[i] = f2h(v);
}

// ============ conv1 MFMA (double-buffered): fp16 [N,Hi,Wi,4] -> NHWC [N,Ho,Wo,96] ============
__global__ __launch_bounds__(256)
void conv1_mfma(const unsigned short* __restrict__ in, const unsigned short* __restrict__ wt,
                unsigned short* __restrict__ out, int Hi, int Wi, int Ho, int Wo, int NPIX) {
  __shared__ __align__(16) unsigned short sA[2][128 * 32];
  __shared__ __align__(16) unsigned short sB[2][128 * 32];
  __shared__ int sOB[128];
  const int t = threadIdx.x;
  const int px0 = blockIdx.x * 128;
  if (t < 128) {
    int g = px0 + t;
    int ob = -1;
    if (g < NPIX) {
      int n = g / (Ho * Wo);
      int r = g - n * Ho * Wo;
      int oy = r / Wo, ox = r - (r / Wo) * Wo;
      ob = ((n * Ho + oy) * Wo + ox) * 96;
    }
    sOB[t] = ob;
  }
  long rbase[2];
#pragma unroll
  for (int i = 0; i < 2; ++i) {
    int pxl = i * 64 + (t >> 2);
    int g = px0 + pxl;
    long rb = 0;
    if (g < NPIX) {
      int n = g / (Ho * Wo);
      int r = g - n * Ho * Wo;
      int oy = r / Wo, ox = r - (r / Wo) * Wo;
      rb = ((long)(n * Hi + 2 * oy) * Wi + 2 * ox) * 4;
    }
    rbase[i] = rb;
  }
  const int a4 = t & 3;
  const int W4 = Wi * 4;
  f32x4 acc[4][4];
  f32x4 zz = {0.f, 0.f, 0.f, 0.f};
#pragma unroll
  for (int m = 0; m < 4; ++m)
#pragma unroll
    for (int n = 0; n < 4; ++n) acc[m][n] = zz;
  const int w = t >> 6;
  const int l = t & 63;
  const int wpx = (w & 1) * 64, wco = (w >> 1) * 64;
  const int arow = wpx + (l & 15);
  const int brow = wco + (l & 15);
  const int q8 = (l >> 4) * 8;

  auto stage = [&](int buf, int kk) {
    int run = kk * 4 + a4;
    int ky = run / 6;
    int e0 = (run - ky * 6) * 8;
    long koff = (long)ky * W4 + e0;
    gload_lds16(in + rbase[0] + koff, &sA[buf][t * 8]);
    gload_lds16(in + rbase[1] + koff, &sA[buf][(256 + t) * 8]);
    const unsigned short* wp = wt + (long)kk * 4096;
    gload_lds16(wp + t * 8, &sB[buf][t * 8]);
    gload_lds16(wp + 2048 + t * 8, &sB[buf][(256 + t) * 8]);
  };

  stage(0, 0);
  __syncthreads();
  int cur = 0;
#pragma unroll 1
  for (int kk = 0; kk < 17; ++kk) {
    if (kk + 1 < 17) stage(cur ^ 1, kk + 1);
    f16x8 av[4], bv[4];
#pragma unroll
    for (int m = 0; m < 4; ++m) av[m] = *(const f16x8*)&sA[cur][(arow + m * 16) * 32 + q8];
#pragma unroll
    for (int n = 0; n < 4; ++n) bv[n] = *(const f16x8*)&sB[cur][(brow + n * 16) * 32 + q8];
#pragma unroll
    for (int m = 0; m < 4; ++m)
#pragma unroll
      for (int n = 0; n < 4; ++n)
        acc[m][n] = __builtin_amdgcn_mfma_f32_16x16x32_f16(av[m], bv[n], acc[m][n], 0, 0, 0);
    __syncthreads();
    cur ^= 1;
  }
#pragma unroll
  for (int m = 0; m < 4; ++m) {
#pragma unroll
    for (int r = 0; r < 4; ++r) {
      int pxl = wpx + m * 16 + (l >> 4) * 4 + r;
      int ob = sOB[pxl];
#pragma unroll
      for (int n = 0; n < 4; ++n) {
        int co = wco + n * 16 + (l & 15);
        if (ob >= 0 && co < 96) out[ob + co] = f2h(acc[m][n][r]);
      }
    }
  }
}

// ============ implicit-GEMM MFMA conv (stride 1, VALID), fp16, double-buffered ============
template <int K>
__global__ __launch_bounds__(256)
void conv_mfma(const unsigned short* __restrict__ in, const unsigned short* __restrict__ wt,
               unsigned short* __restrict__ out,
               int Ci, int Hi, int Wi, int Ho, int Wo, int Co_pad, int Co_real, int NPIX) {
  __shared__ __align__(16) unsigned short sA[2][128 * 32];
  __shared__ __align__(16) unsigned short sB[2][128 * 32];
  __shared__ int sOB[128];
  const int t = threadIdx.x;
  const int px0 = blockIdx.x * 128;
  const int co0 = blockIdx.y * 128;
  if (t < 128) {
    int g = px0 + t;
    int ob = -1;
    if (g < NPIX) {
      int n = g / (Ho * Wo);
      int r = g - n * Ho * Wo;
      int oy = r / Wo, ox = r - (r / Wo) * Wo;
      ob = ((n * Ho + oy) * Wo + ox) * Co_real;
    }
    sOB[t] = ob;
  }
  long rbase[2];
#pragma unroll
  for (int i = 0; i < 2; ++i) {
    int pxl = i * 64 + (t >> 2);
    int g = px0 + pxl;
    long rb = 0;
    if (g < NPIX) {
      int n = g / (Ho * Wo);
      int r = g - n * Ho * Wo;
      int oy = r / Wo, ox = r - (r / Wo) * Wo;
      rb = ((long)(n * Hi + oy) * Wi + ox) * Ci;
    }
    rbase[i] = rb;
  }
  const int seg8 = (t & 3) * 8;
  const int colA = t >> 2;
  f32x4 acc[4][4];
  f32x4 zz = {0.f, 0.f, 0.f, 0.f};
#pragma unroll
  for (int m = 0; m < 4; ++m)
#pragma unroll
    for (int n = 0; n < 4; ++n) acc[m][n] = zz;
  const int w = t >> 6;
  const int l = t & 63;
  const int wpx = (w & 1) * 64, wco = (w >> 1) * 64;
  const int arow = wpx + (l & 15);
  const int brow = wco + (l & 15);
  const int q8 = (l >> 4) * 8;
  int ci0 = 0, kx = 0, ky = 0;
  const int NK = (Ci >> 5) * K * K;

  auto stage = [&](int buf) {
    long koff = (long)(ky * Wi + kx) * Ci + ci0 + seg8;
    gload_lds16(in + rbase[0] + koff, &sA[buf][t * 8]);
    gload_lds16(in + rbase[1] + koff, &sA[buf][(256 + t) * 8]);
    long wbase = (long)((ky * K + kx) * Co_pad + co0) * Ci + ci0 + seg8;
    gload_lds16(wt + wbase + (long)colA * Ci, &sB[buf][t * 8]);
    gload_lds16(wt + wbase + (long)(64 + colA) * Ci, &sB[buf][(256 + t) * 8]);
    ci0 += 32;
    if (ci0 == Ci) { ci0 = 0; ++kx; if (kx == K) { kx = 0; ++ky; } }
  };

  stage(0);
  __syncthreads();
  int cur = 0;
#pragma unroll 1
  for (int kk = 0; kk < NK; ++kk) {
    if (kk + 1 < NK) stage(cur ^ 1);
    f16x8 av[4], bv[4];
#pragma unroll
    for (int m = 0; m < 4; ++m) av[m] = *(const f16x8*)&sA[cur][(arow + m * 16) * 32 + q8];
#pragma unroll
    for (int n = 0; n < 4; ++n) bv[n] = *(const f16x8*)&sB[cur][(brow + n * 16) * 32 + q8];
#pragma unroll
    for (int m = 0; m < 4; ++m)
#pragma unroll
      for (int n = 0; n < 4; ++n)
        acc[m][n] = __builtin_amdgcn_mfma_f32_16x16x32_f16(av[m], bv[n], acc[m][n], 0, 0, 0);
    __syncthreads();
    cur ^= 1;
  }
#pragma unroll
  for (int m = 0; m < 4; ++m) {
#pragma unroll
    for (int r = 0; r < 4; ++r) {
      int pxl = wpx + m * 16 + (l >> 4) * 4 + r;
      int ob = sOB[pxl];
#pragma unroll
      for (int n = 0; n < 4; ++n) {
        int co = co0 + wco + n * 16 + (l & 15);
        if (ob >= 0 && co < Co_real) out[ob + co] = f2h(acc[m][n][r]);
      }
    }
  }
}

// ============ weight transform: [Co][Ci][K][K] fp32 -> [K*K][Co_pad][Ci] fp16 ============
__global__ void wt_transform(const float* __restrict__ w, unsigned short* __restrict__ o,
                             int Co, int Co_pad, int Ci, int KK, long total) {
  long i = (long)blockIdx.x * blockDim.x + threadIdx.x;
  if (i >= total) return;
  int ci = (int)(i % Ci);
  long r = i / Ci;
  int co = (int)(r % Co_pad);
  int rk = (int)(r / Co_pad);
  float v = 0.f;
  if (co < Co) v = w[((long)co * Ci + ci) * KK + rk];
  o[i] = f2h(v);
}

// ============ BN stats: vectorized grid-stride partial sums ============
__global__ void bn_stats_part(const unsigned short* __restrict__ x, float* __restrict__ part,
                              int C, long total8) {
  const int t = threadIdx.x;
  const int G = C >> 3;
  float s[8], q[8];
#pragma unroll
  for (int j = 0; j < 8; ++j) { s[j] = 0.f; q[j] = 0.f; }
  long i = (long)blockIdx.x * blockDim.x + t;
  const long stride = (long)gridDim.x * blockDim.x;
  for (; i < total8; i += stride) {
    const uint4 v = ((const uint4*)x)[i];
    float f[8];
    f[0] = h2f((unsigned short)(v.x & 0xffff)); f[1] = h2f((unsigned short)(v.x >> 16));
    f[2] = h2f((unsigned short)(v.y & 0xffff)); f[3] = h2f((unsigned short)(v.y >> 16));
    f[4] = h2f((unsigned short)(v.z & 0xffff)); f[5] = h2f((unsigned short)(v.z >> 16));
    f[6] = h2f((unsigned short)(v.w & 0xffff)); f[7] = h2f((unsigned short)(v.w >> 16));
#pragma unroll
    for (int j = 0; j < 8; ++j) {
      s[j] += f[j];
      q[j] = fmaf(f[j], f[j], q[j]);
    }
  }
  __shared__ float ls[256][8];
  __shared__ float lq[256][8];
#pragma unroll
  for (int j = 0; j < 8; ++j) { ls[t][j] = s[j]; lq[t][j] = q[j]; }
  __syncthreads();
  if (t < C) {
    const int g = t >> 3, j = t & 7;
    const int Kc = blockDim.x / G;
    float ts = 0.f, tq = 0.f;
    for (int k = 0; k < Kc; ++k) {
      ts += ls[g + k * G][j];
      tq += lq[g + k * G][j];
    }
    part[((long)blockIdx.x * C + t) * 2] = ts;
    part[((long)blockIdx.x * C + t) * 2 + 1] = tq;
  }
}

// ============ BN finalize: one block per channel, deterministic tree ============
__global__ void bn_finalize(const float* __restrict__ part, const float* __restrict__ g,
                            const float* __restrict__ b, float* __restrict__ sc,
                            float* __restrict__ sh, int C, int nch, float cnt) {
  const int c = blockIdx.x;
  const int t = threadIdx.x;
  float s = 0.f, q = 0.f;
  for (int k = t; k < nch; k += 256) {
    s += part[((long)k * C + c) * 2];
    q += part[((long)k * C + c) * 2 + 1];
  }
  __shared__ float ss[256], qq[256];
  ss[t] = s; qq[t] = q;
  __syncthreads();
  for (int off = 128; off > 0; off >>= 1) {
    if (t < off) { ss[t] += ss[t + off]; qq[t] += qq[t + off]; }
    __syncthreads();
  }
  if (t == 0) {
    float m = ss[0] / cnt;
    float v = qq[0] / cnt - m * m;
    float r = rsqrtf(v + 1e-5f);
    float scl = r * g[c];
    sc[c] = scl;
    sh[c] = b[c] - m * scl;
  }
}

// ============ BN apply (8-wide, in place or fp16->fp32) ============
template <bool RELU, bool OUTF32>
__global__ void bn_apply_k(const unsigned short* __restrict__ x, void* __restrict__ y,
                           const float* __restrict__ sc, const float* __restrict__ sh,
                           int C, long total8) {
  long i = (long)blockIdx.x * blockDim.x + threadIdx.x;
  if (i >= total8) return;
  const uint4 v = ((const uint4*)x)[i];
  long base = i * 8;
  int c0 = (int)(base % C);
  const float4 s0 = *(const float4*)&sc[c0];
  const float4 s1 = *(const float4*)&sc[c0 + 4];
  const float4 h0 = *(const float4*)&sh[c0];
  const float4 h1 = *(const float4*)&sh[c0 + 4];
  float f[8];
  f[0] = h2f((unsigned short)(v.x & 0xffff)); f[1] = h2f((unsigned short)(v.x >> 16));
  f[2] = h2f((unsigned short)(v.y & 0xffff)); f[3] = h2f((unsigned short)(v.y >> 16));
  f[4] = h2f((unsigned short)(v.z & 0xffff)); f[5] = h2f((unsigned short)(v.z >> 16));
  f[6] = h2f((unsigned short)(v.w & 0xffff)); f[7] = h2f((unsigned short)(v.w >> 16));
  const float S[8] = {s0.x, s0.y, s0.z, s0.w, s1.x, s1.y, s1.z, s1.w};
  const float H[8] = {h0.x, h0.y, h0.z, h0.w, h1.x, h1.y, h1.z, h1.w};
#pragma unroll
  for (int j = 0; j < 8; ++j) {
    f[j] = fmaf(f[j], S[j], H[j]);
    if (RELU) f[j] = fmaxf(f[j], 0.f);
  }
  if (OUTF32) {
    float4 o0 = {f[0], f[1], f[2], f[3]}, o1 = {f[4], f[5], f[6], f[7]};
    ((float4*)y)[2 * i] = o0;
    ((float4*)y)[2 * i + 1] = o1;
  } else {
    uint4 o;
    o.x = (unsigned)f2h(f[0]) | ((unsigned)f2h(f[1]) << 16);
    o.y = (unsigned)f2h(f[2]) | ((unsigned)f2h(f[3]) << 16);
    o.z = (unsigned)f2h(f[4]) | ((unsigned)f2h(f[5]) << 16);
    o.w = (unsigned)f2h(f[6]) | ((unsigned)f2h(f[7]) << 16);
    ((uint4*)y)[i] = o;
  }
}

// ============ fused BN+ReLU+MaxPool 3x3 s2 (NHWC fp16), 8 channels/thread ============
__global__ void bn_pool_k(const unsigned short* __restrict__ in, unsigned short* __restrict__ out,
                          const float* __restrict__ sc, const float* __restrict__ sh,
                          int C8, int Hi, int Wi, int Ho, int Wo, long total8) {
  long i = (long)blockIdx.x * blockDim.x + threadIdx.x;
  if (i >= total8) return;
  int cg = (int)(i % C8);
  long r = i / C8;
  int ox = (int)(r % Wo);
  r /= Wo;
  int oy = (int)(r % Ho);
  int n = (int)(r / Ho);
  const int c0 = cg * 8;
  const float4 s0 = *(const float4*)&sc[c0];
  const float4 s1 = *(const float4*)&sc[c0 + 4];
  const float4 h0 = *(const float4*)&sh[c0];
  const float4 h1 = *(const float4*)&sh[c0 + 4];
  const float S[8] = {s0.x, s0.y, s0.z, s0.w, s1.x, s1.y, s1.z, s1.w};
  const float H[8] = {h0.x, h0.y, h0.z, h0.w, h1.x, h1.y, h1.z, h1.w};
  const uint4* bp = (const uint4*)in + ((long)(n * Hi + 2 * oy) * Wi + 2 * ox) * C8 + cg;
  float m[8];
#pragma unroll
  for (int j = 0; j < 8; ++j) m[j] = -3.4e38f;
#pragma unroll
  for (int dy = 0; dy < 3; ++dy)
#pragma unroll
    for (int dx = 0; dx < 3; ++dx) {
      const uint4 v = bp[((long)dy * Wi + dx) * C8];
      float f[8];
      f[0] = h2f((unsigned short)(v.x & 0xffff)); f[1] = h2f((unsigned short)(v.x >> 16));
      f[2] = h2f((unsigned short)(v.y & 0xffff)); f[3] = h2f((unsigned short)(v.y >> 16));
      f[4] = h2f((unsigned short)(v.z & 0xffff)); f[5] = h2f((unsigned short)(v.z >> 16));
      f[6] = h2f((unsigned short)(v.w & 0xffff)); f[7] = h2f((unsigned short)(v.w >> 16));
#pragma unroll
      for (int j = 0; j < 8; ++j) {
        f[j] = fmaxf(fmaf(f[j], S[j], H[j]), 0.f);
        m[j] = fmaxf(m[j], f[j]);
      }
    }
  uint4 o;
  o.x = (unsigned)f2h(m[0]) | ((unsigned)f2h(m[1]) << 16);
  o.y = (unsigned)f2h(m[2]) | ((unsigned)f2h(m[3]) << 16);
  o.z = (unsigned)f2h(m[4]) | ((unsigned)f2h(m[5]) << 16);
  o.w = (unsigned)f2h(m[6]) | ((unsigned)f2h(m[7]) << 16);
  ((uint4*)out)[i] = o;
}

// ============ cross-correlation partials: grid (289, 32) ============
__global__ void xcorr_part(const float* __restrict__ o1, const float* __restrict__ o2,
                           float* __restrict__ part) {
  const int p = blockIdx.x;
  const int b = blockIdx.y;
  const int oy = p / 17, ox = p - (p / 17) * 17;
  const float* o1b = o1 + (long)b * 22 * 22 * 128;
  const float* o2b = o2 + (long)b * 4608;
  float acc = 0.f;
  for (int i = threadIdx.x; i < 4608; i += 256) {
    int c = i & 127;
    int r = i >> 7;
    int kx = r % 6, ky = r / 6;
    acc = fmaf(o1b[((oy + ky) * 22 + ox + kx) * 128 + c], o2b[i], acc);
  }
#pragma unroll
  for (int off = 32; off > 0; off >>= 1) acc += __shfl_down(acc, off, 64);
  __shared__ float sh[4];
  const int lane = threadIdx.x & 63, wid = threadIdx.x >> 6;
  if (lane == 0) sh[wid] = acc;
  __syncthreads();
  if (threadIdx.x == 0) part[p * 32 + b] = sh[0] + sh[1] + sh[2] + sh[3];
}

// combine partials (fixed order) + broadcast to [32,1,17,17]
__global__ void xcorr_out(const float* __restrict__ part, float* __restrict__ out, int total) {
  int i = blockIdx.x * 256 + threadIdx.x;
  if (i >= total) return;
  int p = i % 289;
  float s = 0.f;
  for (int b = 0; b < 32; ++b) s += part[p * 32 + b];
  out[i] = s * (1.f / 147456.f);
}

// ============ host ============
extern "C" void kernel_launch(void* const* d_in, const int* in_sizes, int n_in,
                              void* d_out, int out_size, void* d_ws, size_t ws_size,
                              hipStream_t stream) {
  (void)in_sizes; (void)n_in; (void)ws_size; (void)out_size;
  const float* input1 = (const float*)d_in[0];
  const float* input2 = (const float*)d_in[1];
  const float* cw[5];
  const float* bg[5];
  const float* bb[5];
  for (int i = 0; i < 5; ++i) {
    cw[i] = (const float*)d_in[2 + 2 * i];
    bg[i] = (const float*)d_in[12 + 2 * i];
    bb[i] = (const float*)d_in[13 + 2 * i];
  }
  char* p = (char*)d_ws;
  auto alloc = [&](size_t bytes) {
    char* r = p;
    p += (bytes + 255) & ~(size_t)255;
    return r;
  };
  unsigned short* P = (unsigned short*)alloc(93000000);
  unsigned short* Q = (unsigned short*)alloc(7200000);
  unsigned short* R = (unsigned short*)alloc(23000000);
  float* O1 = (float*)alloc(32l * 22 * 22 * 128 * 4);
  float* O2 = (float*)alloc(32l * 6 * 6 * 128 * 4);
  unsigned short* I1h = (unsigned short*)alloc(32l * 255 * 255 * 4 * 2 + 16384);
  unsigned short* I2h = (unsigned short*)alloc(32l * 127 * 127 * 4 * 2 + 16384);
  unsigned short* W1h = (unsigned short*)alloc(17l * 128 * 32 * 2);
  unsigned short* W2 = (unsigned short*)alloc(25l * 256 * 96 * 2);
  unsigned short* W3 = (unsigned short*)alloc(9l * 256 * 256 * 2);
  unsigned short* W4 = (unsigned short*)alloc(9l * 256 * 192 * 2);
  unsigned short* W5 = (unsigned short*)alloc(9l * 128 * 192 * 2);
  float* part = (float*)alloc(1024l * 256 * 2 * 4);
  float* sc = (float*)alloc(256 * 4);
  float* sh = (float*)alloc(256 * 4);

  // weight + input transforms
  {
    int t1 = 17 * 128 * 32;
    wt1_transform<<<(unsigned)((t1 + 255) / 256), 256, 0, stream>>>(cw[0], W1h, t1);
    long t2 = 25l * 256 * 96;
    wt_transform<<<(unsigned)((t2 + 255) / 256), 256, 0, stream>>>(cw[1], W2, 256, 256, 96, 25, t2);
    long t3 = 9l * 256 * 256;
    wt_transform<<<(unsigned)((t3 + 255) / 256), 256, 0, stream>>>(cw[2], W3, 192, 256, 256, 9, t3);
    long t4 = 9l * 256 * 192;
    wt_transform<<<(unsigned)((t4 + 255) / 256), 256, 0, stream>>>(cw[3], W4, 192, 256, 192, 9, t4);
    long t5 = 9l * 128 * 192;
    wt_transform<<<(unsigned)((t5 + 255) / 256), 256, 0, stream>>>(cw[4], W5, 128, 128, 192, 9, t5);
    int p1 = 32 * 255 * 255;
    in_transform<<<(unsigned)((p1 + 255) / 256), 256, 0, stream>>>(input1, I1h, 255 * 255, p1);
    int p2 = 32 * 127 * 127;
    in_transform<<<(unsigned)((p2 + 255) / 256), 256, 0, stream>>>(input2, I2h, 127 * 127, p2);
  }

  const int N = 32;
  auto stats = [&](unsigned short* X, int C, long NP, const float* g, const float* b) {
    long t8 = NP * C / 8;
    int bd = (C == 96 || C == 192) ? 192 : 256;
    int nb = (int)((t8 + bd - 1) / bd);
    if (nb > 1024) nb = 1024;
    if (nb < 1) nb = 1;
    bn_stats_part<<<nb, bd, 0, stream>>>(X, part, C, t8);
    bn_finalize<<<C, 256, 0, stream>>>(part, g, b, sc, sh, C, nb, (float)NP);
  };
  auto apply = [&](unsigned short* X, int C, long NP, bool relu, float* outf) {
    long t8 = NP * C / 8;
    unsigned blocks = (unsigned)((t8 + 255) / 256);
    if (outf)
      bn_apply_k<false, true><<<blocks, 256, 0, stream>>>(X, outf, sc, sh, C, t8);
    else
      bn_apply_k<true, false><<<blocks, 256, 0, stream>>>(X, X, sc, sh, C, t8);
  };
  auto mfma_conv = [&](int K, const unsigned short* in, const unsigned short* wt,
                       unsigned short* out, int Ci, int Hi, int Ho, int Co_pad, int Co_real) {
    int NPIX = N * Ho * Ho;
    dim3 g((unsigned)((NPIX + 127) / 128), (unsigned)(Co_pad / 128));
    if (K == 5)
      conv_mfma<5><<<g, 256, 0, stream>>>(in, wt, out, Ci, Hi, Hi, Ho, Ho, Co_pad, Co_real, NPIX);
    else
      conv_mfma<3><<<g, 256, 0, stream>>>(in, wt, out, Ci, Hi, Hi, Ho, Ho, Co_pad, Co_real, NPIX);
  };

  auto run_branch = [&](const unsigned short* inh, int Hin, float* Oout) {
    int H1 = (Hin - 11) / 2 + 1;
    int P1 = (H1 - 3) / 2 + 1;
    int H2 = P1 - 4;
    int P2 = (H2 - 3) / 2 + 1;
    int H3 = P2 - 2, H4 = P2 - 4, H5 = P2 - 6;
    // conv1 (MFMA) -> P
    int NPIX1 = N * H1 * H1;
    conv1_mfma<<<(unsigned)((NPIX1 + 127) / 128), 256, 0, stream>>>(
        inh, W1h, P, Hin, Hin, H1, H1, NPIX1);
    stats(P, 96, (long)N * H1 * H1, bg[0], bb[0]);
    // fused bn+relu+pool1 -> R
    long pt1 = (long)N * P1 * P1 * 96 / 8;
    bn_pool_k<<<(unsigned)((pt1 + 255) / 256), 256, 0, stream>>>(P, R, sc, sh, 12, H1, H1, P1, P1, pt1);
    // conv2 -> P
    mfma_conv(5, R, W2, P, 96, P1, H2, 256, 256);
    stats(P, 256, (long)N * H2 * H2, bg[1], bb[1]);
    // fused bn+relu+pool2 -> R
    long pt2 = (long)N * P2 * P2 * 256 / 8;
    bn_pool_k<<<(unsigned)((pt2 + 255) / 256), 256, 0, stream>>>(P, R, sc, sh, 32, H2, H2, P2, P2, pt2);
    // conv3 -> P
    mfma_conv(3, R, W3, P, 256, P2, H3, 256, 192);
    stats(P, 192, (long)N * H3 * H3, bg[2], bb[2]);
    apply(P, 192, (long)N * H3 * H3, true, nullptr);
    // conv4 -> Q
    mfma_conv(3, P, W4, Q, 192, H3, H4, 256, 192);
    stats(Q, 192, (long)N * H4 * H4, bg[3], bb[3]);
    apply(Q, 192, (long)N * H4 * H4, true, nullptr);
    // conv5 -> P
    mfma_conv(3, Q, W5, P, 192, H4, H5, 128, 128);
    stats(P, 128, (long)N * H5 * H5, bg[4], bb[4]);
    apply(P, 128, (long)N * H5 * H5, false, Oout);
  };

  run_branch(I1h, 255, O1);
  run_branch(I2h, 127, O2);

  xcorr_part<<<dim3(289, 32), 256, 0, stream>>>(O1, O2, part);
  xcorr_out<<<(9248 + 255) / 256, 256, 0, stream>>>(part, (float*)d_out, 9248);
}

// Round 8
// 828.664 us; speedup vs baseline: 3.6197x; 1.0060x over previous
//
#include <hip/hip_runtime.h>
#include <hip/hip_bf16.h>
#include <cstdint>
#include <cstddef>

typedef __attribute__((ext_vector_type(8))) _Float16 f16x8;
typedef __attribute__((ext_vector_type(4))) float f32x4;

__device__ __forceinline__ float h2f(unsigned short u) {
  union { unsigned short s; _Float16 h; } x; x.s = u; return (float)x.h;
}
__device__ __forceinline__ unsigned short f2h(float f) {
  union { unsigned short s; _Float16 h; } x; x.h = (_Float16)f; return x.s;
}
__device__ __forceinline__ void gload_lds16(const void* g, void* l) {
  __builtin_amdgcn_global_load_lds((const __attribute__((address_space(1))) unsigned int*)g,
                                   (__attribute__((address_space(3))) unsigned int*)l, 16, 0, 0);
}

// ============ input transform: fp32 NCHW [N,3,H,W] -> fp16 [N,H,W,4] (c3=0) ============
__global__ void in_transform(const float* __restrict__ in, unsigned short* __restrict__ out,
                             int HW, int total) {
  int i = blockIdx.x * 256 + threadIdx.x;
  if (i >= total) return;
  int n = i / HW;
  int r = i - n * HW;
  const float* p = in + (long)n * 3 * HW + r;
  uint2 v;
  v.x = (unsigned)f2h(p[0]) | ((unsigned)f2h(p[HW]) << 16);
  v.y = (unsigned)f2h(p[2 * HW]);
  ((uint2*)out)[i] = v;
}

// ============ conv1 weight transform: [96][3][11][11] fp32 -> [17][128][32] fp16 ============
__global__ void wt1_transform(const float* __restrict__ w, unsigned short* __restrict__ o,
                              int total) {
  int i = blockIdx.x * 256 + threadIdx.x;
  if (i >= total) return;
  int j = i & 31;
  int r = i >> 5;
  int co = r & 127;
  int kk = r >> 7;
  int run = kk * 4 + (j >> 3);
  int ky = run / 6;
  int e = (run - ky * 6) * 8 + (j & 7);
  int kx = e >> 2, c = e & 3;
  float v = 0.f;
  if (ky < 11 && kx < 11 && c < 3 && co < 96)
    v = w[((co * 3 + c) * 11 + ky) * 11 + kx];
  o[i] = f2h(v);
}

// ============ conv1 MFMA (dbuf + fused stats): fp16 [N,Hi,Wi,4] -> NHWC [N,Ho,Wo,96] ============
__global__ __launch_bounds__(256)
void conv1_mfma(const unsigned short* __restrict__ in, const unsigned short* __restrict__ wt,
                unsigned short* __restrict__ out, float* __restrict__ part,
                int Hi, int Wi, int Ho, int Wo, int NPIX) {
  __shared__ __align__(16) unsigned short sA[2][128 * 32];
  __shared__ __align__(16) unsigned short sB[2][128 * 32];
  __shared__ int sOB[128];
  __shared__ float sRed[4][64][2];
  const int t = threadIdx.x;
  const int px0 = blockIdx.x * 128;
  if (t < 128) {
    int g = px0 + t;
    int ob = -1;
    if (g < NPIX) {
      int n = g / (Ho * Wo);
      int r = g - n * Ho * Wo;
      int oy = r / Wo, ox = r - (r / Wo) * Wo;
      ob = ((n * Ho + oy) * Wo + ox) * 96;
    }
    sOB[t] = ob;
  }
  long rbase[2];
#pragma unroll
  for (int i = 0; i < 2; ++i) {
    int pxl = i * 64 + (t >> 2);
    int g = px0 + pxl;
    long rb = 0;
    if (g < NPIX) {
      int n = g / (Ho * Wo);
      int r = g - n * Ho * Wo;
      int oy = r / Wo, ox = r - (r / Wo) * Wo;
      rb = ((long)(n * Hi + 2 * oy) * Wi + 2 * ox) * 4;
    }
    rbase[i] = rb;
  }
  const int a4 = t & 3;
  const int W4 = Wi * 4;
  f32x4 acc[4][4];
  f32x4 zz = {0.f, 0.f, 0.f, 0.f};
#pragma unroll
  for (int m = 0; m < 4; ++m)
#pragma unroll
    for (int n = 0; n < 4; ++n) acc[m][n] = zz;
  const int w = t >> 6;
  const int l = t & 63;
  const int wpx = (w & 1) * 64, wco = (w >> 1) * 64;
  const int arow = wpx + (l & 15);
  const int brow = wco + (l & 15);
  const int q8 = (l >> 4) * 8;

  auto stage = [&](int buf, int kk) {
    int run = kk * 4 + a4;
    int ky = run / 6;
    int e0 = (run - ky * 6) * 8;
    long koff = (long)ky * W4 + e0;
    gload_lds16(in + rbase[0] + koff, &sA[buf][t * 8]);
    gload_lds16(in + rbase[1] + koff, &sA[buf][(256 + t) * 8]);
    const unsigned short* wp = wt + (long)kk * 4096;
    gload_lds16(wp + t * 8, &sB[buf][t * 8]);
    gload_lds16(wp + 2048 + t * 8, &sB[buf][(256 + t) * 8]);
  };

  stage(0, 0);
  __syncthreads();
  int cur = 0;
#pragma unroll 1
  for (int kk = 0; kk < 17; ++kk) {
    if (kk + 1 < 17) stage(cur ^ 1, kk + 1);
    f16x8 av[4], bv[4];
#pragma unroll
    for (int m = 0; m < 4; ++m) av[m] = *(const f16x8*)&sA[cur][(arow + m * 16) * 32 + q8];
#pragma unroll
    for (int n = 0; n < 4; ++n) bv[n] = *(const f16x8*)&sB[cur][(brow + n * 16) * 32 + q8];
#pragma unroll
    for (int m = 0; m < 4; ++m)
#pragma unroll
      for (int n = 0; n < 4; ++n)
        acc[m][n] = __builtin_amdgcn_mfma_f32_16x16x32_f16(av[m], bv[n], acc[m][n], 0, 0, 0);
    __syncthreads();
    cur ^= 1;
  }
#pragma unroll
  for (int m = 0; m < 4; ++m) {
#pragma unroll
    for (int r = 0; r < 4; ++r) {
      int pxl = wpx + m * 16 + (l >> 4) * 4 + r;
      int ob = sOB[pxl];
#pragma unroll
      for (int n = 0; n < 4; ++n) {
        int co = wco + n * 16 + (l & 15);
        if (ob >= 0 && co < 96) out[ob + co] = f2h(acc[m][n][r]);
      }
    }
  }
  // fused BN-stat partials (per-channel sum & sumsq over valid px of this block)
  float sn[4], qn[4];
#pragma unroll
  for (int n = 0; n < 4; ++n) { sn[n] = 0.f; qn[n] = 0.f; }
#pragma unroll
  for (int m = 0; m < 4; ++m) {
#pragma unroll
    for (int r = 0; r < 4; ++r) {
      int pxl = wpx + m * 16 + (l >> 4) * 4 + r;
      float msk = (px0 + pxl < NPIX) ? 1.f : 0.f;
#pragma unroll
      for (int n = 0; n < 4; ++n) {
        float v = acc[m][n][r] * msk;
        sn[n] += v;
        qn[n] = fmaf(v, v, qn[n]);
      }
    }
  }
#pragma unroll
  for (int n = 0; n < 4; ++n) {
    sn[n] += __shfl_xor(sn[n], 16, 64);
    sn[n] += __shfl_xor(sn[n], 32, 64);
    qn[n] += __shfl_xor(qn[n], 16, 64);
    qn[n] += __shfl_xor(qn[n], 32, 64);
  }
  if (l < 16) {
#pragma unroll
    for (int n = 0; n < 4; ++n) {
      sRed[w][n * 16 + l][0] = sn[n];
      sRed[w][n * 16 + l][1] = qn[n];
    }
  }
  __syncthreads();
  if (t < 128) {
    int wb = (t >> 6) << 1;
    int cl = t & 63;
    float S = sRed[wb][cl][0] + sRed[wb + 1][cl][0];
    float Q = sRed[wb][cl][1] + sRed[wb + 1][cl][1];
    long idx = ((long)t * gridDim.x + blockIdx.x) * 2;
    part[idx] = S;
    part[idx + 1] = Q;
  }
}

// ============ implicit-GEMM MFMA conv (stride 1, VALID), fp16, dbuf + fused stats ============
template <int K>
__global__ __launch_bounds__(256)
void conv_mfma(const unsigned short* __restrict__ in, const unsigned short* __restrict__ wt,
               unsigned short* __restrict__ out, float* __restrict__ part,
               int Ci, int Hi, int Wi, int Ho, int Wo, int Co_pad, int Co_real, int NPIX) {
  __shared__ __align__(16) unsigned short sA[2][128 * 32];
  __shared__ __align__(16) unsigned short sB[2][128 * 32];
  __shared__ int sOB[128];
  __shared__ float sRed[4][64][2];
  const int t = threadIdx.x;
  const int px0 = blockIdx.x * 128;
  const int co0 = blockIdx.y * 128;
  if (t < 128) {
    int g = px0 + t;
    int ob = -1;
    if (g < NPIX) {
      int n = g / (Ho * Wo);
      int r = g - n * Ho * Wo;
      int oy = r / Wo, ox = r - (r / Wo) * Wo;
      ob = ((n * Ho + oy) * Wo + ox) * Co_real;
    }
    sOB[t] = ob;
  }
  long rbase[2];
#pragma unroll
  for (int i = 0; i < 2; ++i) {
    int pxl = i * 64 + (t >> 2);
    int g = px0 + pxl;
    long rb = 0;
    if (g < NPIX) {
      int n = g / (Ho * Wo);
      int r = g - n * Ho * Wo;
      int oy = r / Wo, ox = r - (r / Wo) * Wo;
      rb = ((long)(n * Hi + oy) * Wi + ox) * Ci;
    }
    rbase[i] = rb;
  }
  const int seg8 = (t & 3) * 8;
  const int colA = t >> 2;
  f32x4 acc[4][4];
  f32x4 zz = {0.f, 0.f, 0.f, 0.f};
#pragma unroll
  for (int m = 0; m < 4; ++m)
#pragma unroll
    for (int n = 0; n < 4; ++n) acc[m][n] = zz;
  const int w = t >> 6;
  const int l = t & 63;
  const int wpx = (w & 1) * 64, wco = (w >> 1) * 64;
  const int arow = wpx + (l & 15);
  const int brow = wco + (l & 15);
  const int q8 = (l >> 4) * 8;
  int ci0 = 0, kx = 0, ky = 0;
  const int NK = (Ci >> 5) * K * K;

  auto stage = [&](int buf) {
    long koff = (long)(ky * Wi + kx) * Ci + ci0 + seg8;
    gload_lds16(in + rbase[0] + koff, &sA[buf][t * 8]);
    gload_lds16(in + rbase[1] + koff, &sA[buf][(256 + t) * 8]);
    long wbase = (long)((ky * K + kx) * Co_pad + co0) * Ci + ci0 + seg8;
    gload_lds16(wt + wbase + (long)colA * Ci, &sB[buf][t * 8]);
    gload_lds16(wt + wbase + (long)(64 + colA) * Ci, &sB[buf][(256 + t) * 8]);
    ci0 += 32;
    if (ci0 == Ci) { ci0 = 0; ++kx; if (kx == K) { kx = 0; ++ky; } }
  };

  stage(0);
  __syncthreads();
  int cur = 0;
#pragma unroll 1
  for (int kk = 0; kk < NK; ++kk) {
    if (kk + 1 < NK) stage(cur ^ 1);
    f16x8 av[4], bv[4];
#pragma unroll
    for (int m = 0; m < 4; ++m) av[m] = *(const f16x8*)&sA[cur][(arow + m * 16) * 32 + q8];
#pragma unroll
    for (int n = 0; n < 4; ++n) bv[n] = *(const f16x8*)&sB[cur][(brow + n * 16) * 32 + q8];
#pragma unroll
    for (int m = 0; m < 4; ++m)
#pragma unroll
      for (int n = 0; n < 4; ++n)
        acc[m][n] = __builtin_amdgcn_mfma_f32_16x16x32_f16(av[m], bv[n], acc[m][n], 0, 0, 0);
    __syncthreads();
    cur ^= 1;
  }
#pragma unroll
  for (int m = 0; m < 4; ++m) {
#pragma unroll
    for (int r = 0; r < 4; ++r) {
      int pxl = wpx + m * 16 + (l >> 4) * 4 + r;
      int ob = sOB[pxl];
#pragma unroll
      for (int n = 0; n < 4; ++n) {
        int co = co0 + wco + n * 16 + (l & 15);
        if (ob >= 0 && co < Co_real) out[ob + co] = f2h(acc[m][n][r]);
      }
    }
  }
  // fused BN-stat partials
  float sn[4], qn[4];
#pragma unroll
  for (int n = 0; n < 4; ++n) { sn[n] = 0.f; qn[n] = 0.f; }
#pragma unroll
  for (int m = 0; m < 4; ++m) {
#pragma unroll
    for (int r = 0; r < 4; ++r) {
      int pxl = wpx + m * 16 + (l >> 4) * 4 + r;
      float msk = (px0 + pxl < NPIX) ? 1.f : 0.f;
#pragma unroll
      for (int n = 0; n < 4; ++n) {
        float v = acc[m][n][r] * msk;
        sn[n] += v;
        qn[n] = fmaf(v, v, qn[n]);
      }
    }
  }
#pragma unroll
  for (int n = 0; n < 4; ++n) {
    sn[n] += __shfl_xor(sn[n], 16, 64);
    sn[n] += __shfl_xor(sn[n], 32, 64);
    qn[n] += __shfl_xor(qn[n], 16, 64);
    qn[n] += __shfl_xor(qn[n], 32, 64);
  }
  if (l < 16) {
#pragma unroll
    for (int n = 0; n < 4; ++n) {
      sRed[w][n * 16 + l][0] = sn[n];
      sRed[w][n * 16 + l][1] = qn[n];
    }
  }
  __syncthreads();
  if (t < 128) {
    int wb = (t >> 6) << 1;
    int cl = t & 63;
    float S = sRed[wb][cl][0] + sRed[wb + 1][cl][0];
    float Q = sRed[wb][cl][1] + sRed[wb + 1][cl][1];
    long idx = ((long)(co0 + t) * gridDim.x + blockIdx.x) * 2;
    part[idx] = S;
    part[idx + 1] = Q;
  }
}

// ============ weight transform: [Co][Ci][K][K] fp32 -> [K*K][Co_pad][Ci] fp16 ============
__global__ void wt_transform(const float* __restrict__ w, unsigned short* __restrict__ o,
                             int Co, int Co_pad, int Ci, int KK, long total) {
  long i = (long)blockIdx.x * blockDim.x + threadIdx.x;
  if (i >= total) return;
  int ci = (int)(i % Ci);
  long r = i / Ci;
  int co = (int)(r % Co_pad);
  int rk = (int)(r / Co_pad);
  float v = 0.f;
  if (co < Co) v = w[((long)co * Ci + ci) * KK + rk];
  o[i] = f2h(v);
}

// ============ BN finalize: one block per channel, reduce NBX partials ============
__global__ void bn_finalize(const float* __restrict__ part, const float* __restrict__ g,
                            const float* __restrict__ b, float* __restrict__ sc,
                            float* __restrict__ sh, int NBX, float cnt) {
  const int c = blockIdx.x;
  const int t = threadIdx.x;
  float s = 0.f, q = 0.f;
  const float* pc = part + (long)c * NBX * 2;
  for (int k = t; k < NBX; k += 256) {
    s += pc[k * 2];
    q += pc[k * 2 + 1];
  }
  __shared__ float ss[256], qq[256];
  ss[t] = s; qq[t] = q;
  __syncthreads();
  for (int off = 128; off > 0; off >>= 1) {
    if (t < off) { ss[t] += ss[t + off]; qq[t] += qq[t + off]; }
    __syncthreads();
  }
  if (t == 0) {
    float m = ss[0] / cnt;
    float v = qq[0] / cnt - m * m;
    float r = rsqrtf(v + 1e-5f);
    float scl = r * g[c];
    sc[c] = scl;
    sh[c] = b[c] - m * scl;
  }
}

// ============ BN apply (8-wide, in place or fp16->fp32) ============
template <bool RELU, bool OUTF32>
__global__ void bn_apply_k(const unsigned short* __restrict__ x, void* __restrict__ y,
                           const float* __restrict__ sc, const float* __restrict__ sh,
                           int C, long total8) {
  long i = (long)blockIdx.x * blockDim.x + threadIdx.x;
  if (i >= total8) return;
  const uint4 v = ((const uint4*)x)[i];
  long base = i * 8;
  int c0 = (int)(base % C);
  const float4 s0 = *(const float4*)&sc[c0];
  const float4 s1 = *(const float4*)&sc[c0 + 4];
  const float4 h0 = *(const float4*)&sh[c0];
  const float4 h1 = *(const float4*)&sh[c0 + 4];
  float f[8];
  f[0] = h2f((unsigned short)(v.x & 0xffff)); f[1] = h2f((unsigned short)(v.x >> 16));
  f[2] = h2f((unsigned short)(v.y & 0xffff)); f[3] = h2f((unsigned short)(v.y >> 16));
  f[4] = h2f((unsigned short)(v.z & 0xffff)); f[5] = h2f((unsigned short)(v.z >> 16));
  f[6] = h2f((unsigned short)(v.w & 0xffff)); f[7] = h2f((unsigned short)(v.w >> 16));
  const float S[8] = {s0.x, s0.y, s0.z, s0.w, s1.x, s1.y, s1.z, s1.w};
  const float H[8] = {h0.x, h0.y, h0.z, h0.w, h1.x, h1.y, h1.z, h1.w};
#pragma unroll
  for (int j = 0; j < 8; ++j) {
    f[j] = fmaf(f[j], S[j], H[j]);
    if (RELU) f[j] = fmaxf(f[j], 0.f);
  }
  if (OUTF32) {
    float4 o0 = {f[0], f[1], f[2], f[3]}, o1 = {f[4], f[5], f[6], f[7]};
    ((float4*)y)[2 * i] = o0;
    ((float4*)y)[2 * i + 1] = o1;
  } else {
    uint4 o;
    o.x = (unsigned)f2h(f[0]) | ((unsigned)f2h(f[1]) << 16);
    o.y = (unsigned)f2h(f[2]) | ((unsigned)f2h(f[3]) << 16);
    o.z = (unsigned)f2h(f[4]) | ((unsigned)f2h(f[5]) << 16);
    o.w = (unsigned)f2h(f[6]) | ((unsigned)f2h(f[7]) << 16);
    ((uint4*)y)[i] = o;
  }
}

// ============ fused BN+ReLU+MaxPool 3x3 s2 (NHWC fp16), 8 channels/thread ============
__global__ void bn_pool_k(const unsigned short* __restrict__ in, unsigned short* __restrict__ out,
                          const float* __restrict__ sc, const float* __restrict__ sh,
                          int C8, int Hi, int Wi, int Ho, int Wo, long total8) {
  long i = (long)blockIdx.x * blockDim.x + threadIdx.x;
  if (i >= total8) return;
  int cg = (int)(i % C8);
  long r = i / C8;
  int ox = (int)(r % Wo);
  r /= Wo;
  int oy = (int)(r % Ho);
  int n = (int)(r / Ho);
  const int c0 = cg * 8;
  const float4 s0 = *(const float4*)&sc[c0];
  const float4 s1 = *(const float4*)&sc[c0 + 4];
  const float4 h0 = *(const float4*)&sh[c0];
  const float4 h1 = *(const float4*)&sh[c0 + 4];
  const float S[8] = {s0.x, s0.y, s0.z, s0.w, s1.x, s1.y, s1.z, s1.w};
  const float H[8] = {h0.x, h0.y, h0.z, h0.w, h1.x, h1.y, h1.z, h1.w};
  const uint4* bp = (const uint4*)in + ((long)(n * Hi + 2 * oy) * Wi + 2 * ox) * C8 + cg;
  float m[8];
#pragma unroll
  for (int j = 0; j < 8; ++j) m[j] = -3.4e38f;
#pragma unroll
  for (int dy = 0; dy < 3; ++dy)
#pragma unroll
    for (int dx = 0; dx < 3; ++dx) {
      const uint4 v = bp[((long)dy * Wi + dx) * C8];
      float f[8];
      f[0] = h2f((unsigned short)(v.x & 0xffff)); f[1] = h2f((unsigned short)(v.x >> 16));
      f[2] = h2f((unsigned short)(v.y & 0xffff)); f[3] = h2f((unsigned short)(v.y >> 16));
      f[4] = h2f((unsigned short)(v.z & 0xffff)); f[5] = h2f((unsigned short)(v.z >> 16));
      f[6] = h2f((unsigned short)(v.w & 0xffff)); f[7] = h2f((unsigned short)(v.w >> 16));
#pragma unroll
      for (int j = 0; j < 8; ++j) {
        f[j] = fmaxf(fmaf(f[j], S[j], H[j]), 0.f);
        m[j] = fmaxf(m[j], f[j]);
      }
    }
  uint4 o;
  o.x = (unsigned)f2h(m[0]) | ((unsigned)f2h(m[1]) << 16);
  o.y = (unsigned)f2h(m[2]) | ((unsigned)f2h(m[3]) << 16);
  o.z = (unsigned)f2h(m[4]) | ((unsigned)f2h(m[5]) << 16);
  o.w = (unsigned)f2h(m[6]) | ((unsigned)f2h(m[7]) << 16);
  ((uint4*)out)[i] = o;
}

// ============ cross-correlation partials: grid (289, 32) ============
__global__ void xcorr_part(const float* __restrict__ o1, const float* __restrict__ o2,
                           float* __restrict__ part) {
  const int p = blockIdx.x;
  const int b = blockIdx.y;
  const int oy = p / 17, ox = p - (p / 17) * 17;
  const float* o1b = o1 + (long)b * 22 * 22 * 128;
  const float* o2b = o2 + (long)b * 4608;
  float acc = 0.f;
  for (int i = threadIdx.x; i < 4608; i += 256) {
    int c = i & 127;
    int r = i >> 7;
    int kx = r % 6, ky = r / 6;
    acc = fmaf(o1b[((oy + ky) * 22 + ox + kx) * 128 + c], o2b[i], acc);
  }
#pragma unroll
  for (int off = 32; off > 0; off >>= 1) acc += __shfl_down(acc, off, 64);
  __shared__ float sh[4];
  const int lane = threadIdx.x & 63, wid = threadIdx.x >> 6;
  if (lane == 0) sh[wid] = acc;
  __syncthreads();
  if (threadIdx.x == 0) part[p * 32 + b] = sh[0] + sh[1] + sh[2] + sh[3];
}

// combine partials (fixed order) + broadcast to [32,1,17,17]
__global__ void xcorr_out(const float* __restrict__ part, float* __restrict__ out, int total) {
  int i = blockIdx.x * 256 + threadIdx.x;
  if (i >= total) return;
  int p = i % 289;
  float s = 0.f;
  for (int b = 0; b < 32; ++b) s += part[p * 32 + b];
  out[i] = s * (1.f / 147456.f);
}

// ============ host ============
extern "C" void kernel_launch(void* const* d_in, const int* in_sizes, int n_in,
                              void* d_out, int out_size, void* d_ws, size_t ws_size,
                              hipStream_t stream) {
  (void)in_sizes; (void)n_in; (void)ws_size; (void)out_size;
  const float* input1 = (const float*)d_in[0];
  const float* input2 = (const float*)d_in[1];
  const float* cw[5];
  const float* bg[5];
  const float* bb[5];
  for (int i = 0; i < 5; ++i) {
    cw[i] = (const float*)d_in[2 + 2 * i];
    bg[i] = (const float*)d_in[12 + 2 * i];
    bb[i] = (const float*)d_in[13 + 2 * i];
  }
  char* p = (char*)d_ws;
  auto alloc = [&](size_t bytes) {
    char* r = p;
    p += (bytes + 255) & ~(size_t)255;
    return r;
  };
  unsigned short* P = (unsigned short*)alloc(93000000);
  unsigned short* Q = (unsigned short*)alloc(7200000);
  unsigned short* R = (unsigned short*)alloc(23000000);
  float* O1 = (float*)alloc(32l * 22 * 22 * 128 * 4);
  float* O2 = (float*)alloc(32l * 6 * 6 * 128 * 4);
  unsigned short* I1h = (unsigned short*)alloc(32l * 255 * 255 * 4 * 2 + 16384);
  unsigned short* I2h = (unsigned short*)alloc(32l * 127 * 127 * 4 * 2 + 16384);
  unsigned short* W1h = (unsigned short*)alloc(17l * 128 * 32 * 2);
  unsigned short* W2 = (unsigned short*)alloc(25l * 256 * 96 * 2);
  unsigned short* W3 = (unsigned short*)alloc(9l * 256 * 256 * 2);
  unsigned short* W4 = (unsigned short*)alloc(9l * 256 * 192 * 2);
  unsigned short* W5 = (unsigned short*)alloc(9l * 128 * 192 * 2);
  float* part = (float*)alloc(8500000);   // stat partials: up to 128ch x 3784 blk x 2
  float* sc = (float*)alloc(256 * 4);
  float* sh = (float*)alloc(256 * 4);

  // weight + input transforms
  {
    int t1 = 17 * 128 * 32;
    wt1_transform<<<(unsigned)((t1 + 255) / 256), 256, 0, stream>>>(cw[0], W1h, t1);
    long t2 = 25l * 256 * 96;
    wt_transform<<<(unsigned)((t2 + 255) / 256), 256, 0, stream>>>(cw[1], W2, 256, 256, 96, 25, t2);
    long t3 = 9l * 256 * 256;
    wt_transform<<<(unsigned)((t3 + 255) / 256), 256, 0, stream>>>(cw[2], W3, 192, 256, 256, 9, t3);
    long t4 = 9l * 256 * 192;
    wt_transform<<<(unsigned)((t4 + 255) / 256), 256, 0, stream>>>(cw[3], W4, 192, 256, 192, 9, t4);
    long t5 = 9l * 128 * 192;
    wt_transform<<<(unsigned)((t5 + 255) / 256), 256, 0, stream>>>(cw[4], W5, 128, 128, 192, 9, t5);
    int p1 = 32 * 255 * 255;
    in_transform<<<(unsigned)((p1 + 255) / 256), 256, 0, stream>>>(input1, I1h, 255 * 255, p1);
    int p2 = 32 * 127 * 127;
    in_transform<<<(unsigned)((p2 + 255) / 256), 256, 0, stream>>>(input2, I2h, 127 * 127, p2);
  }

  const int N = 32;
  auto finalize = [&](int C, int NBX, long NP, const float* g, const float* b) {
    bn_finalize<<<C, 256, 0, stream>>>(part, g, b, sc, sh, NBX, (float)NP);
  };
  auto apply = [&](unsigned short* X, int C, long NP, bool relu, float* outf) {
    long t8 = NP * C / 8;
    unsigned blocks = (unsigned)((t8 + 255) / 256);
    if (outf)
      bn_apply_k<false, true><<<blocks, 256, 0, stream>>>(X, outf, sc, sh, C, t8);
    else
      bn_apply_k<true, false><<<blocks, 256, 0, stream>>>(X, X, sc, sh, C, t8);
  };
  auto mfma_conv = [&](int K, const unsigned short* in, const unsigned short* wt,
                       unsigned short* out, int Ci, int Hi, int Ho, int Co_pad, int Co_real) {
    int NPIX = N * Ho * Ho;
    dim3 g((unsigned)((NPIX + 127) / 128), (unsigned)(Co_pad / 128));
    if (K == 5)
      conv_mfma<5><<<g, 256, 0, stream>>>(in, wt, out, part, Ci, Hi, Hi, Ho, Ho, Co_pad, Co_real, NPIX);
    else
      conv_mfma<3><<<g, 256, 0, stream>>>(in, wt, out, part, Ci, Hi, Hi, Ho, Ho, Co_pad, Co_real, NPIX);
  };

  auto run_branch = [&](const unsigned short* inh, int Hin, float* Oout) {
    int H1 = (Hin - 11) / 2 + 1;
    int P1 = (H1 - 3) / 2 + 1;
    int H2 = P1 - 4;
    int P2 = (H2 - 3) / 2 + 1;
    int H3 = P2 - 2, H4 = P2 - 4, H5 = P2 - 6;
    // conv1 (MFMA, fused stats) -> P
    int NPIX1 = N * H1 * H1;
    int NBX1 = (NPIX1 + 127) / 128;
    conv1_mfma<<<(unsigned)NBX1, 256, 0, stream>>>(inh, W1h, P, part, Hin, Hin, H1, H1, NPIX1);
    finalize(96, NBX1, (long)N * H1 * H1, bg[0], bb[0]);
    // fused bn+relu+pool1 -> R
    long pt1 = (long)N * P1 * P1 * 96 / 8;
    bn_pool_k<<<(unsigned)((pt1 + 255) / 256), 256, 0, stream>>>(P, R, sc, sh, 12, H1, H1, P1, P1, pt1);
    // conv2 -> P
    mfma_conv(5, R, W2, P, 96, P1, H2, 256, 256);
    finalize(256, (N * H2 * H2 + 127) / 128, (long)N * H2 * H2, bg[1], bb[1]);
    // fused bn+relu+pool2 -> R
    long pt2 = (long)N * P2 * P2 * 256 / 8;
    bn_pool_k<<<(unsigned)((pt2 + 255) / 256), 256, 0, stream>>>(P, R, sc, sh, 32, H2, H2, P2, P2, pt2);
    // conv3 -> P
    mfma_conv(3, R, W3, P, 256, P2, H3, 256, 192);
    finalize(192, (N * H3 * H3 + 127) / 128, (long)N * H3 * H3, bg[2], bb[2]);
    apply(P, 192, (long)N * H3 * H3, true, nullptr);
    // conv4 -> Q
    mfma_conv(3, P, W4, Q, 192, H3, H4, 256, 192);
    finalize(192, (N * H4 * H4 + 127) / 128, (long)N * H4 * H4, bg[3], bb[3]);
    apply(Q, 192, (long)N * H4 * H4, true, nullptr);
    // conv5 -> P
    mfma_conv(3, Q, W5, P, 192, H4, H5, 128, 128);
    finalize(128, (N * H5 * H5 + 127) / 128, (long)N * H5 * H5, bg[4], bb[4]);
    apply(P, 128, (long)N * H5 * H5, false, Oout);
  };

  run_branch(I1h, 255, O1);
  run_branch(I2h, 127, O2);

  xcorr_part<<<dim3(289, 32), 256, 0, stream>>>(O1, O2, part);
  xcorr_out<<<(9248 + 255) / 256, 256, 0, stream>>>(part, (float*)d_out, 9248);
}

// Round 9
// 817.577 us; speedup vs baseline: 3.6688x; 1.0136x over previous
//
#include <hip/hip_runtime.h>
#include <hip/hip_bf16.h>
#include <cstdint>
#include <cstddef>

typedef __attribute__((ext_vector_type(8))) _Float16 f16x8;
typedef __attribute__((ext_vector_type(4))) float f32x4;

__device__ __forceinline__ float h2f(unsigned short u) {
  union { unsigned short s; _Float16 h; } x; x.s = u; return (float)x.h;
}
__device__ __forceinline__ unsigned short f2h(float f) {
  union { unsigned short s; _Float16 h; } x; x.h = (_Float16)f; return x.s;
}
__device__ __forceinline__ void gload_lds16(const void* g, void* l) {
  __builtin_amdgcn_global_load_lds((const __attribute__((address_space(1))) unsigned int*)g,
                                   (__attribute__((address_space(3))) unsigned int*)l, 16, 0, 0);
}

// ============ input transform: fp32 NCHW [N,3,H,W] -> fp16 [N,H,W,4] (c3=0) ============
__global__ void in_transform(const float* __restrict__ in, unsigned short* __restrict__ out,
                             int HW, int total) {
  int i = blockIdx.x * 256 + threadIdx.x;
  if (i >= total) return;
  int n = i / HW;
  int r = i - n * HW;
  const float* p = in + (long)n * 3 * HW + r;
  uint2 v;
  v.x = (unsigned)f2h(p[0]) | ((unsigned)f2h(p[HW]) << 16);
  v.y = (unsigned)f2h(p[2 * HW]);
  ((uint2*)out)[i] = v;
}

// ============ conv1 weight transform: [96][3][11][11] fp32 -> [17][128][32] fp16 ============
__global__ void wt1_transform(const float* __restrict__ w, unsigned short* __restrict__ o,
                              int total) {
  int i = blockIdx.x * 256 + threadIdx.x;
  if (i >= total) return;
  int j = i & 31;
  int r = i >> 5;
  int co = r & 127;
  int kk = r >> 7;
  int run = kk * 4 + (j >> 3);
  int ky = run / 6;
  int e = (run - ky * 6) * 8 + (j & 7);
  int kx = e >> 2, c = e & 3;
  float v = 0.f;
  if (ky < 11 && kx < 11 && c < 3 && co < 96)
    v = w[((co * 3 + c) * 11 + ky) * 11 + kx];
  o[i] = f2h(v);
}

// ============ conv1 MFMA (3-slot pipelined + fused stats) ============
__global__ __launch_bounds__(256)
void conv1_mfma(const unsigned short* __restrict__ in, const unsigned short* __restrict__ wt,
                unsigned short* __restrict__ out, float* __restrict__ part,
                int Hi, int Wi, int Ho, int Wo, int NPIX) {
  __shared__ __align__(16) unsigned short sA[3][128 * 32];
  __shared__ __align__(16) unsigned short sB[3][128 * 32];
  __shared__ int sOB[128];
  __shared__ float sRed[4][64][2];
  const int t = threadIdx.x;
  const int px0 = blockIdx.x * 128;
  if (t < 128) {
    int g = px0 + t;
    int ob = -1;
    if (g < NPIX) {
      int n = g / (Ho * Wo);
      int r = g - n * Ho * Wo;
      int oy = r / Wo, ox = r - (r / Wo) * Wo;
      ob = ((n * Ho + oy) * Wo + ox) * 96;
    }
    sOB[t] = ob;
  }
  long rbase[2];
#pragma unroll
  for (int i = 0; i < 2; ++i) {
    int pxl = i * 64 + (t >> 2);
    int g = px0 + pxl;
    long rb = 0;
    if (g < NPIX) {
      int n = g / (Ho * Wo);
      int r = g - n * Ho * Wo;
      int oy = r / Wo, ox = r - (r / Wo) * Wo;
      rb = ((long)(n * Hi + 2 * oy) * Wi + 2 * ox) * 4;
    }
    rbase[i] = rb;
  }
  const int a4 = t & 3;
  const int W4 = Wi * 4;
  f32x4 acc[4][4];
  f32x4 zz = {0.f, 0.f, 0.f, 0.f};
#pragma unroll
  for (int m = 0; m < 4; ++m)
#pragma unroll
    for (int n = 0; n < 4; ++n) acc[m][n] = zz;
  const int w = t >> 6;
  const int l = t & 63;
  const int wpx = (w & 1) * 64, wco = (w >> 1) * 64;
  const int arow = wpx + (l & 15);
  const int brow = wco + (l & 15);
  const int q8 = (l >> 4) * 8;

  auto stage = [&](int slot, int kk) {
    int run = kk * 4 + a4;
    int ky = run / 6;
    int e0 = (run - ky * 6) * 8;
    long koff = (long)ky * W4 + e0;
    gload_lds16(in + rbase[0] + koff, &sA[slot][t * 8]);
    gload_lds16(in + rbase[1] + koff, &sA[slot][(256 + t) * 8]);
    const unsigned short* wp = wt + (long)kk * 4096;
    gload_lds16(wp + t * 8, &sB[slot][t * 8]);
    gload_lds16(wp + 2048 + t * 8, &sB[slot][(256 + t) * 8]);
  };

  stage(0, 0);
  stage(1, 1);
  asm volatile("s_waitcnt vmcnt(4)" ::: "memory");
  __builtin_amdgcn_sched_barrier(0);
  __builtin_amdgcn_s_barrier();
  __builtin_amdgcn_sched_barrier(0);
  int cur = 0;
#pragma unroll 1
  for (int kk = 0; kk < 17; ++kk) {
    if (kk + 2 < 17) {
      int s2 = cur + 2;
      if (s2 >= 3) s2 -= 3;
      stage(s2, kk + 2);
    }
    f16x8 av[4], bv[4];
#pragma unroll
    for (int m = 0; m < 4; ++m) av[m] = *(const f16x8*)&sA[cur][(arow + m * 16) * 32 + q8];
#pragma unroll
    for (int n = 0; n < 4; ++n) bv[n] = *(const f16x8*)&sB[cur][(brow + n * 16) * 32 + q8];
#pragma unroll
    for (int m = 0; m < 4; ++m)
#pragma unroll
      for (int n = 0; n < 4; ++n)
        acc[m][n] = __builtin_amdgcn_mfma_f32_16x16x32_f16(av[m], bv[n], acc[m][n], 0, 0, 0);
    __builtin_amdgcn_sched_barrier(0);
    if (kk + 1 < 17) {
      if (kk + 2 < 17)
        asm volatile("s_waitcnt vmcnt(4)" ::: "memory");
      else
        asm volatile("s_waitcnt vmcnt(0)" ::: "memory");
    }
    __builtin_amdgcn_s_barrier();
    __builtin_amdgcn_sched_barrier(0);
    ++cur;
    if (cur == 3) cur = 0;
  }
#pragma unroll
  for (int m = 0; m < 4; ++m) {
#pragma unroll
    for (int r = 0; r < 4; ++r) {
      int pxl = wpx + m * 16 + (l >> 4) * 4 + r;
      int ob = sOB[pxl];
#pragma unroll
      for (int n = 0; n < 4; ++n) {
        int co = wco + n * 16 + (l & 15);
        if (ob >= 0 && co < 96) out[ob + co] = f2h(acc[m][n][r]);
      }
    }
  }
  float sn[4], qn[4];
#pragma unroll
  for (int n = 0; n < 4; ++n) { sn[n] = 0.f; qn[n] = 0.f; }
#pragma unroll
  for (int m = 0; m < 4; ++m) {
#pragma unroll
    for (int r = 0; r < 4; ++r) {
      int pxl = wpx + m * 16 + (l >> 4) * 4 + r;
      float msk = (px0 + pxl < NPIX) ? 1.f : 0.f;
#pragma unroll
      for (int n = 0; n < 4; ++n) {
        float v = acc[m][n][r] * msk;
        sn[n] += v;
        qn[n] = fmaf(v, v, qn[n]);
      }
    }
  }
#pragma unroll
  for (int n = 0; n < 4; ++n) {
    sn[n] += __shfl_xor(sn[n], 16, 64);
    sn[n] += __shfl_xor(sn[n], 32, 64);
    qn[n] += __shfl_xor(qn[n], 16, 64);
    qn[n] += __shfl_xor(qn[n], 32, 64);
  }
  if (l < 16) {
#pragma unroll
    for (int n = 0; n < 4; ++n) {
      sRed[w][n * 16 + l][0] = sn[n];
      sRed[w][n * 16 + l][1] = qn[n];
    }
  }
  __syncthreads();
  if (t < 128) {
    int wb = (t >> 6) << 1;
    int cl = t & 63;
    float S = sRed[wb][cl][0] + sRed[wb + 1][cl][0];
    float Q = sRed[wb][cl][1] + sRed[wb + 1][cl][1];
    long idx = ((long)t * gridDim.x + blockIdx.x) * 2;
    part[idx] = S;
    part[idx + 1] = Q;
  }
}

// ============ implicit-GEMM MFMA conv, 3-slot pipelined + fused stats ============
template <int K>
__global__ __launch_bounds__(256)
void conv_mfma(const unsigned short* __restrict__ in, const unsigned short* __restrict__ wt,
               unsigned short* __restrict__ out, float* __restrict__ part,
               int Ci, int Hi, int Wi, int Ho, int Wo, int Co_pad, int Co_real, int NPIX) {
  __shared__ __align__(16) unsigned short sA[3][128 * 32];
  __shared__ __align__(16) unsigned short sB[3][128 * 32];
  __shared__ int sOB[128];
  __shared__ float sRed[4][64][2];
  const int t = threadIdx.x;
  const int px0 = blockIdx.x * 128;
  const int co0 = blockIdx.y * 128;
  if (t < 128) {
    int g = px0 + t;
    int ob = -1;
    if (g < NPIX) {
      int n = g / (Ho * Wo);
      int r = g - n * Ho * Wo;
      int oy = r / Wo, ox = r - (r / Wo) * Wo;
      ob = ((n * Ho + oy) * Wo + ox) * Co_real;
    }
    sOB[t] = ob;
  }
  long rbase[2];
#pragma unroll
  for (int i = 0; i < 2; ++i) {
    int pxl = i * 64 + (t >> 2);
    int g = px0 + pxl;
    long rb = 0;
    if (g < NPIX) {
      int n = g / (Ho * Wo);
      int r = g - n * Ho * Wo;
      int oy = r / Wo, ox = r - (r / Wo) * Wo;
      rb = ((long)(n * Hi + oy) * Wi + ox) * Ci;
    }
    rbase[i] = rb;
  }
  const int seg8 = (t & 3) * 8;
  const int colA = t >> 2;
  f32x4 acc[4][4];
  f32x4 zz = {0.f, 0.f, 0.f, 0.f};
#pragma unroll
  for (int m = 0; m < 4; ++m)
#pragma unroll
    for (int n = 0; n < 4; ++n) acc[m][n] = zz;
  const int w = t >> 6;
  const int l = t & 63;
  const int wpx = (w & 1) * 64, wco = (w >> 1) * 64;
  const int arow = wpx + (l & 15);
  const int brow = wco + (l & 15);
  const int q8 = (l >> 4) * 8;
  int ci0 = 0, kx = 0, ky = 0;
  const int NK = (Ci >> 5) * K * K;

  auto stage = [&](int slot) {
    long koff = (long)(ky * Wi + kx) * Ci + ci0 + seg8;
    gload_lds16(in + rbase[0] + koff, &sA[slot][t * 8]);
    gload_lds16(in + rbase[1] + koff, &sA[slot][(256 + t) * 8]);
    long wbase = (long)((ky * K + kx) * Co_pad + co0) * Ci + ci0 + seg8;
    gload_lds16(wt + wbase + (long)colA * Ci, &sB[slot][t * 8]);
    gload_lds16(wt + wbase + (long)(64 + colA) * Ci, &sB[slot][(256 + t) * 8]);
    ci0 += 32;
    if (ci0 == Ci) { ci0 = 0; ++kx; if (kx == K) { kx = 0; ++ky; } }
  };

  stage(0);
  stage(1);
  asm volatile("s_waitcnt vmcnt(4)" ::: "memory");
  __builtin_amdgcn_sched_barrier(0);
  __builtin_amdgcn_s_barrier();
  __builtin_amdgcn_sched_barrier(0);
  int cur = 0;
#pragma unroll 1
  for (int kk = 0; kk < NK; ++kk) {
    if (kk + 2 < NK) {
      int s2 = cur + 2;
      if (s2 >= 3) s2 -= 3;
      stage(s2);
    }
    f16x8 av[4], bv[4];
#pragma unroll
    for (int m = 0; m < 4; ++m) av[m] = *(const f16x8*)&sA[cur][(arow + m * 16) * 32 + q8];
#pragma unroll
    for (int n = 0; n < 4; ++n) bv[n] = *(const f16x8*)&sB[cur][(brow + n * 16) * 32 + q8];
#pragma unroll
    for (int m = 0; m < 4; ++m)
#pragma unroll
      for (int n = 0; n < 4; ++n)
        acc[m][n] = __builtin_amdgcn_mfma_f32_16x16x32_f16(av[m], bv[n], acc[m][n], 0, 0, 0);
    __builtin_amdgcn_sched_barrier(0);
    if (kk + 1 < NK) {
      if (kk + 2 < NK)
        asm volatile("s_waitcnt vmcnt(4)" ::: "memory");
      else
        asm volatile("s_waitcnt vmcnt(0)" ::: "memory");
    }
    __builtin_amdgcn_s_barrier();
    __builtin_amdgcn_sched_barrier(0);
    ++cur;
    if (cur == 3) cur = 0;
  }
#pragma unroll
  for (int m = 0; m < 4; ++m) {
#pragma unroll
    for (int r = 0; r < 4; ++r) {
      int pxl = wpx + m * 16 + (l >> 4) * 4 + r;
      int ob = sOB[pxl];
#pragma unroll
      for (int n = 0; n < 4; ++n) {
        int co = co0 + wco + n * 16 + (l & 15);
        if (ob >= 0 && co < Co_real) out[ob + co] = f2h(acc[m][n][r]);
      }
    }
  }
  float sn[4], qn[4];
#pragma unroll
  for (int n = 0; n < 4; ++n) { sn[n] = 0.f; qn[n] = 0.f; }
#pragma unroll
  for (int m = 0; m < 4; ++m) {
#pragma unroll
    for (int r = 0; r < 4; ++r) {
      int pxl = wpx + m * 16 + (l >> 4) * 4 + r;
      float msk = (px0 + pxl < NPIX) ? 1.f : 0.f;
#pragma unroll
      for (int n = 0; n < 4; ++n) {
        float v = acc[m][n][r] * msk;
        sn[n] += v;
        qn[n] = fmaf(v, v, qn[n]);
      }
    }
  }
#pragma unroll
  for (int n = 0; n < 4; ++n) {
    sn[n] += __shfl_xor(sn[n], 16, 64);
    sn[n] += __shfl_xor(sn[n], 32, 64);
    qn[n] += __shfl_xor(qn[n], 16, 64);
    qn[n] += __shfl_xor(qn[n], 32, 64);
  }
  if (l < 16) {
#pragma unroll
    for (int n = 0; n < 4; ++n) {
      sRed[w][n * 16 + l][0] = sn[n];
      sRed[w][n * 16 + l][1] = qn[n];
    }
  }
  __syncthreads();
  if (t < 128) {
    int wb = (t >> 6) << 1;
    int cl = t & 63;
    float S = sRed[wb][cl][0] + sRed[wb + 1][cl][0];
    float Q = sRed[wb][cl][1] + sRed[wb + 1][cl][1];
    long idx = ((long)(co0 + t) * gridDim.x + blockIdx.x) * 2;
    part[idx] = S;
    part[idx + 1] = Q;
  }
}

// ============ weight transform: [Co][Ci][K][K] fp32 -> [K*K][Co_pad][Ci] fp16 ============
__global__ void wt_transform(const float* __restrict__ w, unsigned short* __restrict__ o,
                             int Co, int Co_pad, int Ci, int KK, long total) {
  long i = (long)blockIdx.x * blockDim.x + threadIdx.x;
  if (i >= total) return;
  int ci = (int)(i % Ci);
  long r = i / Ci;
  int co = (int)(r % Co_pad);
  int rk = (int)(r / Co_pad);
  float v = 0.f;
  if (co < Co) v = w[((long)co * Ci + ci) * KK + rk];
  o[i] = f2h(v);
}

// ============ BN finalize: one block per channel, reduce NBX partials ============
__global__ void bn_finalize(const float* __restrict__ part, const float* __restrict__ g,
                            const float* __restrict__ b, float* __restrict__ sc,
                            float* __restrict__ sh, int NBX, float cnt) {
  const int c = blockIdx.x;
  const int t = threadIdx.x;
  float s = 0.f, q = 0.f;
  const float* pc = part + (long)c * NBX * 2;
  for (int k = t; k < NBX; k += 256) {
    s += pc[k * 2];
    q += pc[k * 2 + 1];
  }
  __shared__ float ss[256], qq[256];
  ss[t] = s; qq[t] = q;
  __syncthreads();
  for (int off = 128; off > 0; off >>= 1) {
    if (t < off) { ss[t] += ss[t + off]; qq[t] += qq[t + off]; }
    __syncthreads();
  }
  if (t == 0) {
    float m = ss[0] / cnt;
    float v = qq[0] / cnt - m * m;
    float r = rsqrtf(v + 1e-5f);
    float scl = r * g[c];
    sc[c] = scl;
    sh[c] = b[c] - m * scl;
  }
}

// ============ BN apply (8-wide, in place or fp16->fp32) ============
template <bool RELU, bool OUTF32>
__global__ void bn_apply_k(const unsigned short* __restrict__ x, void* __restrict__ y,
                           const float* __restrict__ sc, const float* __restrict__ sh,
                           int C, long total8) {
  long i = (long)blockIdx.x * blockDim.x + threadIdx.x;
  if (i >= total8) return;
  const uint4 v = ((const uint4*)x)[i];
  long base = i * 8;
  int c0 = (int)(base % C);
  const float4 s0 = *(const float4*)&sc[c0];
  const float4 s1 = *(const float4*)&sc[c0 + 4];
  const float4 h0 = *(const float4*)&sh[c0];
  const float4 h1 = *(const float4*)&sh[c0 + 4];
  float f[8];
  f[0] = h2f((unsigned short)(v.x & 0xffff)); f[1] = h2f((unsigned short)(v.x >> 16));
  f[2] = h2f((unsigned short)(v.y & 0xffff)); f[3] = h2f((unsigned short)(v.y >> 16));
  f[4] = h2f((unsigned short)(v.z & 0xffff)); f[5] = h2f((unsigned short)(v.z >> 16));
  f[6] = h2f((unsigned short)(v.w & 0xffff)); f[7] = h2f((unsigned short)(v.w >> 16));
  const float S[8] = {s0.x, s0.y, s0.z, s0.w, s1.x, s1.y, s1.z, s1.w};
  const float H[8] = {h0.x, h0.y, h0.z, h0.w, h1.x, h1.y, h1.z, h1.w};
#pragma unroll
  for (int j = 0; j < 8; ++j) {
    f[j] = fmaf(f[j], S[j], H[j]);
    if (RELU) f[j] = fmaxf(f[j], 0.f);
  }
  if (OUTF32) {
    float4 o0 = {f[0], f[1], f[2], f[3]}, o1 = {f[4], f[5], f[6], f[7]};
    ((float4*)y)[2 * i] = o0;
    ((float4*)y)[2 * i + 1] = o1;
  } else {
    uint4 o;
    o.x = (unsigned)f2h(f[0]) | ((unsigned)f2h(f[1]) << 16);
    o.y = (unsigned)f2h(f[2]) | ((unsigned)f2h(f[3]) << 16);
    o.z = (unsigned)f2h(f[4]) | ((unsigned)f2h(f[5]) << 16);
    o.w = (unsigned)f2h(f[6]) | ((unsigned)f2h(f[7]) << 16);
    ((uint4*)y)[i] = o;
  }
}

// ============ fused BN+ReLU+MaxPool 3x3 s2 (NHWC fp16), 8 channels/thread ============
__global__ void bn_pool_k(const unsigned short* __restrict__ in, unsigned short* __restrict__ out,
                          const float* __restrict__ sc, const float* __restrict__ sh,
                          int C8, int Hi, int Wi, int Ho, int Wo, long total8) {
  long i = (long)blockIdx.x * blockDim.x + threadIdx.x;
  if (i >= total8) return;
  int cg = (int)(i % C8);
  long r = i / C8;
  int ox = (int)(r % Wo);
  r /= Wo;
  int oy = (int)(r % Ho);
  int n = (int)(r / Ho);
  const int c0 = cg * 8;
  const float4 s0 = *(const float4*)&sc[c0];
  const float4 s1 = *(const float4*)&sc[c0 + 4];
  const float4 h0 = *(const float4*)&sh[c0];
  const float4 h1 = *(const float4*)&sh[c0 + 4];
  const float S[8] = {s0.x, s0.y, s0.z, s0.w, s1.x, s1.y, s1.z, s1.w};
  const float H[8] = {h0.x, h0.y, h0.z, h0.w, h1.x, h1.y, h1.z, h1.w};
  const uint4* bp = (const uint4*)in + ((long)(n * Hi + 2 * oy) * Wi + 2 * ox) * C8 + cg;
  float m[8];
#pragma unroll
  for (int j = 0; j < 8; ++j) m[j] = -3.4e38f;
#pragma unroll
  for (int dy = 0; dy < 3; ++dy)
#pragma unroll
    for (int dx = 0; dx < 3; ++dx) {
      const uint4 v = bp[((long)dy * Wi + dx) * C8];
      float f[8];
      f[0] = h2f((unsigned short)(v.x & 0xffff)); f[1] = h2f((unsigned short)(v.x >> 16));
      f[2] = h2f((unsigned short)(v.y & 0xffff)); f[3] = h2f((unsigned short)(v.y >> 16));
      f[4] = h2f((unsigned short)(v.z & 0xffff)); f[5] = h2f((unsigned short)(v.z >> 16));
      f[6] = h2f((unsigned short)(v.w & 0xffff)); f[7] = h2f((unsigned short)(v.w >> 16));
#pragma unroll
      for (int j = 0; j < 8; ++j) {
        f[j] = fmaxf(fmaf(f[j], S[j], H[j]), 0.f);
        m[j] = fmaxf(m[j], f[j]);
      }
    }
  uint4 o;
  o.x = (unsigned)f2h(m[0]) | ((unsigned)f2h(m[1]) << 16);
  o.y = (unsigned)f2h(m[2]) | ((unsigned)f2h(m[3]) << 16);
  o.z = (unsigned)f2h(m[4]) | ((unsigned)f2h(m[5]) << 16);
  o.w = (unsigned)f2h(m[6]) | ((unsigned)f2h(m[7]) << 16);
  ((uint4*)out)[i] = o;
}

// ============ cross-correlation partials: grid (289, 32) ============
__global__ void xcorr_part(const float* __restrict__ o1, const float* __restrict__ o2,
                           float* __restrict__ part) {
  const int p = blockIdx.x;
  const int b = blockIdx.y;
  const int oy = p / 17, ox = p - (p / 17) * 17;
  const float* o1b = o1 + (long)b * 22 * 22 * 128;
  const float* o2b = o2 + (long)b * 4608;
  float acc = 0.f;
  for (int i = threadIdx.x; i < 4608; i += 256) {
    int c = i & 127;
    int r = i >> 7;
    int kx = r % 6, ky = r / 6;
    acc = fmaf(o1b[((oy + ky) * 22 + ox + kx) * 128 + c], o2b[i], acc);
  }
#pragma unroll
  for (int off = 32; off > 0; off >>= 1) acc += __shfl_down(acc, off, 64);
  __shared__ float sh[4];
  const int lane = threadIdx.x & 63, wid = threadIdx.x >> 6;
  if (lane == 0) sh[wid] = acc;
  __syncthreads();
  if (threadIdx.x == 0) part[p * 32 + b] = sh[0] + sh[1] + sh[2] + sh[3];
}

// combine partials (fixed order) + broadcast to [32,1,17,17]
__global__ void xcorr_out(const float* __restrict__ part, float* __restrict__ out, int total) {
  int i = blockIdx.x * 256 + threadIdx.x;
  if (i >= total) return;
  int p = i % 289;
  float s = 0.f;
  for (int b = 0; b < 32; ++b) s += part[p * 32 + b];
  out[i] = s * (1.f / 147456.f);
}

// ============ host ============
extern "C" void kernel_launch(void* const* d_in, const int* in_sizes, int n_in,
                              void* d_out, int out_size, void* d_ws, size_t ws_size,
                              hipStream_t stream) {
  (void)in_sizes; (void)n_in; (void)ws_size; (void)out_size;
  const float* input1 = (const float*)d_in[0];
  const float* input2 = (const float*)d_in[1];
  const float* cw[5];
  const float* bg[5];
  const float* bb[5];
  for (int i = 0; i < 5; ++i) {
    cw[i] = (const float*)d_in[2 + 2 * i];
    bg[i] = (const float*)d_in[12 + 2 * i];
    bb[i] = (const float*)d_in[13 + 2 * i];
  }
  char* p = (char*)d_ws;
  auto alloc = [&](size_t bytes) {
    char* r = p;
    p += (bytes + 255) & ~(size_t)255;
    return r;
  };
  unsigned short* P = (unsigned short*)alloc(93000000);
  unsigned short* Q = (unsigned short*)alloc(7200000);
  unsigned short* R = (unsigned short*)alloc(23000000);
  float* O1 = (float*)alloc(32l * 22 * 22 * 128 * 4);
  float* O2 = (float*)alloc(32l * 6 * 6 * 128 * 4);
  unsigned short* I1h = (unsigned short*)alloc(32l * 255 * 255 * 4 * 2 + 16384);
  unsigned short* I2h = (unsigned short*)alloc(32l * 127 * 127 * 4 * 2 + 16384);
  unsigned short* W1h = (unsigned short*)alloc(17l * 128 * 32 * 2);
  unsigned short* W2 = (unsigned short*)alloc(25l * 256 * 96 * 2);
  unsigned short* W3 = (unsigned short*)alloc(9l * 256 * 256 * 2);
  unsigned short* W4 = (unsigned short*)alloc(9l * 256 * 192 * 2);
  unsigned short* W5 = (unsigned short*)alloc(9l * 128 * 192 * 2);
  float* part = (float*)alloc(8500000);
  float* sc = (float*)alloc(256 * 4);
  float* sh = (float*)alloc(256 * 4);

  // weight + input transforms
  {
    int t1 = 17 * 128 * 32;
    wt1_transform<<<(unsigned)((t1 + 255) / 256), 256, 0, stream>>>(cw[0], W1h, t1);
    long t2 = 25l * 256 * 96;
    wt_transform<<<(unsigned)((t2 + 255) / 256), 256, 0, stream>>>(cw[1], W2, 256, 256, 96, 25, t2);
    long t3 = 9l * 256 * 256;
    wt_transform<<<(unsigned)((t3 + 255) / 256), 256, 0, stream>>>(cw[2], W3, 192, 256, 256, 9, t3);
    long t4 = 9l * 256 * 192;
    wt_transform<<<(unsigned)((t4 + 255) / 256), 256, 0, stream>>>(cw[3], W4, 192, 256, 192, 9, t4);
    long t5 = 9l * 128 * 192;
    wt_transform<<<(unsigned)((t5 + 255) / 256), 256, 0, stream>>>(cw[4], W5, 128, 128, 192, 9, t5);
    int p1 = 32 * 255 * 255;
    in_transform<<<(unsigned)((p1 + 255) / 256), 256, 0, stream>>>(input1, I1h, 255 * 255, p1);
    int p2 = 32 * 127 * 127;
    in_transform<<<(unsigned)((p2 + 255) / 256), 256, 0, stream>>>(input2, I2h, 127 * 127, p2);
  }

  const int N = 32;
  auto finalize = [&](int C, int NBX, long NP, const float* g, const float* b) {
    bn_finalize<<<C, 256, 0, stream>>>(part, g, b, sc, sh, NBX, (float)NP);
  };
  auto apply = [&](unsigned short* X, int C, long NP, bool relu, float* outf) {
    long t8 = NP * C / 8;
    unsigned blocks = (unsigned)((t8 + 255) / 256);
    if (outf)
      bn_apply_k<false, true><<<blocks, 256, 0, stream>>>(X, outf, sc, sh, C, t8);
    else
      bn_apply_k<true, false><<<blocks, 256, 0, stream>>>(X, X, sc, sh, C, t8);
  };
  auto mfma_conv = [&](int K, const unsigned short* in, const unsigned short* wt,
                       unsigned short* out, int Ci, int Hi, int Ho, int Co_pad, int Co_real) {
    int NPIX = N * Ho * Ho;
    dim3 g((unsigned)((NPIX + 127) / 128), (unsigned)(Co_pad / 128));
    if (K == 5)
      conv_mfma<5><<<g, 256, 0, stream>>>(in, wt, out, part, Ci, Hi, Hi, Ho, Ho, Co_pad, Co_real, NPIX);
    else
      conv_mfma<3><<<g, 256, 0, stream>>>(in, wt, out, part, Ci, Hi, Hi, Ho, Ho, Co_pad, Co_real, NPIX);
  };

  auto run_branch = [&](const unsigned short* inh, int Hin, float* Oout) {
    int H1 = (Hin - 11) / 2 + 1;
    int P1 = (H1 - 3) / 2 + 1;
    int H2 = P1 - 4;
    int P2 = (H2 - 3) / 2 + 1;
    int H3 = P2 - 2, H4 = P2 - 4, H5 = P2 - 6;
    // conv1 (MFMA, fused stats) -> P
    int NPIX1 = N * H1 * H1;
    int NBX1 = (NPIX1 + 127) / 128;
    conv1_mfma<<<(unsigned)NBX1, 256, 0, stream>>>(inh, W1h, P, part, Hin, Hin, H1, H1, NPIX1);
    finalize(96, NBX1, (long)N * H1 * H1, bg[0], bb[0]);
    // fused bn+relu+pool1 -> R
    long pt1 = (long)N * P1 * P1 * 96 / 8;
    bn_pool_k<<<(unsigned)((pt1 + 255) / 256), 256, 0, stream>>>(P, R, sc, sh, 12, H1, H1, P1, P1, pt1);
    // conv2 -> P
    mfma_conv(5, R, W2, P, 96, P1, H2, 256, 256);
    finalize(256, (N * H2 * H2 + 127) / 128, (long)N * H2 * H2, bg[1], bb[1]);
    // fused bn+relu+pool2 -> R
    long pt2 = (long)N * P2 * P2 * 256 / 8;
    bn_pool_k<<<(unsigned)((pt2 + 255) / 256), 256, 0, stream>>>(P, R, sc, sh, 32, H2, H2, P2, P2, pt2);
    // conv3 -> P
    mfma_conv(3, R, W3, P, 256, P2, H3, 256, 192);
    finalize(192, (N * H3 * H3 + 127) / 128, (long)N * H3 * H3, bg[2], bb[2]);
    apply(P, 192, (long)N * H3 * H3, true, nullptr);
    // conv4 -> Q
    mfma_conv(3, P, W4, Q, 192, H3, H4, 256, 192);
    finalize(192, (N * H4 * H4 + 127) / 128, (long)N * H4 * H4, bg[3], bb[3]);
    apply(Q, 192, (long)N * H4 * H4, true, nullptr);
    // conv5 -> P
    mfma_conv(3, Q, W5, P, 192, H4, H5, 128, 128);
    finalize(128, (N * H5 * H5 + 127) / 128, (long)N * H5 * H5, bg[4], bb[4]);
    apply(P, 128, (long)N * H5 * H5, false, Oout);
  };

  run_branch(I1h, 255, O1);
  run_branch(I2h, 127, O2);

  xcorr_part<<<dim3(289, 32), 256, 0, stream>>>(O1, O2, part);
  xcorr_out<<<(9248 + 255) / 256, 256, 0, stream>>>(part, (float*)d_out, 9248);
}

// Round 10
// 800.705 us; speedup vs baseline: 3.7461x; 1.0211x over previous
//
#include <hip/hip_runtime.h>
#include <hip/hip_bf16.h>
#include <cstdint>
#include <cstddef>

typedef __attribute__((ext_vector_type(8))) _Float16 f16x8;
typedef __attribute__((ext_vector_type(4))) float f32x4;

__device__ __forceinline__ float h2f(unsigned short u) {
  union { unsigned short s; _Float16 h; } x; x.s = u; return (float)x.h;
}
__device__ __forceinline__ unsigned short f2h(float f) {
  union { unsigned short s; _Float16 h; } x; x.h = (_Float16)f; return x.s;
}
__device__ __forceinline__ void gload_lds16(const void* g, void* l) {
  __builtin_amdgcn_global_load_lds((const __attribute__((address_space(1))) unsigned int*)g,
                                   (__attribute__((address_space(3))) unsigned int*)l, 16, 0, 0);
}

// ============ input transform: fp32 NCHW [N,3,H,W] -> fp16 [N,H,W,4] (c3=0) ============
__global__ void in_transform(const float* __restrict__ in, unsigned short* __restrict__ out,
                             int HW, int total) {
  int i = blockIdx.x * 256 + threadIdx.x;
  if (i >= total) return;
  int n = i / HW;
  int r = i - n * HW;
  const float* p = in + (long)n * 3 * HW + r;
  uint2 v;
  v.x = (unsigned)f2h(p[0]) | ((unsigned)f2h(p[HW]) << 16);
  v.y = (unsigned)f2h(p[2 * HW]);
  ((uint2*)out)[i] = v;
}

// ============ conv1 weight transform: [96][3][11][11] fp32 -> [17][128][32] fp16 ============
__global__ void wt1_transform(const float* __restrict__ w, unsigned short* __restrict__ o,
                              int total) {
  int i = blockIdx.x * 256 + threadIdx.x;
  if (i >= total) return;
  int j = i & 31;
  int r = i >> 5;
  int co = r & 127;
  int kk = r >> 7;
  int run = kk * 4 + (j >> 3);
  int ky = run / 6;
  int e = (run - ky * 6) * 8 + (j & 7);
  int kx = e >> 2, c = e & 3;
  float v = 0.f;
  if (ky < 11 && kx < 11 && c < 3 && co < 96)
    v = w[((co * 3 + c) * 11 + ky) * 11 + kx];
  o[i] = f2h(v);
}

// ============ conv1 MFMA (3-slot pipelined + bank-swizzled + fused stats) ============
__global__ __launch_bounds__(256)
void conv1_mfma(const unsigned short* __restrict__ in, const unsigned short* __restrict__ wt,
                unsigned short* __restrict__ out, float* __restrict__ part,
                int Hi, int Wi, int Ho, int Wo, int NPIX) {
  __shared__ __align__(16) unsigned short sA[3][128 * 32];
  __shared__ __align__(16) unsigned short sB[3][128 * 32];
  __shared__ int sOB[128];
  __shared__ float sRed[4][64][2];
  const int t = threadIdx.x;
  const int px0 = blockIdx.x * 128;
  if (t < 128) {
    int g = px0 + t;
    int ob = -1;
    if (g < NPIX) {
      int n = g / (Ho * Wo);
      int r = g - n * Ho * Wo;
      int oy = r / Wo, ox = r - (r / Wo) * Wo;
      ob = ((n * Ho + oy) * Wo + ox) * 96;
    }
    sOB[t] = ob;
  }
  long rbase[2];
#pragma unroll
  for (int i = 0; i < 2; ++i) {
    int pxl = i * 64 + (t >> 2);
    int g = px0 + pxl;
    long rb = 0;
    if (g < NPIX) {
      int n = g / (Ho * Wo);
      int r = g - n * Ho * Wo;
      int oy = r / Wo, ox = r - (r / Wo) * Wo;
      rb = ((long)(n * Hi + 2 * oy) * Wi + 2 * ox) * 4;
    }
    rbase[i] = rb;
  }
  // source-side swizzle: physical slot (row=t>>2, p=t&3) stores logical seg p ^ ((row>>1)&3)
  const int swz = (t & 3) ^ ((t >> 3) & 3);
  const int W4 = Wi * 4;
  f32x4 acc[4][4];
  f32x4 zz = {0.f, 0.f, 0.f, 0.f};
#pragma unroll
  for (int m = 0; m < 4; ++m)
#pragma unroll
    for (int n = 0; n < 4; ++n) acc[m][n] = zz;
  const int w = t >> 6;
  const int l = t & 63;
  const int wpx = (w & 1) * 64, wco = (w >> 1) * 64;
  const int arow = wpx + (l & 15);
  const int brow = wco + (l & 15);
  // read-side swizzle (m-independent: (row>>1)&3 == ((l&15)>>1)&3 for row = base + l&15 + m*16)
  const int q8s = (((l >> 4) ^ (((l & 15) >> 1) & 3)) * 8);

  auto stage = [&](int slot, int kk) {
    int run = kk * 4 + swz;
    int ky = run / 6;
    int e0 = (run - ky * 6) * 8;
    long koff = (long)ky * W4 + e0;
    gload_lds16(in + rbase[0] + koff, &sA[slot][t * 8]);
    gload_lds16(in + rbase[1] + koff, &sA[slot][(256 + t) * 8]);
    const unsigned short* wp = wt + (long)kk * 4096;
    gload_lds16(wp + (t >> 2) * 32 + swz * 8, &sB[slot][t * 8]);
    gload_lds16(wp + 2048 + (t >> 2) * 32 + swz * 8, &sB[slot][(256 + t) * 8]);
  };

  stage(0, 0);
  stage(1, 1);
  asm volatile("s_waitcnt vmcnt(4)" ::: "memory");
  __builtin_amdgcn_sched_barrier(0);
  __builtin_amdgcn_s_barrier();
  __builtin_amdgcn_sched_barrier(0);
  int cur = 0;
#pragma unroll 1
  for (int kk = 0; kk < 17; ++kk) {
    if (kk + 2 < 17) {
      int s2 = cur + 2;
      if (s2 >= 3) s2 -= 3;
      stage(s2, kk + 2);
    }
    f16x8 av[4], bv[4];
#pragma unroll
    for (int m = 0; m < 4; ++m) av[m] = *(const f16x8*)&sA[cur][(arow + m * 16) * 32 + q8s];
#pragma unroll
    for (int n = 0; n < 4; ++n) bv[n] = *(const f16x8*)&sB[cur][(brow + n * 16) * 32 + q8s];
#pragma unroll
    for (int m = 0; m < 4; ++m)
#pragma unroll
      for (int n = 0; n < 4; ++n)
        acc[m][n] = __builtin_amdgcn_mfma_f32_16x16x32_f16(av[m], bv[n], acc[m][n], 0, 0, 0);
    __builtin_amdgcn_sched_barrier(0);
    if (kk + 1 < 17) {
      if (kk + 2 < 17)
        asm volatile("s_waitcnt vmcnt(4)" ::: "memory");
      else
        asm volatile("s_waitcnt vmcnt(0)" ::: "memory");
    }
    __builtin_amdgcn_s_barrier();
    __builtin_amdgcn_sched_barrier(0);
    ++cur;
    if (cur == 3) cur = 0;
  }
#pragma unroll
  for (int m = 0; m < 4; ++m) {
#pragma unroll
    for (int r = 0; r < 4; ++r) {
      int pxl = wpx + m * 16 + (l >> 4) * 4 + r;
      int ob = sOB[pxl];
#pragma unroll
      for (int n = 0; n < 4; ++n) {
        int co = wco + n * 16 + (l & 15);
        if (ob >= 0 && co < 96) out[ob + co] = f2h(acc[m][n][r]);
      }
    }
  }
  float sn[4], qn[4];
#pragma unroll
  for (int n = 0; n < 4; ++n) { sn[n] = 0.f; qn[n] = 0.f; }
#pragma unroll
  for (int m = 0; m < 4; ++m) {
#pragma unroll
    for (int r = 0; r < 4; ++r) {
      int pxl = wpx + m * 16 + (l >> 4) * 4 + r;
      float msk = (px0 + pxl < NPIX) ? 1.f : 0.f;
#pragma unroll
      for (int n = 0; n < 4; ++n) {
        float v = acc[m][n][r] * msk;
        sn[n] += v;
        qn[n] = fmaf(v, v, qn[n]);
      }
    }
  }
#pragma unroll
  for (int n = 0; n < 4; ++n) {
    sn[n] += __shfl_xor(sn[n], 16, 64);
    sn[n] += __shfl_xor(sn[n], 32, 64);
    qn[n] += __shfl_xor(qn[n], 16, 64);
    qn[n] += __shfl_xor(qn[n], 32, 64);
  }
  if (l < 16) {
#pragma unroll
    for (int n = 0; n < 4; ++n) {
      sRed[w][n * 16 + l][0] = sn[n];
      sRed[w][n * 16 + l][1] = qn[n];
    }
  }
  __syncthreads();
  if (t < 128) {
    int wb = (t >> 6) << 1;
    int cl = t & 63;
    float S = sRed[wb][cl][0] + sRed[wb + 1][cl][0];
    float Q = sRed[wb][cl][1] + sRed[wb + 1][cl][1];
    long idx = ((long)t * gridDim.x + blockIdx.x) * 2;
    part[idx] = S;
    part[idx + 1] = Q;
  }
}

// ============ implicit-GEMM MFMA conv, 3-slot pipelined + bank-swizzled + fused stats ============
template <int K>
__global__ __launch_bounds__(256)
void conv_mfma(const unsigned short* __restrict__ in, const unsigned short* __restrict__ wt,
               unsigned short* __restrict__ out, float* __restrict__ part,
               int Ci, int Hi, int Wi, int Ho, int Wo, int Co_pad, int Co_real, int NPIX) {
  __shared__ __align__(16) unsigned short sA[3][128 * 32];
  __shared__ __align__(16) unsigned short sB[3][128 * 32];
  __shared__ int sOB[128];
  __shared__ float sRed[4][64][2];
  const int t = threadIdx.x;
  const int px0 = blockIdx.x * 128;
  const int co0 = blockIdx.y * 128;
  if (t < 128) {
    int g = px0 + t;
    int ob = -1;
    if (g < NPIX) {
      int n = g / (Ho * Wo);
      int r = g - n * Ho * Wo;
      int oy = r / Wo, ox = r - (r / Wo) * Wo;
      ob = ((n * Ho + oy) * Wo + ox) * Co_real;
    }
    sOB[t] = ob;
  }
  long rbase[2];
#pragma unroll
  for (int i = 0; i < 2; ++i) {
    int pxl = i * 64 + (t >> 2);
    int g = px0 + pxl;
    long rb = 0;
    if (g < NPIX) {
      int n = g / (Ho * Wo);
      int r = g - n * Ho * Wo;
      int oy = r / Wo, ox = r - (r / Wo) * Wo;
      rb = ((long)(n * Hi + oy) * Wi + ox) * Ci;
    }
    rbase[i] = rb;
  }
  // source-side swizzle segment (both A and B stage at row = t>>2, phys slot = t&3)
  const int seg8 = ((t & 3) ^ ((t >> 3) & 3)) * 8;
  const int colA = t >> 2;
  f32x4 acc[4][4];
  f32x4 zz = {0.f, 0.f, 0.f, 0.f};
#pragma unroll
  for (int m = 0; m < 4; ++m)
#pragma unroll
    for (int n = 0; n < 4; ++n) acc[m][n] = zz;
  const int w = t >> 6;
  const int l = t & 63;
  const int wpx = (w & 1) * 64, wco = (w >> 1) * 64;
  const int arow = wpx + (l & 15);
  const int brow = wco + (l & 15);
  const int q8s = (((l >> 4) ^ (((l & 15) >> 1) & 3)) * 8);
  int ci0 = 0, kx = 0, ky = 0;
  const int NK = (Ci >> 5) * K * K;

  auto stage = [&](int slot) {
    long koff = (long)(ky * Wi + kx) * Ci + ci0 + seg8;
    gload_lds16(in + rbase[0] + koff, &sA[slot][t * 8]);
    gload_lds16(in + rbase[1] + koff, &sA[slot][(256 + t) * 8]);
    long wbase = (long)((ky * K + kx) * Co_pad + co0) * Ci + ci0 + seg8;
    gload_lds16(wt + wbase + (long)colA * Ci, &sB[slot][t * 8]);
    gload_lds16(wt + wbase + (long)(64 + colA) * Ci, &sB[slot][(256 + t) * 8]);
    ci0 += 32;
    if (ci0 == Ci) { ci0 = 0; ++kx; if (kx == K) { kx = 0; ++ky; } }
  };

  stage(0);
  stage(1);
  asm volatile("s_waitcnt vmcnt(4)" ::: "memory");
  __builtin_amdgcn_sched_barrier(0);
  __builtin_amdgcn_s_barrier();
  __builtin_amdgcn_sched_barrier(0);
  int cur = 0;
#pragma unroll 1
  for (int kk = 0; kk < NK; ++kk) {
    if (kk + 2 < NK) {
      int s2 = cur + 2;
      if (s2 >= 3) s2 -= 3;
      stage(s2);
    }
    f16x8 av[4], bv[4];
#pragma unroll
    for (int m = 0; m < 4; ++m) av[m] = *(const f16x8*)&sA[cur][(arow + m * 16) * 32 + q8s];
#pragma unroll
    for (int n = 0; n < 4; ++n) bv[n] = *(const f16x8*)&sB[cur][(brow + n * 16) * 32 + q8s];
#pragma unroll
    for (int m = 0; m < 4; ++m)
#pragma unroll
      for (int n = 0; n < 4; ++n)
        acc[m][n] = __builtin_amdgcn_mfma_f32_16x16x32_f16(av[m], bv[n], acc[m][n], 0, 0, 0);
    __builtin_amdgcn_sched_barrier(0);
    if (kk + 1 < NK) {
      if (kk + 2 < NK)
        asm volatile("s_waitcnt vmcnt(4)" ::: "memory");
      else
        asm volatile("s_waitcnt vmcnt(0)" ::: "memory");
    }
    __builtin_amdgcn_s_barrier();
    __builtin_amdgcn_sched_barrier(0);
    ++cur;
    if (cur == 3) cur = 0;
  }
#pragma unroll
  for (int m = 0; m < 4; ++m) {
#pragma unroll
    for (int r = 0; r < 4; ++r) {
      int pxl = wpx + m * 16 + (l >> 4) * 4 + r;
      int ob = sOB[pxl];
#pragma unroll
      for (int n = 0; n < 4; ++n) {
        int co = co0 + wco + n * 16 + (l & 15);
        if (ob >= 0 && co < Co_real) out[ob + co] = f2h(acc[m][n][r]);
      }
    }
  }
  float sn[4], qn[4];
#pragma unroll
  for (int n = 0; n < 4; ++n) { sn[n] = 0.f; qn[n] = 0.f; }
#pragma unroll
  for (int m = 0; m < 4; ++m) {
#pragma unroll
    for (int r = 0; r < 4; ++r) {
      int pxl = wpx + m * 16 + (l >> 4) * 4 + r;
      float msk = (px0 + pxl < NPIX) ? 1.f : 0.f;
#pragma unroll
      for (int n = 0; n < 4; ++n) {
        float v = acc[m][n][r] * msk;
        sn[n] += v;
        qn[n] = fmaf(v, v, qn[n]);
      }
    }
  }
#pragma unroll
  for (int n = 0; n < 4; ++n) {
    sn[n] += __shfl_xor(sn[n], 16, 64);
    sn[n] += __shfl_xor(sn[n], 32, 64);
    qn[n] += __shfl_xor(qn[n], 16, 64);
    qn[n] += __shfl_xor(qn[n], 32, 64);
  }
  if (l < 16) {
#pragma unroll
    for (int n = 0; n < 4; ++n) {
      sRed[w][n * 16 + l][0] = sn[n];
      sRed[w][n * 16 + l][1] = qn[n];
    }
  }
  __syncthreads();
  if (t < 128) {
    int wb = (t >> 6) << 1;
    int cl = t & 63;
    float S = sRed[wb][cl][0] + sRed[wb + 1][cl][0];
    float Q = sRed[wb][cl][1] + sRed[wb + 1][cl][1];
    long idx = ((long)(co0 + t) * gridDim.x + blockIdx.x) * 2;
    part[idx] = S;
    part[idx + 1] = Q;
  }
}

// ============ weight transform: [Co][Ci][K][K] fp32 -> [K*K][Co_pad][Ci] fp16 ============
__global__ void wt_transform(const float* __restrict__ w, unsigned short* __restrict__ o,
                             int Co, int Co_pad, int Ci, int KK, long total) {
  long i = (long)blockIdx.x * blockDim.x + threadIdx.x;
  if (i >= total) return;
  int ci = (int)(i % Ci);
  long r = i / Ci;
  int co = (int)(r % Co_pad);
  int rk = (int)(r / Co_pad);
  float v = 0.f;
  if (co < Co) v = w[((long)co * Ci + ci) * KK + rk];
  o[i] = f2h(v);
}

// ============ BN finalize: one block per channel, reduce NBX partials ============
__global__ void bn_finalize(const float* __restrict__ part, const float* __restrict__ g,
                            const float* __restrict__ b, float* __restrict__ sc,
                            float* __restrict__ sh, int NBX, float cnt) {
  const int c = blockIdx.x;
  const int t = threadIdx.x;
  float s = 0.f, q = 0.f;
  const float* pc = part + (long)c * NBX * 2;
  for (int k = t; k < NBX; k += 256) {
    s += pc[k * 2];
    q += pc[k * 2 + 1];
  }
  __shared__ float ss[256], qq[256];
  ss[t] = s; qq[t] = q;
  __syncthreads();
  for (int off = 128; off > 0; off >>= 1) {
    if (t < off) { ss[t] += ss[t + off]; qq[t] += qq[t + off]; }
    __syncthreads();
  }
  if (t == 0) {
    float m = ss[0] / cnt;
    float v = qq[0] / cnt - m * m;
    float r = rsqrtf(v + 1e-5f);
    float scl = r * g[c];
    sc[c] = scl;
    sh[c] = b[c] - m * scl;
  }
}

// ============ BN apply (8-wide, in place or fp16->fp32) ============
template <bool RELU, bool OUTF32>
__global__ void bn_apply_k(const unsigned short* __restrict__ x, void* __restrict__ y,
                           const float* __restrict__ sc, const float* __restrict__ sh,
                           int C, long total8) {
  long i = (long)blockIdx.x * blockDim.x + threadIdx.x;
  if (i >= total8) return;
  const uint4 v = ((const uint4*)x)[i];
  long base = i * 8;
  int c0 = (int)(base % C);
  const float4 s0 = *(const float4*)&sc[c0];
  const float4 s1 = *(const float4*)&sc[c0 + 4];
  const float4 h0 = *(const float4*)&sh[c0];
  const float4 h1 = *(const float4*)&sh[c0 + 4];
  float f[8];
  f[0] = h2f((unsigned short)(v.x & 0xffff)); f[1] = h2f((unsigned short)(v.x >> 16));
  f[2] = h2f((unsigned short)(v.y & 0xffff)); f[3] = h2f((unsigned short)(v.y >> 16));
  f[4] = h2f((unsigned short)(v.z & 0xffff)); f[5] = h2f((unsigned short)(v.z >> 16));
  f[6] = h2f((unsigned short)(v.w & 0xffff)); f[7] = h2f((unsigned short)(v.w >> 16));
  const float S[8] = {s0.x, s0.y, s0.z, s0.w, s1.x, s1.y, s1.z, s1.w};
  const float H[8] = {h0.x, h0.y, h0.z, h0.w, h1.x, h1.y, h1.z, h1.w};
#pragma unroll
  for (int j = 0; j < 8; ++j) {
    f[j] = fmaf(f[j], S[j], H[j]);
    if (RELU) f[j] = fmaxf(f[j], 0.f);
  }
  if (OUTF32) {
    float4 o0 = {f[0], f[1], f[2], f[3]}, o1 = {f[4], f[5], f[6], f[7]};
    ((float4*)y)[2 * i] = o0;
    ((float4*)y)[2 * i + 1] = o1;
  } else {
    uint4 o;
    o.x = (unsigned)f2h(f[0]) | ((unsigned)f2h(f[1]) << 16);
    o.y = (unsigned)f2h(f[2]) | ((unsigned)f2h(f[3]) << 16);
    o.z = (unsigned)f2h(f[4]) | ((unsigned)f2h(f[5]) << 16);
    o.w = (unsigned)f2h(f[6]) | ((unsigned)f2h(f[7]) << 16);
    ((uint4*)y)[i] = o;
  }
}

// ============ fused BN+ReLU+MaxPool 3x3 s2 (NHWC fp16), 8 channels/thread ============
__global__ void bn_pool_k(const unsigned short* __restrict__ in, unsigned short* __restrict__ out,
                          const float* __restrict__ sc, const float* __restrict__ sh,
                          int C8, int Hi, int Wi, int Ho, int Wo, long total8) {
  long i = (long)blockIdx.x * blockDim.x + threadIdx.x;
  if (i >= total8) return;
  int cg = (int)(i % C8);
  long r = i / C8;
  int ox = (int)(r % Wo);
  r /= Wo;
  int oy = (int)(r % Ho);
  int n = (int)(r / Ho);
  const int c0 = cg * 8;
  const float4 s0 = *(const float4*)&sc[c0];
  const float4 s1 = *(const float4*)&sc[c0 + 4];
  const float4 h0 = *(const float4*)&sh[c0];
  const float4 h1 = *(const float4*)&sh[c0 + 4];
  const float S[8] = {s0.x, s0.y, s0.z, s0.w, s1.x, s1.y, s1.z, s1.w};
  const float H[8] = {h0.x, h0.y, h0.z, h0.w, h1.x, h1.y, h1.z, h1.w};
  const uint4* bp = (const uint4*)in + ((long)(n * Hi + 2 * oy) * Wi + 2 * ox) * C8 + cg;
  float m[8];
#pragma unroll
  for (int j = 0; j < 8; ++j) m[j] = -3.4e38f;
#pragma unroll
  for (int dy = 0; dy < 3; ++dy)
#pragma unroll
    for (int dx = 0; dx < 3; ++dx) {
      const uint4 v = bp[((long)dy * Wi + dx) * C8];
      float f[8];
      f[0] = h2f((unsigned short)(v.x & 0xffff)); f[1] = h2f((unsigned short)(v.x >> 16));
      f[2] = h2f((unsigned short)(v.y & 0xffff)); f[3] = h2f((unsigned short)(v.y >> 16));
      f[4] = h2f((unsigned short)(v.z & 0xffff)); f[5] = h2f((unsigned short)(v.z >> 16));
      f[6] = h2f((unsigned short)(v.w & 0xffff)); f[7] = h2f((unsigned short)(v.w >> 16));
#pragma unroll
      for (int j = 0; j < 8; ++j) {
        f[j] = fmaxf(fmaf(f[j], S[j], H[j]), 0.f);
        m[j] = fmaxf(m[j], f[j]);
      }
    }
  uint4 o;
  o.x = (unsigned)f2h(m[0]) | ((unsigned)f2h(m[1]) << 16);
  o.y = (unsigned)f2h(m[2]) | ((unsigned)f2h(m[3]) << 16);
  o.z = (unsigned)f2h(m[4]) | ((unsigned)f2h(m[5]) << 16);
  o.w = (unsigned)f2h(m[6]) | ((unsigned)f2h(m[7]) << 16);
  ((uint4*)out)[i] = o;
}

// ============ cross-correlation partials: grid (289, 32) ============
__global__ void xcorr_part(const float* __restrict__ o1, const float* __restrict__ o2,
                           float* __restrict__ part) {
  const int p = blockIdx.x;
  const int b = blockIdx.y;
  const int oy = p / 17, ox = p - (p / 17) * 17;
  const float* o1b = o1 + (long)b * 22 * 22 * 128;
  const float* o2b = o2 + (long)b * 4608;
  float acc = 0.f;
  for (int i = threadIdx.x; i < 4608; i += 256) {
    int c = i & 127;
    int r = i >> 7;
    int kx = r % 6, ky = r / 6;
    acc = fmaf(o1b[((oy + ky) * 22 + ox + kx) * 128 + c], o2b[i], acc);
  }
#pragma unroll
  for (int off = 32; off > 0; off >>= 1) acc += __shfl_down(acc, off, 64);
  __shared__ float sh[4];
  const int lane = threadIdx.x & 63, wid = threadIdx.x >> 6;
  if (lane == 0) sh[wid] = acc;
  __syncthreads();
  if (threadIdx.x == 0) part[p * 32 + b] = sh[0] + sh[1] + sh[2] + sh[3];
}

// combine partials (fixed order) + broadcast to [32,1,17,17]
__global__ void xcorr_out(const float* __restrict__ part, float* __restrict__ out, int total) {
  int i = blockIdx.x * 256 + threadIdx.x;
  if (i >= total) return;
  int p = i % 289;
  float s = 0.f;
  for (int b = 0; b < 32; ++b) s += part[p * 32 + b];
  out[i] = s * (1.f / 147456.f);
}

// ============ host ============
extern "C" void kernel_launch(void* const* d_in, const int* in_sizes, int n_in,
                              void* d_out, int out_size, void* d_ws, size_t ws_size,
                              hipStream_t stream) {
  (void)in_sizes; (void)n_in; (void)ws_size; (void)out_size;
  const float* input1 = (const float*)d_in[0];
  const float* input2 = (const float*)d_in[1];
  const float* cw[5];
  const float* bg[5];
  const float* bb[5];
  for (int i = 0; i < 5; ++i) {
    cw[i] = (const float*)d_in[2 + 2 * i];
    bg[i] = (const float*)d_in[12 + 2 * i];
    bb[i] = (const float*)d_in[13 + 2 * i];
  }
  char* p = (char*)d_ws;
  auto alloc = [&](size_t bytes) {
    char* r = p;
    p += (bytes + 255) & ~(size_t)255;
    return r;
  };
  unsigned short* P = (unsigned short*)alloc(93000000);
  unsigned short* Q = (unsigned short*)alloc(7200000);
  unsigned short* R = (unsigned short*)alloc(23000000);
  float* O1 = (float*)alloc(32l * 22 * 22 * 128 * 4);
  float* O2 = (float*)alloc(32l * 6 * 6 * 128 * 4);
  unsigned short* I1h = (unsigned short*)alloc(32l * 255 * 255 * 4 * 2 + 16384);
  unsigned short* I2h = (unsigned short*)alloc(32l * 127 * 127 * 4 * 2 + 16384);
  unsigned short* W1h = (unsigned short*)alloc(17l * 128 * 32 * 2);
  unsigned short* W2 = (unsigned short*)alloc(25l * 256 * 96 * 2);
  unsigned short* W3 = (unsigned short*)alloc(9l * 256 * 256 * 2);
  unsigned short* W4 = (unsigned short*)alloc(9l * 256 * 192 * 2);
  unsigned short* W5 = (unsigned short*)alloc(9l * 128 * 192 * 2);
  float* part = (float*)alloc(8500000);
  float* sc = (float*)alloc(256 * 4);
  float* sh = (float*)alloc(256 * 4);

  // weight + input transforms
  {
    int t1 = 17 * 128 * 32;
    wt1_transform<<<(unsigned)((t1 + 255) / 256), 256, 0, stream>>>(cw[0], W1h, t1);
    long t2 = 25l * 256 * 96;
    wt_transform<<<(unsigned)((t2 + 255) / 256), 256, 0, stream>>>(cw[1], W2, 256, 256, 96, 25, t2);
    long t3 = 9l * 256 * 256;
    wt_transform<<<(unsigned)((t3 + 255) / 256), 256, 0, stream>>>(cw[2], W3, 192, 256, 256, 9, t3);
    long t4 = 9l * 256 * 192;
    wt_transform<<<(unsigned)((t4 + 255) / 256), 256, 0, stream>>>(cw[3], W4, 192, 256, 192, 9, t4);
    long t5 = 9l * 128 * 192;
    wt_transform<<<(unsigned)((t5 + 255) / 256), 256, 0, stream>>>(cw[4], W5, 128, 128, 192, 9, t5);
    int p1 = 32 * 255 * 255;
    in_transform<<<(unsigned)((p1 + 255) / 256), 256, 0, stream>>>(input1, I1h, 255 * 255, p1);
    int p2 = 32 * 127 * 127;
    in_transform<<<(unsigned)((p2 + 255) / 256), 256, 0, stream>>>(input2, I2h, 127 * 127, p2);
  }

  const int N = 32;
  auto finalize = [&](int C, int NBX, long NP, const float* g, const float* b) {
    bn_finalize<<<C, 256, 0, stream>>>(part, g, b, sc, sh, NBX, (float)NP);
  };
  auto apply = [&](unsigned short* X, int C, long NP, bool relu, float* outf) {
    long t8 = NP * C / 8;
    unsigned blocks = (unsigned)((t8 + 255) / 256);
    if (outf)
      bn_apply_k<false, true><<<blocks, 256, 0, stream>>>(X, outf, sc, sh, C, t8);
    else
      bn_apply_k<true, false><<<blocks, 256, 0, stream>>>(X, X, sc, sh, C, t8);
  };
  auto mfma_conv = [&](int K, const unsigned short* in, const unsigned short* wt,
                       unsigned short* out, int Ci, int Hi, int Ho, int Co_pad, int Co_real) {
    int NPIX = N * Ho * Ho;
    dim3 g((unsigned)((NPIX + 127) / 128), (unsigned)(Co_pad / 128));
    if (K == 5)
      conv_mfma<5><<<g, 256, 0, stream>>>(in, wt, out, part, Ci, Hi, Hi, Ho, Ho, Co_pad, Co_real, NPIX);
    else
      conv_mfma<3><<<g, 256, 0, stream>>>(in, wt, out, part, Ci, Hi, Hi, Ho, Ho, Co_pad, Co_real, NPIX);
  };

  auto run_branch = [&](const unsigned short* inh, int Hin, float* Oout) {
    int H1 = (Hin - 11) / 2 + 1;
    int P1 = (H1 - 3) / 2 + 1;
    int H2 = P1 - 4;
    int P2 = (H2 - 3) / 2 + 1;
    int H3 = P2 - 2, H4 = P2 - 4, H5 = P2 - 6;
    // conv1 (MFMA, fused stats) -> P
    int NPIX1 = N * H1 * H1;
    int NBX1 = (NPIX1 + 127) / 128;
    conv1_mfma<<<(unsigned)NBX1, 256, 0, stream>>>(inh, W1h, P, part, Hin, Hin, H1, H1, NPIX1);
    finalize(96, NBX1, (long)N * H1 * H1, bg[0], bb[0]);
    // fused bn+relu+pool1 -> R
    long pt1 = (long)N * P1 * P1 * 96 / 8;
    bn_pool_k<<<(unsigned)((pt1 + 255) / 256), 256, 0, stream>>>(P, R, sc, sh, 12, H1, H1, P1, P1, pt1);
    // conv2 -> P
    mfma_conv(5, R, W2, P, 96, P1, H2, 256, 256);
    finalize(256, (N * H2 * H2 + 127) / 128, (long)N * H2 * H2, bg[1], bb[1]);
    // fused bn+relu+pool2 -> R
    long pt2 = (long)N * P2 * P2 * 256 / 8;
    bn_pool_k<<<(unsigned)((pt2 + 255) / 256), 256, 0, stream>>>(P, R, sc, sh, 32, H2, H2, P2, P2, pt2);
    // conv3 -> P
    mfma_conv(3, R, W3, P, 256, P2, H3, 256, 192);
    finalize(192, (N * H3 * H3 + 127) / 128, (long)N * H3 * H3, bg[2], bb[2]);
    apply(P, 192, (long)N * H3 * H3, true, nullptr);
    // conv4 -> Q
    mfma_conv(3, P, W4, Q, 192, H3, H4, 256, 192);
    finalize(192, (N * H4 * H4 + 127) / 128, (long)N * H4 * H4, bg[3], bb[3]);
    apply(Q, 192, (long)N * H4 * H4, true, nullptr);
    // conv5 -> P
    mfma_conv(3, Q, W5, P, 192, H4, H5, 128, 128);
    finalize(128, (N * H5 * H5 + 127) / 128, (long)N * H5 * H5, bg[4], bb[4]);
    apply(P, 128, (long)N * H5 * H5, false, Oout);
  };

  run_branch(I1h, 255, O1);
  run_branch(I2h, 127, O2);

  xcorr_part<<<dim3(289, 32), 256, 0, stream>>>(O1, O2, part);
  xcorr_out<<<(9248 + 255) / 256, 256, 0, stream>>>(part, (float*)d_out, 9248);
}

// Round 11
// 607.786 us; speedup vs baseline: 4.9351x; 1.3174x over previous
//
#include <hip/hip_runtime.h>
#include <hip/hip_bf16.h>
#include <cstdint>
#include <cstddef>

typedef __attribute__((ext_vector_type(8))) _Float16 f16x8;
typedef __attribute__((ext_vector_type(4))) float f32x4;

__device__ __forceinline__ float h2f(unsigned short u) {
  union { unsigned short s; _Float16 h; } x; x.s = u; return (float)x.h;
}
__device__ __forceinline__ unsigned short f2h(float f) {
  union { unsigned short s; _Float16 h; } x; x.h = (_Float16)f; return x.s;
}
__device__ __forceinline__ void gload_lds16(const void* g, void* l) {
  __builtin_amdgcn_global_load_lds((const __attribute__((address_space(1))) unsigned int*)g,
                                   (__attribute__((address_space(3))) unsigned int*)l, 16, 0, 0);
}

// ============ merged input transform: both branches, fp32 NCHW -> fp16 [N,H,W,4] ============
__global__ void in_all(const float* __restrict__ in1, const float* __restrict__ in2,
                       unsigned short* __restrict__ o1, unsigned short* __restrict__ o2) {
  int i = blockIdx.x * 256 + threadIdx.x;
  const int p1 = 32 * 255 * 255;
  const int p2 = 32 * 127 * 127;
  const float* in;
  unsigned short* o;
  int HW;
  if (i < p1) {
    in = in1; o = o1; HW = 255 * 255;
  } else if (i < p1 + p2) {
    i -= p1; in = in2; o = o2; HW = 127 * 127;
  } else return;
  int n = i / HW;
  int r = i - n * HW;
  const float* p = in + (long)n * 3 * HW + r;
  uint2 v;
  v.x = (unsigned)f2h(p[0]) | ((unsigned)f2h(p[HW]) << 16);
  v.y = (unsigned)f2h(p[2 * HW]);
  ((uint2*)o)[i] = v;
}

// ============ merged weight transform (all 5 layers) ============
__device__ __forceinline__ void wtx(const float* __restrict__ w, unsigned short* __restrict__ o,
                                    long i, int Co, int Co_pad, int Ci, int KK) {
  int ci = (int)(i % Ci);
  long r = i / Ci;
  int co = (int)(r % Co_pad);
  int rk = (int)(r / Co_pad);
  float v = 0.f;
  if (co < Co) v = w[((long)co * Ci + ci) * KK + rk];
  o[i] = f2h(v);
}
__global__ void wt_all(const float* __restrict__ w1, const float* __restrict__ w2,
                       const float* __restrict__ w3, const float* __restrict__ w4,
                       const float* __restrict__ w5,
                       unsigned short* __restrict__ W1h, unsigned short* __restrict__ W2,
                       unsigned short* __restrict__ W3, unsigned short* __restrict__ W4,
                       unsigned short* __restrict__ W5) {
  long i = (long)blockIdx.x * 256 + threadIdx.x;
  const long t1 = 17 * 128 * 32;          // conv1 special
  const long t2 = 25l * 256 * 96;
  const long t3 = 9l * 256 * 256;
  const long t4 = 9l * 256 * 192;
  const long t5 = 9l * 128 * 192;
  if (i < t1) {
    int j = (int)(i & 31);
    int r = (int)(i >> 5);
    int co = r & 127;
    int kk = r >> 7;
    int run = kk * 4 + (j >> 3);
    int ky = run / 6;
    int e = (run - ky * 6) * 8 + (j & 7);
    int kx = e >> 2, c = e & 3;
    float v = 0.f;
    if (ky < 11 && kx < 11 && c < 3 && co < 96)
      v = w1[((co * 3 + c) * 11 + ky) * 11 + kx];
    W1h[i] = f2h(v);
  } else if (i < t1 + t2) {
    wtx(w2, W2, i - t1, 256, 256, 96, 25);
  } else if (i < t1 + t2 + t3) {
    wtx(w3, W3, i - t1 - t2, 192, 256, 256, 9);
  } else if (i < t1 + t2 + t3 + t4) {
    wtx(w4, W4, i - t1 - t2 - t3, 192, 256, 192, 9);
  } else if (i < t1 + t2 + t3 + t4 + t5) {
    wtx(w5, W5, i - t1 - t2 - t3 - t4, 128, 128, 192, 9);
  }
}

// ============ conv1 MFMA, branch-merged, dbuf + swizzle + fused stats ============
__global__ __launch_bounds__(256)
void conv1_mfma(const unsigned short* __restrict__ in, const unsigned short* __restrict__ wt,
                unsigned short* __restrict__ out, float* __restrict__ part,
                int Hi1, int Ho1, int NPIX1, int BX1, long inOff2, long outOff2,
                int Hi2, int Ho2, int NPIX2) {
  __shared__ __align__(16) unsigned short sA[2][128 * 32];
  __shared__ __align__(16) unsigned short sB[2][128 * 32];
  __shared__ int sOB[128];
  __shared__ float sRed[4][64][2];
  const int t = threadIdx.x;
  const int bxg = blockIdx.x;
  const bool br2 = bxg >= BX1;
  const int lbx = br2 ? bxg - BX1 : bxg;
  const unsigned short* inB = in + (br2 ? inOff2 : 0);
  unsigned short* outB = out + (br2 ? outOff2 : 0);
  const int Hi = br2 ? Hi2 : Hi1, Wi = Hi;
  const int Ho = br2 ? Ho2 : Ho1, Wo = Ho;
  const int NPIX = br2 ? NPIX2 : NPIX1;
  const int px0 = lbx * 128;
  if (t < 128) {
    int g = px0 + t;
    int ob = -1;
    if (g < NPIX) {
      int n = g / (Ho * Wo);
      int r = g - n * Ho * Wo;
      int oy = r / Wo, ox = r - (r / Wo) * Wo;
      ob = ((n * Ho + oy) * Wo + ox) * 96;
    }
    sOB[t] = ob;
  }
  long rbase[2];
#pragma unroll
  for (int i = 0; i < 2; ++i) {
    int pxl = i * 64 + (t >> 2);
    int g = px0 + pxl;
    long rb = 0;
    if (g < NPIX) {
      int n = g / (Ho * Wo);
      int r = g - n * Ho * Wo;
      int oy = r / Wo, ox = r - (r / Wo) * Wo;
      rb = ((long)(n * Hi + 2 * oy) * Wi + 2 * ox) * 4;
    }
    rbase[i] = rb;
  }
  const int swz = (t & 3) ^ ((t >> 3) & 3);
  const int W4 = Wi * 4;
  f32x4 acc[4][4];
  f32x4 zz = {0.f, 0.f, 0.f, 0.f};
#pragma unroll
  for (int m = 0; m < 4; ++m)
#pragma unroll
    for (int n = 0; n < 4; ++n) acc[m][n] = zz;
  const int w = t >> 6;
  const int l = t & 63;
  const int wpx = (w & 1) * 64, wco = (w >> 1) * 64;
  const int arow = wpx + (l & 15);
  const int brow = wco + (l & 15);
  const int q8s = (((l >> 4) ^ (((l & 15) >> 1) & 3)) * 8);

  auto stage = [&](int buf, int kk) {
    int run = kk * 4 + swz;
    int ky = run / 6;
    int e0 = (run - ky * 6) * 8;
    long koff = (long)ky * W4 + e0;
    gload_lds16(inB + rbase[0] + koff, &sA[buf][t * 8]);
    gload_lds16(inB + rbase[1] + koff, &sA[buf][(256 + t) * 8]);
    const unsigned short* wp = wt + (long)kk * 4096;
    gload_lds16(wp + (t >> 2) * 32 + swz * 8, &sB[buf][t * 8]);
    gload_lds16(wp + 2048 + (t >> 2) * 32 + swz * 8, &sB[buf][(256 + t) * 8]);
  };

  stage(0, 0);
  __syncthreads();
  int cur = 0;
#pragma unroll 1
  for (int kk = 0; kk < 17; ++kk) {
    if (kk + 1 < 17) stage(cur ^ 1, kk + 1);
    f16x8 av[4], bv[4];
#pragma unroll
    for (int m = 0; m < 4; ++m) av[m] = *(const f16x8*)&sA[cur][(arow + m * 16) * 32 + q8s];
#pragma unroll
    for (int n = 0; n < 4; ++n) bv[n] = *(const f16x8*)&sB[cur][(brow + n * 16) * 32 + q8s];
#pragma unroll
    for (int m = 0; m < 4; ++m)
#pragma unroll
      for (int n = 0; n < 4; ++n)
        acc[m][n] = __builtin_amdgcn_mfma_f32_16x16x32_f16(av[m], bv[n], acc[m][n], 0, 0, 0);
    __syncthreads();
    cur ^= 1;
  }
#pragma unroll
  for (int m = 0; m < 4; ++m) {
#pragma unroll
    for (int r = 0; r < 4; ++r) {
      int pxl = wpx + m * 16 + (l >> 4) * 4 + r;
      int ob = sOB[pxl];
#pragma unroll
      for (int n = 0; n < 4; ++n) {
        int co = wco + n * 16 + (l & 15);
        if (ob >= 0 && co < 96) outB[ob + co] = f2h(acc[m][n][r]);
      }
    }
  }
  float sn[4], qn[4];
#pragma unroll
  for (int n = 0; n < 4; ++n) { sn[n] = 0.f; qn[n] = 0.f; }
#pragma unroll
  for (int m = 0; m < 4; ++m) {
#pragma unroll
    for (int r = 0; r < 4; ++r) {
      int pxl = wpx + m * 16 + (l >> 4) * 4 + r;
      float msk = (px0 + pxl < NPIX) ? 1.f : 0.f;
#pragma unroll
      for (int n = 0; n < 4; ++n) {
        float v = acc[m][n][r] * msk;
        sn[n] += v;
        qn[n] = fmaf(v, v, qn[n]);
      }
    }
  }
#pragma unroll
  for (int n = 0; n < 4; ++n) {
    sn[n] += __shfl_xor(sn[n], 16, 64);
    sn[n] += __shfl_xor(sn[n], 32, 64);
    qn[n] += __shfl_xor(qn[n], 16, 64);
    qn[n] += __shfl_xor(qn[n], 32, 64);
  }
  if (l < 16) {
#pragma unroll
    for (int n = 0; n < 4; ++n) {
      sRed[w][n * 16 + l][0] = sn[n];
      sRed[w][n * 16 + l][1] = qn[n];
    }
  }
  __syncthreads();
  if (t < 128) {
    int wb = (t >> 6) << 1;
    int cl = t & 63;
    float S = sRed[wb][cl][0] + sRed[wb + 1][cl][0];
    float Q = sRed[wb][cl][1] + sRed[wb + 1][cl][1];
    long idx = ((long)t * gridDim.x + bxg) * 2;
    part[idx] = S;
    part[idx + 1] = Q;
  }
}

// ============ implicit-GEMM MFMA conv, branch-merged, dbuf + swizzle + fused stats ============
template <int K>
__global__ __launch_bounds__(256)
void conv_mfma(const unsigned short* __restrict__ in, const unsigned short* __restrict__ wt,
               unsigned short* __restrict__ out, float* __restrict__ part,
               int Ci, int Co_pad, int Co_real,
               int Hi1, int Ho1, int NPIX1, int BX1, long inOff2, long outOff2,
               int Hi2, int Ho2, int NPIX2) {
  __shared__ __align__(16) unsigned short sA[2][128 * 32];
  __shared__ __align__(16) unsigned short sB[2][128 * 32];
  __shared__ int sOB[128];
  __shared__ float sRed[4][64][2];
  const int t = threadIdx.x;
  const int bxg = blockIdx.x;
  const bool br2 = bxg >= BX1;
  const int lbx = br2 ? bxg - BX1 : bxg;
  const unsigned short* inB = in + (br2 ? inOff2 : 0);
  unsigned short* outB = out + (br2 ? outOff2 : 0);
  const int Hi = br2 ? Hi2 : Hi1, Wi = Hi;
  const int Ho = br2 ? Ho2 : Ho1, Wo = Ho;
  const int NPIX = br2 ? NPIX2 : NPIX1;
  const int px0 = lbx * 128;
  const int co0 = blockIdx.y * 128;
  if (t < 128) {
    int g = px0 + t;
    int ob = -1;
    if (g < NPIX) {
      int n = g / (Ho * Wo);
      int r = g - n * Ho * Wo;
      int oy = r / Wo, ox = r - (r / Wo) * Wo;
      ob = ((n * Ho + oy) * Wo + ox) * Co_real;
    }
    sOB[t] = ob;
  }
  long rbase[2];
#pragma unroll
  for (int i = 0; i < 2; ++i) {
    int pxl = i * 64 + (t >> 2);
    int g = px0 + pxl;
    long rb = 0;
    if (g < NPIX) {
      int n = g / (Ho * Wo);
      int r = g - n * Ho * Wo;
      int oy = r / Wo, ox = r - (r / Wo) * Wo;
      rb = ((long)(n * Hi + oy) * Wi + ox) * Ci;
    }
    rbase[i] = rb;
  }
  const int seg8 = ((t & 3) ^ ((t >> 3) & 3)) * 8;
  const int colA = t >> 2;
  f32x4 acc[4][4];
  f32x4 zz = {0.f, 0.f, 0.f, 0.f};
#pragma unroll
  for (int m = 0; m < 4; ++m)
#pragma unroll
    for (int n = 0; n < 4; ++n) acc[m][n] = zz;
  const int w = t >> 6;
  const int l = t & 63;
  const int wpx = (w & 1) * 64, wco = (w >> 1) * 64;
  const int arow = wpx + (l & 15);
  const int brow = wco + (l & 15);
  const int q8s = (((l >> 4) ^ (((l & 15) >> 1) & 3)) * 8);
  int ci0 = 0, kx = 0, ky = 0;
  const int NK = (Ci >> 5) * K * K;

  auto stage = [&](int buf) {
    long koff = (long)(ky * Wi + kx) * Ci + ci0 + seg8;
    gload_lds16(inB + rbase[0] + koff, &sA[buf][t * 8]);
    gload_lds16(inB + rbase[1] + koff, &sA[buf][(256 + t) * 8]);
    long wbase = (long)((ky * K + kx) * Co_pad + co0) * Ci + ci0 + seg8;
    gload_lds16(wt + wbase + (long)colA * Ci, &sB[buf][t * 8]);
    gload_lds16(wt + wbase + (long)(64 + colA) * Ci, &sB[buf][(256 + t) * 8]);
    ci0 += 32;
    if (ci0 == Ci) { ci0 = 0; ++kx; if (kx == K) { kx = 0; ++ky; } }
  };

  stage(0);
  __syncthreads();
  int cur = 0;
#pragma unroll 1
  for (int kk = 0; kk < NK; ++kk) {
    if (kk + 1 < NK) stage(cur ^ 1);
    f16x8 av[4], bv[4];
#pragma unroll
    for (int m = 0; m < 4; ++m) av[m] = *(const f16x8*)&sA[cur][(arow + m * 16) * 32 + q8s];
#pragma unroll
    for (int n = 0; n < 4; ++n) bv[n] = *(const f16x8*)&sB[cur][(brow + n * 16) * 32 + q8s];
#pragma unroll
    for (int m = 0; m < 4; ++m)
#pragma unroll
      for (int n = 0; n < 4; ++n)
        acc[m][n] = __builtin_amdgcn_mfma_f32_16x16x32_f16(av[m], bv[n], acc[m][n], 0, 0, 0);
    __syncthreads();
    cur ^= 1;
  }
#pragma unroll
  for (int m = 0; m < 4; ++m) {
#pragma unroll
    for (int r = 0; r < 4; ++r) {
      int pxl = wpx + m * 16 + (l >> 4) * 4 + r;
      int ob = sOB[pxl];
#pragma unroll
      for (int n = 0; n < 4; ++n) {
        int co = co0 + wco + n * 16 + (l & 15);
        if (ob >= 0 && co < Co_real) outB[ob + co] = f2h(acc[m][n][r]);
      }
    }
  }
  float sn[4], qn[4];
#pragma unroll
  for (int n = 0; n < 4; ++n) { sn[n] = 0.f; qn[n] = 0.f; }
#pragma unroll
  for (int m = 0; m < 4; ++m) {
#pragma unroll
    for (int r = 0; r < 4; ++r) {
      int pxl = wpx + m * 16 + (l >> 4) * 4 + r;
      float msk = (px0 + pxl < NPIX) ? 1.f : 0.f;
#pragma unroll
      for (int n = 0; n < 4; ++n) {
        float v = acc[m][n][r] * msk;
        sn[n] += v;
        qn[n] = fmaf(v, v, qn[n]);
      }
    }
  }
#pragma unroll
  for (int n = 0; n < 4; ++n) {
    sn[n] += __shfl_xor(sn[n], 16, 64);
    sn[n] += __shfl_xor(sn[n], 32, 64);
    qn[n] += __shfl_xor(qn[n], 16, 64);
    qn[n] += __shfl_xor(qn[n], 32, 64);
  }
  if (l < 16) {
#pragma unroll
    for (int n = 0; n < 4; ++n) {
      sRed[w][n * 16 + l][0] = sn[n];
      sRed[w][n * 16 + l][1] = qn[n];
    }
  }
  __syncthreads();
  if (t < 128) {
    int wb = (t >> 6) << 1;
    int cl = t & 63;
    float S = sRed[wb][cl][0] + sRed[wb + 1][cl][0];
    float Q = sRed[wb][cl][1] + sRed[wb + 1][cl][1];
    long idx = ((long)(co0 + t) * gridDim.x + bxg) * 2;
    part[idx] = S;
    part[idx + 1] = Q;
  }
}

// ============ BN finalize, branch-merged: grid = 2C blocks ============
__global__ void bn_finalize(const float* __restrict__ part, const float* __restrict__ g,
                            const float* __restrict__ b, float* __restrict__ sc,
                            float* __restrict__ sh, int C, int BX1, int BXtot,
                            float cnt1, float cnt2) {
  const int cb = blockIdx.x;
  const bool br2 = cb >= C;
  const int c = br2 ? cb - C : cb;
  const int k0 = br2 ? BX1 : 0;
  const int k1 = br2 ? BXtot : BX1;
  const float cnt = br2 ? cnt2 : cnt1;
  const int t = threadIdx.x;
  float s = 0.f, q = 0.f;
  const float* pc = part + (long)c * BXtot * 2;
  for (int k = k0 + t; k < k1; k += 256) {
    s += pc[k * 2];
    q += pc[k * 2 + 1];
  }
  __shared__ float ss[256], qq[256];
  ss[t] = s; qq[t] = q;
  __syncthreads();
  for (int off = 128; off > 0; off >>= 1) {
    if (t < off) { ss[t] += ss[t + off]; qq[t] += qq[t + off]; }
    __syncthreads();
  }
  if (t == 0) {
    float m = ss[0] / cnt;
    float v = qq[0] / cnt - m * m;
    float r = rsqrtf(v + 1e-5f);
    float scl = r * g[c];
    int o = c + (br2 ? 256 : 0);
    sc[o] = scl;
    sh[o] = b[c] - m * scl;
  }
}

// ============ BN apply, branch-merged (in place fp16 or fp16->fp32) ============
template <bool RELU, bool OUTF32>
__global__ void bn_apply_k(const unsigned short* __restrict__ x, void* __restrict__ y,
                           const float* __restrict__ sc, const float* __restrict__ sh,
                           int C, long t81, long t82, long xOff2, long yOff2q4) {
  long i = (long)blockIdx.x * blockDim.x + threadIdx.x;
  if (i >= t81 + t82) return;
  const bool br2 = i >= t81;
  const long ii = br2 ? i - t81 : i;
  const int scO = br2 ? 256 : 0;
  const uint4 v = ((const uint4*)x + (br2 ? xOff2 : 0))[ii];
  int c0 = (int)((ii * 8) % C);
  const float4 s0 = *(const float4*)&sc[scO + c0];
  const float4 s1 = *(const float4*)&sc[scO + c0 + 4];
  const float4 h0 = *(const float4*)&sh[scO + c0];
  const float4 h1 = *(const float4*)&sh[scO + c0 + 4];
  float f[8];
  f[0] = h2f((unsigned short)(v.x & 0xffff)); f[1] = h2f((unsigned short)(v.x >> 16));
  f[2] = h2f((unsigned short)(v.y & 0xffff)); f[3] = h2f((unsigned short)(v.y >> 16));
  f[4] = h2f((unsigned short)(v.z & 0xffff)); f[5] = h2f((unsigned short)(v.z >> 16));
  f[6] = h2f((unsigned short)(v.w & 0xffff)); f[7] = h2f((unsigned short)(v.w >> 16));
  const float S[8] = {s0.x, s0.y, s0.z, s0.w, s1.x, s1.y, s1.z, s1.w};
  const float H[8] = {h0.x, h0.y, h0.z, h0.w, h1.x, h1.y, h1.z, h1.w};
#pragma unroll
  for (int j = 0; j < 8; ++j) {
    f[j] = fmaf(f[j], S[j], H[j]);
    if (RELU) f[j] = fmaxf(f[j], 0.f);
  }
  if (OUTF32) {
    float4* yb = (float4*)y + (br2 ? yOff2q4 : 0);
    float4 o0 = {f[0], f[1], f[2], f[3]}, o1 = {f[4], f[5], f[6], f[7]};
    yb[2 * ii] = o0;
    yb[2 * ii + 1] = o1;
  } else {
    uint4 o;
    o.x = (unsigned)f2h(f[0]) | ((unsigned)f2h(f[1]) << 16);
    o.y = (unsigned)f2h(f[2]) | ((unsigned)f2h(f[3]) << 16);
    o.z = (unsigned)f2h(f[4]) | ((unsigned)f2h(f[5]) << 16);
    o.w = (unsigned)f2h(f[6]) | ((unsigned)f2h(f[7]) << 16);
    ((uint4*)y + (br2 ? xOff2 : 0))[ii] = o;
  }
}

// ============ fused BN+ReLU+MaxPool 3x3 s2, branch-merged ============
__global__ void bn_pool_k(const unsigned short* __restrict__ in, unsigned short* __restrict__ out,
                          const float* __restrict__ sc, const float* __restrict__ sh,
                          int C8, int Hi1, int Ho1, long t81, long inOff2, long outOff2,
                          int Hi2, int Ho2, long t82) {
  long i = (long)blockIdx.x * blockDim.x + threadIdx.x;
  if (i >= t81 + t82) return;
  const bool br2 = i >= t81;
  const long ii = br2 ? i - t81 : i;
  const int Hi = br2 ? Hi2 : Hi1, Wi = Hi;
  const int Ho = br2 ? Ho2 : Ho1, Wo = Ho;
  const int scO = br2 ? 256 : 0;
  const uint4* inB = (const uint4*)in + (br2 ? inOff2 : 0);
  uint4* outB = (uint4*)out + (br2 ? outOff2 : 0);
  int cg = (int)(ii % C8);
  long r = ii / C8;
  int ox = (int)(r % Wo);
  r /= Wo;
  int oy = (int)(r % Ho);
  int n = (int)(r / Ho);
  const int c0 = cg * 8;
  const float4 s0 = *(const float4*)&sc[scO + c0];
  const float4 s1 = *(const float4*)&sc[scO + c0 + 4];
  const float4 h0 = *(const float4*)&sh[scO + c0];
  const float4 h1 = *(const float4*)&sh[scO + c0 + 4];
  const float S[8] = {s0.x, s0.y, s0.z, s0.w, s1.x, s1.y, s1.z, s1.w};
  const float H[8] = {h0.x, h0.y, h0.z, h0.w, h1.x, h1.y, h1.z, h1.w};
  const uint4* bp = inB + ((long)(n * Hi + 2 * oy) * Wi + 2 * ox) * C8 + cg;
  float m[8];
#pragma unroll
  for (int j = 0; j < 8; ++j) m[j] = -3.4e38f;
#pragma unroll
  for (int dy = 0; dy < 3; ++dy)
#pragma unroll
    for (int dx = 0; dx < 3; ++dx) {
      const uint4 v = bp[((long)dy * Wi + dx) * C8];
      float f[8];
      f[0] = h2f((unsigned short)(v.x & 0xffff)); f[1] = h2f((unsigned short)(v.x >> 16));
      f[2] = h2f((unsigned short)(v.y & 0xffff)); f[3] = h2f((unsigned short)(v.y >> 16));
      f[4] = h2f((unsigned short)(v.z & 0xffff)); f[5] = h2f((unsigned short)(v.z >> 16));
      f[6] = h2f((unsigned short)(v.w & 0xffff)); f[7] = h2f((unsigned short)(v.w >> 16));
#pragma unroll
      for (int j = 0; j < 8; ++j) {
        f[j] = fmaxf(fmaf(f[j], S[j], H[j]), 0.f);
        m[j] = fmaxf(m[j], f[j]);
      }
    }
  uint4 o;
  o.x = (unsigned)f2h(m[0]) | ((unsigned)f2h(m[1]) << 16);
  o.y = (unsigned)f2h(m[2]) | ((unsigned)f2h(m[3]) << 16);
  o.z = (unsigned)f2h(m[4]) | ((unsigned)f2h(m[5]) << 16);
  o.w = (unsigned)f2h(m[6]) | ((unsigned)f2h(m[7]) << 16);
  outB[ii] = o;
}

// ============ cross-correlation partials: grid (289, 32) ============
__global__ void xcorr_part(const float* __restrict__ o1, const float* __restrict__ o2,
                           float* __restrict__ part) {
  const int p = blockIdx.x;
  const int b = blockIdx.y;
  const int oy = p / 17, ox = p - (p / 17) * 17;
  const float* o1b = o1 + (long)b * 22 * 22 * 128;
  const float* o2b = o2 + (long)b * 4608;
  float acc = 0.f;
  for (int i = threadIdx.x; i < 4608; i += 256) {
    int c = i & 127;
    int r = i >> 7;
    int kx = r % 6, ky = r / 6;
    acc = fmaf(o1b[((oy + ky) * 22 + ox + kx) * 128 + c], o2b[i], acc);
  }
#pragma unroll
  for (int off = 32; off > 0; off >>= 1) acc += __shfl_down(acc, off, 64);
  __shared__ float sh[4];
  const int lane = threadIdx.x & 63, wid = threadIdx.x >> 6;
  if (lane == 0) sh[wid] = acc;
  __syncthreads();
  if (threadIdx.x == 0) part[p * 32 + b] = sh[0] + sh[1] + sh[2] + sh[3];
}

__global__ void xcorr_out(const float* __restrict__ part, float* __restrict__ out, int total) {
  int i = blockIdx.x * 256 + threadIdx.x;
  if (i >= total) return;
  int p = i % 289;
  float s = 0.f;
  for (int b = 0; b < 32; ++b) s += part[p * 32 + b];
  out[i] = s * (1.f / 147456.f);
}

// ============ host ============
extern "C" void kernel_launch(void* const* d_in, const int* in_sizes, int n_in,
                              void* d_out, int out_size, void* d_ws, size_t ws_size,
                              hipStream_t stream) {
  (void)in_sizes; (void)n_in; (void)ws_size; (void)out_size;
  const float* input1 = (const float*)d_in[0];
  const float* input2 = (const float*)d_in[1];
  const float* cw[5];
  const float* bg[5];
  const float* bb[5];
  for (int i = 0; i < 5; ++i) {
    cw[i] = (const float*)d_in[2 + 2 * i];
    bg[i] = (const float*)d_in[12 + 2 * i];
    bb[i] = (const float*)d_in[13 + 2 * i];
  }
  // geometry
  const int H1a = 123, P1a = 61, H2a = 57, P2a = 28, H3a = 26, H4a = 24, H5a = 22;
  const int H1b = 59, P1b = 29, H2b = 25, P2b = 12, H3b = 10, H4b = 8, H5b = 6;
  auto NP = [](int h) { return 32 * h * h; };
  const int NP1a = NP(H1a), NP1b = NP(H1b);
  const int NP2a = NP(H2a), NP2b = NP(H2b);
  const int NP3a = NP(H3a), NP3b = NP(H3b);
  const int NP4a = NP(H4a), NP4b = NP(H4b);
  const int NP5a = NP(H5a), NP5b = NP(H5b);
  auto BX = [](int np) { return (np + 127) / 128; };

  char* p = (char*)d_ws;
  auto alloc = [&](size_t bytes) {
    char* r = p;
    p += (bytes + 255) & ~(size_t)255;
    return r;
  };
  // P holds conv outputs of layers 1/3/5 (b1+b2 concatenated); sized for layer1
  unsigned short* P = (unsigned short*)alloc(((size_t)NP1a + NP1b) * 96 * 2);
  unsigned short* R = (unsigned short*)alloc(((size_t)NP(P1a) + NP(P1b)) * 96 * 2);
  unsigned short* Q = (unsigned short*)alloc(((size_t)NP4a + NP4b) * 192 * 2);
  float* O12 = (float*)alloc(((size_t)NP5a + NP5b) * 128 * 4);
  unsigned short* I12h = (unsigned short*)alloc(((size_t)32 * 255 * 255 * 4 + (size_t)32 * 127 * 127 * 4) * 2 + 16384);
  unsigned short* W1h = (unsigned short*)alloc(17l * 128 * 32 * 2);
  unsigned short* W2 = (unsigned short*)alloc(25l * 256 * 96 * 2);
  unsigned short* W3 = (unsigned short*)alloc(9l * 256 * 256 * 2);
  unsigned short* W4 = (unsigned short*)alloc(9l * 256 * 192 * 2);
  unsigned short* W5 = (unsigned short*)alloc(9l * 128 * 192 * 2);
  float* part = (float*)alloc(9000000);
  float* sc = (float*)alloc(512 * 4);
  float* sh = (float*)alloc(512 * 4);
  float* O1 = O12;
  float* O2 = O12 + (size_t)NP5a * 128;

  // merged transforms
  {
    long wt_tot = 17l * 128 * 32 + 25l * 256 * 96 + 9l * 256 * 256 + 9l * 256 * 192 + 9l * 128 * 192;
    wt_all<<<(unsigned)((wt_tot + 255) / 256), 256, 0, stream>>>(cw[0], cw[1], cw[2], cw[3], cw[4],
                                                                 W1h, W2, W3, W4, W5);
    long in_tot = 32l * 255 * 255 + 32l * 127 * 127;
    in_all<<<(unsigned)((in_tot + 255) / 256), 256, 0, stream>>>(input1, input2, I12h,
                                                                 I12h + 32l * 255 * 255 * 4);
  }

  // ---- layer 1 ----
  {
    int BX1 = BX(NP1a), BXt = BX1 + BX(NP1b);
    conv1_mfma<<<(unsigned)BXt, 256, 0, stream>>>(I12h, W1h, P, part,
        255, H1a, NP1a, BX1, 32l * 255 * 255 * 4, (long)NP1a * 96,
        127, H1b, NP1b);
    bn_finalize<<<192, 256, 0, stream>>>(part, bg[0], bb[0], sc, sh, 96, BX1, BXt,
                                         (float)NP1a, (float)NP1b);
    long t81 = (long)NP(P1a) * 96 / 8, t82 = (long)NP(P1b) * 96 / 8;
    bn_pool_k<<<(unsigned)((t81 + t82 + 255) / 256), 256, 0, stream>>>(
        P, R, sc, sh, 12, H1a, P1a, t81, (long)NP1a * 96 / 8, t81, H1b, P1b, t82);
  }
  // ---- layer 2 ----
  {
    int BX1 = BX(NP2a), BXt = BX1 + BX(NP2b);
    dim3 g((unsigned)BXt, 2);
    conv_mfma<5><<<g, 256, 0, stream>>>(R, W2, P, part, 96, 256, 256,
        P1a, H2a, NP2a, BX1, (long)NP(P1a) * 96, (long)NP2a * 256,
        P1b, H2b, NP2b);
    bn_finalize<<<512, 256, 0, stream>>>(part, bg[1], bb[1], sc, sh, 256, BX1, BXt,
                                         (float)NP2a, (float)NP2b);
    long t81 = (long)NP(P2a) * 256 / 8, t82 = (long)NP(P2b) * 256 / 8;
    bn_pool_k<<<(unsigned)((t81 + t82 + 255) / 256), 256, 0, stream>>>(
        P, R, sc, sh, 32, H2a, P2a, t81, (long)NP2a * 256 / 8, t81, H2b, P2b, t82);
  }
  // ---- layer 3 ----
  {
    int BX1 = BX(NP3a), BXt = BX1 + BX(NP3b);
    dim3 g((unsigned)BXt, 2);
    conv_mfma<3><<<g, 256, 0, stream>>>(R, W3, P, part, 256, 256, 192,
        P2a, H3a, NP3a, BX1, (long)NP(P2a) * 256, (long)NP3a * 192,
        P2b, H3b, NP3b);
    bn_finalize<<<384, 256, 0, stream>>>(part, bg[2], bb[2], sc, sh, 192, BX1, BXt,
                                         (float)NP3a, (float)NP3b);
    long t81 = (long)NP3a * 192 / 8, t82 = (long)NP3b * 192 / 8;
    bn_apply_k<true, false><<<(unsigned)((t81 + t82 + 255) / 256), 256, 0, stream>>>(
        P, P, sc, sh, 192, t81, t82, t81, 0);
  }
  // ---- layer 4 ----
  {
    int BX1 = BX(NP4a), BXt = BX1 + BX(NP4b);
    dim3 g((unsigned)BXt, 2);
    conv_mfma<3><<<g, 256, 0, stream>>>(P, W4, Q, part, 192, 256, 192,
        H3a, H4a, NP4a, BX1, (long)NP3a * 192, (long)NP4a * 192,
        H3b, H4b, NP4b);
    bn_finalize<<<384, 256, 0, stream>>>(part, bg[3], bb[3], sc, sh, 192, BX1, BXt,
                                         (float)NP4a, (float)NP4b);
    long t81 = (long)NP4a * 192 / 8, t82 = (long)NP4b * 192 / 8;
    bn_apply_k<true, false><<<(unsigned)((t81 + t82 + 255) / 256), 256, 0, stream>>>(
        Q, Q, sc, sh, 192, t81, t82, t81, 0);
  }
  // ---- layer 5 ----
  {
    int BX1 = BX(NP5a), BXt = BX1 + BX(NP5b);
    dim3 g((unsigned)BXt, 1);
    conv_mfma<3><<<g, 256, 0, stream>>>(Q, W5, P, part, 192, 128, 128,
        H4a, H5a, NP5a, BX1, (long)NP4a * 192, (long)NP5a * 128,
        H4b, H5b, NP5b);
    bn_finalize<<<256, 256, 0, stream>>>(part, bg[4], bb[4], sc, sh, 128, BX1, BXt,
                                         (float)NP5a, (float)NP5b);
    long t81 = (long)NP5a * 128 / 8, t82 = (long)NP5b * 128 / 8;
    bn_apply_k<false, true><<<(unsigned)((t81 + t82 + 255) / 256), 256, 0, stream>>>(
        P, O12, sc, sh, 128, t81, t82, t81, (long)NP5a * 128 / 4);
  }

  xcorr_part<<<dim3(289, 32), 256, 0, stream>>>(O1, O2, part);
  xcorr_out<<<(9248 + 255) / 256, 256, 0, stream>>>(part, (float*)d_out, 9248);
}